// Round 6
// baseline (9609.483 us; speedup 1.0000x reference)
//
#include <hip/hip_runtime.h>
#include <cstdint>

#define SEQ   4096
#define DM    768
#define NH    12
#define HD    64
#define KD    768

typedef float  f32x4  __attribute__((ext_vector_type(4)));
typedef short  bf16x8 __attribute__((ext_vector_type(8)));

typedef __attribute__((address_space(1))) const unsigned int gu32;
typedef __attribute__((address_space(3))) unsigned int lu32;

__device__ __forceinline__ unsigned short f2b(float f) {
  unsigned int u = __builtin_bit_cast(unsigned int, f);
  u += 0x7fffu + ((u >> 16) & 1u);
  return (unsigned short)(u >> 16);
}
__device__ __forceinline__ float b2f(unsigned short s) {
  return __builtin_bit_cast(float, ((unsigned int)s) << 16);
}

__device__ __forceinline__ void gload_lds16(const void* g, void* l) {
  gu32* gp = reinterpret_cast<gu32*>(reinterpret_cast<uintptr_t>(g));
  lu32* lp = reinterpret_cast<lu32*>(reinterpret_cast<uintptr_t>(l));
  __builtin_amdgcn_global_load_lds(gp, lp, 16, 0, 0);
}

// ---------------- pack/convert: f32 -> bf16 (R3-verified) ----------------
__global__ void convert_all(const float* __restrict__ x,
                            const float* __restrict__ wq,
                            const float* __restrict__ wk,
                            const float* __restrict__ wv,
                            const float* __restrict__ wo,
                            unsigned short* __restrict__ xb,
                            unsigned short* __restrict__ wqkv,
                            unsigned short* __restrict__ wob)
{
  const int XN = SEQ * DM;
  const int WN = DM * DM;
  const int total4 = (XN + 4 * WN) >> 2;
  for (int i = blockIdx.x * blockDim.x + threadIdx.x; i < total4;
       i += gridDim.x * blockDim.x) {
    const int base = i << 2;
    const float* src;
    unsigned short* dst;
    if (base < XN)                 { src = x  + base;               dst = xb   + base; }
    else if (base < XN + WN)       { src = wq + (base - XN);        dst = wqkv + (base - XN); }
    else if (base < XN + 2 * WN)   { src = wk + (base - XN - WN);   dst = wqkv + (base - XN); }
    else if (base < XN + 3 * WN)   { src = wv + (base - XN - 2*WN); dst = wqkv + (base - XN); }
    else                           { src = wo + (base - XN - 3*WN); dst = wob  + (base - XN - 3*WN); }
    const float4 v = *(const float4*)src;
    *(ushort4*)dst = make_ushort4(f2b(v.x), f2b(v.y), f2b(v.z), f2b(v.w));
  }
}

// ---------------- GEMM C = A[M,K] * B[N,K]^T (R3-verified, row-major out) ----
template<int EPI>
__global__ __launch_bounds__(256, 2)
void gemm_bt(const unsigned short* __restrict__ A,
             const unsigned short* __restrict__ B,
             unsigned short* __restrict__ qb,
             unsigned short* __restrict__ kb,
             unsigned short* __restrict__ vb,
             const float* __restrict__ bq,
             const float* __restrict__ bk,
             const float* __restrict__ bv,
             const float* __restrict__ bo,
             float* __restrict__ outf)
{
  __shared__ __align__(16) unsigned short As[128 * 32];
  __shared__ __align__(16) unsigned short Bs[128 * 32];
  const int t  = threadIdx.x;
  const int w  = t >> 6;
  const int l  = t & 63;
  const int m0 = blockIdx.y * 128;
  const int n0 = blockIdx.x * 128;
  const int wr = (w >> 1) * 64;
  const int wc = (w & 1) * 64;
  const int lr = l & 15;
  const int lk = (l >> 4) * 8;

  const int row1 = t >> 2;
  const int row2 = row1 + 64;
  const int seg  = t & 3;

  f32x4 acc[4][4];
#pragma unroll
  for (int i = 0; i < 4; i++)
#pragma unroll
    for (int j = 0; j < 4; j++) acc[i][j] = (f32x4){0.f, 0.f, 0.f, 0.f};

  char* ldsA0 = (char*)As + (size_t)(w * 64) * 16;
  char* ldsA1 = (char*)As + (size_t)(w * 64 + 256) * 16;
  char* ldsB0 = (char*)Bs + (size_t)(w * 64) * 16;
  char* ldsB1 = (char*)Bs + (size_t)(w * 64 + 256) * 16;

  for (int k0 = 0; k0 < KD; k0 += 32) {
    gload_lds16(A + (size_t)(m0 + row1) * KD + k0 + seg * 8, ldsA0);
    gload_lds16(A + (size_t)(m0 + row2) * KD + k0 + seg * 8, ldsA1);
    gload_lds16(B + (size_t)(n0 + row1) * KD + k0 + seg * 8, ldsB0);
    gload_lds16(B + (size_t)(n0 + row2) * KD + k0 + seg * 8, ldsB1);
    __syncthreads();
    bf16x8 af[4], bfv[4];
#pragma unroll
    for (int fi = 0; fi < 4; fi++)
      af[fi] = *(const bf16x8*)(As + (wr + fi * 16 + lr) * 32 + lk);
#pragma unroll
    for (int fj = 0; fj < 4; fj++)
      bfv[fj] = *(const bf16x8*)(Bs + (wc + fj * 16 + lr) * 32 + lk);
#pragma unroll
    for (int fi = 0; fi < 4; fi++)
#pragma unroll
      for (int fj = 0; fj < 4; fj++)
        acc[fi][fj] = __builtin_amdgcn_mfma_f32_16x16x32_bf16(af[fi], bfv[fj], acc[fi][fj], 0, 0, 0);
    __syncthreads();
  }

#pragma unroll
  for (int fi = 0; fi < 4; fi++) {
    const int mbase = m0 + wr + fi * 16 + (l >> 4) * 4;
#pragma unroll
    for (int fj = 0; fj < 4; fj++) {
      const int n = n0 + wc + fj * 16 + lr;
      if (EPI == 1) {
        const float bb = bo[n];
#pragma unroll
        for (int r = 0; r < 4; r++)
          outf[(size_t)(mbase + r) * DM + n] = acc[fi][fj][r] + bb;
      } else if (n < DM) {                       // Q (scaled by 1/8)
        const int hh = n >> 6, dk = n & 63;
        const float bb = bq[n];
#pragma unroll
        for (int r = 0; r < 4; r++)
          qb[((size_t)hh * SEQ + mbase + r) * HD + dk] = f2b((acc[fi][fj][r] + bb) * 0.125f);
      } else if (n < 2 * DM) {                   // K row-major [h][s][dk]
        const int n2 = n - DM, hh = n2 >> 6, dk = n2 & 63;
        const float bb = bk[n2];
#pragma unroll
        for (int r = 0; r < 4; r++)
          kb[((size_t)hh * SEQ + mbase + r) * HD + dk] = f2b(acc[fi][fj][r] + bb);
      } else {                                   // V row-major [h][s][dk]
        const int n3 = n - 2 * DM, hh = n3 >> 6, dk = n3 & 63;
        const float bb = bv[n3];
#pragma unroll
        for (int r = 0; r < 4; r++)
          vb[((size_t)hh * SEQ + mbase + r) * HD + dk] = f2b(acc[fi][fj][r] + bb);
      }
    }
  }
}

// ---------------- BISECT 2: SCALAR QK^T into C-layout slots, rest = R5 -------
// mask: valid(qi, j) = (qi==0) || (j==0) || |qi-j| <= 256
#define PSTR 72
__global__ __launch_bounds__(256, 2)
void attn_bisect2(const unsigned short* __restrict__ qb,
                  const unsigned short* __restrict__ kb,
                  const unsigned short* __restrict__ vb,
                  unsigned short* __restrict__ ctx)
{
  __shared__ __align__(16) unsigned short plds[4][16 * PSTR];
  const int h  = blockIdx.y;
  const int i0 = blockIdx.x * 64;
  const int t  = threadIdx.x;
  const int w  = t >> 6, l = t & 63;
  const int lr = l & 15;
  const int qbase = i0 + w * 16;
  const unsigned short* Qh = qb + (size_t)h * SEQ * HD;
  const unsigned short* Kh = kb + (size_t)h * SEQ * HD;
  const unsigned short* Vh = vb + (size_t)h * SEQ * HD;

  f32x4 o[4];
#pragma unroll
  for (int i = 0; i < 4; i++) o[i] = (f32x4){0.f, 0.f, 0.f, 0.f};
  float mrow[4] = {-1e30f, -1e30f, -1e30f, -1e30f};
  float lsum[4] = {0.f, 0.f, 0.f, 0.f};

  int cbeg, cend, cfirst;
  if (i0 == 0) {
    cbeg = 0; cend = (SEQ / 64) - 1; cfirst = 0;
  } else {
    int lo = i0 - 256; if (lo < 0) lo = 0;
    int hi = i0 + 320; if (hi > SEQ) hi = SEQ;
    cbeg = lo >> 6; cend = (hi - 1) >> 6;
    cfirst = (cbeg > 0) ? (cbeg - 1) : cbeg;
  }
  const int qi0 = qbase + (l >> 4) * 4;
  unsigned short* P = &plds[w][0];

  for (int cc = cfirst; cc <= cend; cc++) {
    const int c  = (cc < cbeg) ? 0 : cc;
    const int j0 = c * 64;

    // ---- SCALAR QK^T into the same C-layout slots:
    //      sc[fj][r] = S[qi0+r][j0+fj*16+lr]
    f32x4 sc[4];
#pragma unroll
    for (int fj = 0; fj < 4; fj++) {
      const unsigned short* Kp = Kh + (size_t)(j0 + fj * 16 + lr) * HD;
      bf16x8 kv[8];
#pragma unroll
      for (int d0 = 0; d0 < 8; d0++) kv[d0] = *(const bf16x8*)(Kp + d0 * 8);
#pragma unroll
      for (int r = 0; r < 4; r++) {
        const unsigned short* Qp = Qh + (size_t)(qi0 + r) * HD;
        float s = 0.f;
#pragma unroll
        for (int d0 = 0; d0 < 8; d0++) {
          const bf16x8 qv = *(const bf16x8*)(Qp + d0 * 8);
#pragma unroll
          for (int e = 0; e < 8; e++)
            s += b2f((unsigned short)qv[e]) * b2f((unsigned short)kv[d0][e]);
        }
        sc[fj][r] = s;
      }
    }

    // ---- mask + online softmax (UNCHANGED from R5)
#pragma unroll
    for (int r = 0; r < 4; r++) {
      const int qi = qi0 + r;
      float mx = -1e30f;
#pragma unroll
      for (int fj = 0; fj < 4; fj++) {
        const int j = j0 + fj * 16 + lr;
        const bool valid = (qi == 0) || (j == 0) ||
                           ((j - qi) <= 256 && (qi - j) <= 256);
        const float v = valid ? sc[fj][r] : -1e30f;
        sc[fj][r] = v;
        mx = fmaxf(mx, v);
      }
      for (int d = 1; d < 16; d <<= 1) mx = fmaxf(mx, __shfl_xor(mx, d));
      const float mnew = fmaxf(mrow[r], mx);
      const float scale = __expf(mrow[r] - mnew);
      mrow[r] = mnew;
      float sum = 0.f;
#pragma unroll
      for (int fj = 0; fj < 4; fj++) {
        const float p = __expf(sc[fj][r] - mnew);
        sc[fj][r] = p;
        sum += p;
      }
      for (int d = 1; d < 16; d <<= 1) sum += __shfl_xor(sum, d);
      lsum[r] = lsum[r] * scale + sum;
#pragma unroll
      for (int fn = 0; fn < 4; fn++) o[fn][r] *= scale;
    }

    // ---- P -> LDS (UNCHANGED)
#pragma unroll
    for (int fj = 0; fj < 4; fj++)
#pragma unroll
      for (int r = 0; r < 4; r++)
        P[(size_t)((l >> 4) * 4 + r) * PSTR + fj * 16 + lr] = f2b(sc[fj][r]);
    __syncthreads();

    // ---- SCALAR PV (UNCHANGED from R5)
#pragma unroll
    for (int r = 0; r < 4; r++) {
      const int prow = (l >> 4) * 4 + r;
      float pv[4] = {0.f, 0.f, 0.f, 0.f};
      for (int jj = 0; jj < 64; jj++) {
        const float pj = b2f(P[(size_t)prow * PSTR + jj]);
        const unsigned short* Vrow = Vh + (size_t)(j0 + jj) * HD + lr;
#pragma unroll
        for (int fn = 0; fn < 4; fn++)
          pv[fn] += pj * b2f(Vrow[fn * 16]);
      }
#pragma unroll
      for (int fn = 0; fn < 4; fn++) o[fn][r] += pv[fn];
    }
    __syncthreads();
  }

#pragma unroll
  for (int fn = 0; fn < 4; fn++)
#pragma unroll
    for (int r = 0; r < 4; r++) {
      const int s = qi0 + r;
      const float val = o[fn][r] / lsum[r];
      ctx[(size_t)s * DM + h * HD + fn * 16 + lr] = f2b(val);
    }
}

// ---------------- launch ----------------
extern "C" void kernel_launch(void* const* d_in, const int* in_sizes, int n_in,
                              void* d_out, int out_size, void* d_ws, size_t ws_size,
                              hipStream_t stream)
{
  (void)in_sizes; (void)n_in; (void)out_size; (void)ws_size;
  const float* x  = (const float*)d_in[0];
  const float* Wq = (const float*)d_in[1];
  const float* bq = (const float*)d_in[2];
  const float* Wk = (const float*)d_in[3];
  const float* bk = (const float*)d_in[4];
  const float* Wv = (const float*)d_in[5];
  const float* bv = (const float*)d_in[6];
  const float* Wo = (const float*)d_in[7];
  const float* bo = (const float*)d_in[8];
  float* out = (float*)d_out;

  char* ws = (char*)d_ws;
  unsigned short* xb   = (unsigned short*)(ws + 0);         // 4096x768 bf16 (dead after gemm<0>)
  unsigned short* wqkv = (unsigned short*)(ws + 6291456);   // 2304x768 bf16
  unsigned short* wob  = (unsigned short*)(ws + 9830400);   // 768x768 bf16
  unsigned short* qbuf = (unsigned short*)(ws + 11010048);  // [12][4096][64]
  unsigned short* kbuf = (unsigned short*)(ws + 17301504);  // [12][4096][64]
  unsigned short* vbuf = (unsigned short*)(ws + 23592960);  // [12][4096][64] row-major
  unsigned short* ctx  = (unsigned short*)(ws + 0);         // aliases xb (safe: xb dead)

  convert_all<<<dim3(1024), dim3(256), 0, stream>>>(x, Wq, Wk, Wv, Wo, xb, wqkv, wob);
  gemm_bt<0><<<dim3(18, 32), dim3(256), 0, stream>>>(xb, wqkv, qbuf, kbuf, vbuf,
                                                     bq, bk, bv, nullptr, nullptr);
  attn_bisect2<<<dim3(SEQ / 64, NH), dim3(256), 0, stream>>>(qbuf, kbuf, vbuf, ctx);
  gemm_bt<1><<<dim3(6, 32), dim3(256), 0, stream>>>(ctx, wob, nullptr, nullptr, nullptr,
                                                    nullptr, nullptr, nullptr, bo, out);
}

// Round 11
// 743.131 us; speedup vs baseline: 12.9311x; 12.9311x over previous
//
#include <hip/hip_runtime.h>
#include <cstdint>

#define SEQ   4096
#define DM    768
#define NH    12
#define HD    64
#define KD    768

typedef float  f32x4  __attribute__((ext_vector_type(4)));
typedef short  bf16x8 __attribute__((ext_vector_type(8)));

typedef __attribute__((address_space(1))) const unsigned int gu32;
typedef __attribute__((address_space(3))) unsigned int lu32;

__device__ __forceinline__ unsigned short f2b(float f) {
  unsigned int u = __builtin_bit_cast(unsigned int, f);
  u += 0x7fffu + ((u >> 16) & 1u);
  return (unsigned short)(u >> 16);
}
__device__ __forceinline__ float b2f(unsigned short s) {
  return __builtin_bit_cast(float, ((unsigned int)s) << 16);
}

__device__ __forceinline__ void gload_lds16(const void* g, void* l) {
  gu32* gp = reinterpret_cast<gu32*>(reinterpret_cast<uintptr_t>(g));
  lu32* lp = reinterpret_cast<lu32*>(reinterpret_cast<uintptr_t>(l));
  __builtin_amdgcn_global_load_lds(gp, lp, 16, 0, 0);
}

// ---------------- pack/convert: f32 -> bf16 (R3-verified) ----------------
__global__ void convert_all(const float* __restrict__ x,
                            const float* __restrict__ wq,
                            const float* __restrict__ wk,
                            const float* __restrict__ wv,
                            const float* __restrict__ wo,
                            unsigned short* __restrict__ xb,
                            unsigned short* __restrict__ wqkv,
                            unsigned short* __restrict__ wob)
{
  const int XN = SEQ * DM;
  const int WN = DM * DM;
  const int total4 = (XN + 4 * WN) >> 2;
  for (int i = blockIdx.x * blockDim.x + threadIdx.x; i < total4;
       i += gridDim.x * blockDim.x) {
    const int base = i << 2;
    const float* src;
    unsigned short* dst;
    if (base < XN)                 { src = x  + base;               dst = xb   + base; }
    else if (base < XN + WN)       { src = wq + (base - XN);        dst = wqkv + (base - XN); }
    else if (base < XN + 2 * WN)   { src = wk + (base - XN - WN);   dst = wqkv + (base - XN); }
    else if (base < XN + 3 * WN)   { src = wv + (base - XN - 2*WN); dst = wqkv + (base - XN); }
    else                           { src = wo + (base - XN - 3*WN); dst = wob  + (base - XN - 3*WN); }
    const float4 v = *(const float4*)src;
    *(ushort4*)dst = make_ushort4(f2b(v.x), f2b(v.y), f2b(v.z), f2b(v.w));
  }
}

// ---------------- GEMM C = A[M,K] * B[N,K]^T (R3-verified) ----------------
template<int EPI>
__global__ __launch_bounds__(256, 2)
void gemm_bt(const unsigned short* __restrict__ A,
             const unsigned short* __restrict__ B,
             unsigned short* __restrict__ qb,
             unsigned short* __restrict__ kb,
             unsigned short* __restrict__ vb,
             const float* __restrict__ bq,
             const float* __restrict__ bk,
             const float* __restrict__ bv,
             const float* __restrict__ bo,
             float* __restrict__ outf)
{
  __shared__ __align__(16) unsigned short As[128 * 32];
  __shared__ __align__(16) unsigned short Bs[128 * 32];
  const int t  = threadIdx.x;
  const int w  = t >> 6;
  const int l  = t & 63;
  const int m0 = blockIdx.y * 128;
  const int n0 = blockIdx.x * 128;
  const int wr = (w >> 1) * 64;
  const int wc = (w & 1) * 64;
  const int lr = l & 15;
  const int lk = (l >> 4) * 8;

  const int row1 = t >> 2;
  const int row2 = row1 + 64;
  const int seg  = t & 3;

  f32x4 acc[4][4];
#pragma unroll
  for (int i = 0; i < 4; i++)
#pragma unroll
    for (int j = 0; j < 4; j++) acc[i][j] = (f32x4){0.f, 0.f, 0.f, 0.f};

  char* ldsA0 = (char*)As + (size_t)(w * 64) * 16;
  char* ldsA1 = (char*)As + (size_t)(w * 64 + 256) * 16;
  char* ldsB0 = (char*)Bs + (size_t)(w * 64) * 16;
  char* ldsB1 = (char*)Bs + (size_t)(w * 64 + 256) * 16;

  for (int k0 = 0; k0 < KD; k0 += 32) {
    gload_lds16(A + (size_t)(m0 + row1) * KD + k0 + seg * 8, ldsA0);
    gload_lds16(A + (size_t)(m0 + row2) * KD + k0 + seg * 8, ldsA1);
    gload_lds16(B + (size_t)(n0 + row1) * KD + k0 + seg * 8, ldsB0);
    gload_lds16(B + (size_t)(n0 + row2) * KD + k0 + seg * 8, ldsB1);
    __syncthreads();
    bf16x8 af[4], bfv[4];
#pragma unroll
    for (int fi = 0; fi < 4; fi++)
      af[fi] = *(const bf16x8*)(As + (wr + fi * 16 + lr) * 32 + lk);
#pragma unroll
    for (int fj = 0; fj < 4; fj++)
      bfv[fj] = *(const bf16x8*)(Bs + (wc + fj * 16 + lr) * 32 + lk);
#pragma unroll
    for (int fi = 0; fi < 4; fi++)
#pragma unroll
      for (int fj = 0; fj < 4; fj++)
        acc[fi][fj] = __builtin_amdgcn_mfma_f32_16x16x32_bf16(af[fi], bfv[fj], acc[fi][fj], 0, 0, 0);
    __syncthreads();
  }

#pragma unroll
  for (int fi = 0; fi < 4; fi++) {
    const int mbase = m0 + wr + fi * 16 + (l >> 4) * 4;
#pragma unroll
    for (int fj = 0; fj < 4; fj++) {
      const int n = n0 + wc + fj * 16 + lr;
      if (EPI == 1) {
        const float bb = bo[n];
#pragma unroll
        for (int r = 0; r < 4; r++)
          outf[(size_t)(mbase + r) * DM + n] = acc[fi][fj][r] + bb;
      } else if (n < DM) {                       // Q (scaled by 1/8)
        const int hh = n >> 6, dk = n & 63;
        const float bb = bq[n];
#pragma unroll
        for (int r = 0; r < 4; r++)
          qb[((size_t)hh * SEQ + mbase + r) * HD + dk] = f2b((acc[fi][fj][r] + bb) * 0.125f);
      } else if (n < 2 * DM) {                   // K row-major [h][s][dk]
        const int n2 = n - DM, hh = n2 >> 6, dk = n2 & 63;
        const float bb = bk[n2];
#pragma unroll
        for (int r = 0; r < 4; r++)
          kb[((size_t)hh * SEQ + mbase + r) * HD + dk] = f2b(acc[fi][fj][r] + bb);
      } else {                                   // V row-major [h][s][dk]
        const int n3 = n - 2 * DM, hh = n3 >> 6, dk = n3 & 63;
        const float bb = bv[n3];
#pragma unroll
        for (int r = 0; r < 4; r++)
          vb[((size_t)hh * SEQ + mbase + r) * HD + dk] = f2b(acc[fi][fj][r] + bb);
      }
    }
  }
}

// ------------- band attention, wave-per-query, scalar f32 (fast R3) ----------
// mask: valid(qi, j) = (qi==0) || (j==0) || |qi-j| <= 256
// Row 0 is computed band-only here and OVERWRITTEN by attn_global12 after.
__global__ __launch_bounds__(256)
void attn_band2(const unsigned short* __restrict__ qb,
                const unsigned short* __restrict__ kb,
                const unsigned short* __restrict__ vb,
                unsigned short* __restrict__ ctx)
{
  __shared__ __align__(16) float plds[4][64];
  const int h    = blockIdx.y;
  const int w    = threadIdx.x >> 6;
  const int lane = threadIdx.x & 63;
  const int qi   = blockIdx.x * 4 + w;

  const unsigned short* Qh = qb + (size_t)h * SEQ * HD;
  const unsigned short* Kh = kb + (size_t)h * SEQ * HD;
  const unsigned short* Vh = vb + (size_t)h * SEQ * HD;

  // q row -> 64 f32 registers (identical in all lanes; q pre-scaled by 1/8)
  float qf[64];
#pragma unroll
  for (int d0 = 0; d0 < 8; d0++) {
    const bf16x8 qv = *(const bf16x8*)(Qh + (size_t)qi * HD + d0 * 8);
#pragma unroll
    for (int e = 0; e < 8; e++) qf[d0 * 8 + e] = b2f((unsigned short)qv[e]);
  }

  int cbeg, cend;
  {
    int lo = qi - 256; if (lo < 0) lo = 0;
    int hi = qi + 257; if (hi > SEQ) hi = SEQ;
    cbeg = lo >> 6; cend = (hi - 1) >> 6;
  }
  const int cfirst = (cbeg > 0) ? (cbeg - 1) : cbeg;

  float o = 0.f, m = -1e30f, lsum = 0.f;

  for (int cc = cfirst; cc <= cend; cc++) {
    const int c = (cc < cbeg) ? 0 : cc;
    const int j = c * 64 + lane;

    // ---- s_j = q . k_j, 4-way ILP
    const unsigned short* Kp = Kh + (size_t)j * HD;
    float s0 = 0.f, s1 = 0.f, s2 = 0.f, s3 = 0.f;
#pragma unroll
    for (int d0 = 0; d0 < 8; d0++) {
      const bf16x8 kv = *(const bf16x8*)(Kp + d0 * 8);
      s0 += qf[d0 * 8 + 0] * b2f((unsigned short)kv[0]);
      s1 += qf[d0 * 8 + 1] * b2f((unsigned short)kv[1]);
      s2 += qf[d0 * 8 + 2] * b2f((unsigned short)kv[2]);
      s3 += qf[d0 * 8 + 3] * b2f((unsigned short)kv[3]);
      s0 += qf[d0 * 8 + 4] * b2f((unsigned short)kv[4]);
      s1 += qf[d0 * 8 + 5] * b2f((unsigned short)kv[5]);
      s2 += qf[d0 * 8 + 6] * b2f((unsigned short)kv[6]);
      s3 += qf[d0 * 8 + 7] * b2f((unsigned short)kv[7]);
    }
    float s = (s0 + s1) + (s2 + s3);
    const bool valid = (qi == 0) || (j == 0) ||
                       ((j - qi) <= 256 && (qi - j) <= 256);
    s = valid ? s : -1e30f;

    // ---- wave-wide online softmax (R3-verified pattern)
    float mx = s;
    for (int d = 1; d < 64; d <<= 1) mx = fmaxf(mx, __shfl_xor(mx, d));
    const float mnew = fmaxf(m, mx);
    const float esc  = __expf(m - mnew);
    const float p    = __expf(s - mnew);
    float psum = p;
    for (int d = 1; d < 64; d <<= 1) psum += __shfl_xor(psum, d);
    lsum = lsum * esc + psum;
    o   *= esc;
    m    = mnew;

    // ---- p -> wave-private LDS line, then uniform-address broadcast reads
    plds[w][lane] = p;
    float pv0 = 0.f, pv1 = 0.f, pv2 = 0.f, pv3 = 0.f;
#pragma unroll
    for (int q4 = 0; q4 < 16; q4++) {
      const f32x4 p4 = *(const f32x4*)&plds[w][q4 * 4];
      const unsigned short* Vp = Vh + (size_t)(c * 64 + q4 * 4) * HD + lane;
      pv0 += p4[0] * b2f(Vp[0 * HD]);
      pv1 += p4[1] * b2f(Vp[1 * HD]);
      pv2 += p4[2] * b2f(Vp[2 * HD]);
      pv3 += p4[3] * b2f(Vp[3 * HD]);
    }
    o += (pv0 + pv1) + (pv2 + pv3);
  }

  ctx[(size_t)qi * DM + h * HD + lane] = f2b(o / lsum);
}

// ---------------- global row: query 0 attends to ALL keys (row-major V) ------
__global__ __launch_bounds__(256)
void attn_global12(const unsigned short* __restrict__ qb,
                   const unsigned short* __restrict__ kb,
                   const unsigned short* __restrict__ vb,
                   unsigned short* __restrict__ ctx)
{
  __shared__ float sc[SEQ];
  __shared__ float q0[HD];
  __shared__ float red[4];
  __shared__ float accl[4][HD];
  const int t = threadIdx.x;
  const int h = blockIdx.x;
  const unsigned short* Qh = qb + (size_t)h * SEQ * HD;
  const unsigned short* Kh = kb + (size_t)h * SEQ * HD;
  const unsigned short* Vh = vb + (size_t)h * SEQ * HD;

  if (t < HD) q0[t] = b2f(Qh[t]);   // pre-scaled by 1/8
  __syncthreads();

  for (int j = t; j < SEQ; j += 256) {
    const unsigned short* Kp = Kh + (size_t)j * HD;
    float a0 = 0.f, a1 = 0.f;
    for (int d0 = 0; d0 < 8; d0++) {
      const bf16x8 kv = *(const bf16x8*)(Kp + d0 * 8);
#pragma unroll
      for (int e = 0; e < 8; e += 2) {
        a0 += q0[d0 * 8 + e]     * b2f((unsigned short)kv[e]);
        a1 += q0[d0 * 8 + e + 1] * b2f((unsigned short)kv[e + 1]);
      }
    }
    sc[j] = a0 + a1;
  }
  __syncthreads();

  float mx = -1e30f;
  for (int j = t; j < SEQ; j += 256) mx = fmaxf(mx, sc[j]);
  for (int d = 1; d < 64; d <<= 1) mx = fmaxf(mx, __shfl_xor(mx, d));
  if ((t & 63) == 0) red[t >> 6] = mx;
  __syncthreads();
  mx = fmaxf(fmaxf(red[0], red[1]), fmaxf(red[2], red[3]));
  __syncthreads();

  float sum = 0.f;
  for (int j = t; j < SEQ; j += 256) {
    const float p = __expf(sc[j] - mx);
    sc[j] = p;
    sum += p;
  }
  for (int d = 1; d < 64; d <<= 1) sum += __shfl_xor(sum, d);
  __syncthreads();
  if ((t & 63) == 0) red[t >> 6] = sum;
  __syncthreads();
  const float inv = 1.f / (red[0] + red[1] + red[2] + red[3]);

  const int dd = t & 63, part = t >> 6;
  float a0 = 0.f, a1 = 0.f, a2 = 0.f, a3 = 0.f;
  const int jb = part * 1024;
  for (int j = 0; j < 1024; j += 4) {
    a0 += sc[jb + j + 0] * b2f(Vh[(size_t)(jb + j + 0) * HD + dd]);
    a1 += sc[jb + j + 1] * b2f(Vh[(size_t)(jb + j + 1) * HD + dd]);
    a2 += sc[jb + j + 2] * b2f(Vh[(size_t)(jb + j + 2) * HD + dd]);
    a3 += sc[jb + j + 3] * b2f(Vh[(size_t)(jb + j + 3) * HD + dd]);
  }
  accl[part][dd] = (a0 + a1) + (a2 + a3);
  __syncthreads();
  if (part == 0) {
    const float v = (accl[0][dd] + accl[1][dd] + accl[2][dd] + accl[3][dd]) * inv;
    ctx[(size_t)h * HD + dd] = f2b(v);   // row 0
  }
}

// ---------------- launch ----------------
extern "C" void kernel_launch(void* const* d_in, const int* in_sizes, int n_in,
                              void* d_out, int out_size, void* d_ws, size_t ws_size,
                              hipStream_t stream)
{
  (void)in_sizes; (void)n_in; (void)out_size; (void)ws_size;
  const float* x  = (const float*)d_in[0];
  const float* Wq = (const float*)d_in[1];
  const float* bq = (const float*)d_in[2];
  const float* Wk = (const float*)d_in[3];
  const float* bk = (const float*)d_in[4];
  const float* Wv = (const float*)d_in[5];
  const float* bv = (const float*)d_in[6];
  const float* Wo = (const float*)d_in[7];
  const float* bo = (const float*)d_in[8];
  float* out = (float*)d_out;

  char* ws = (char*)d_ws;
  unsigned short* xb   = (unsigned short*)(ws + 0);         // dead after gemm<0>
  unsigned short* wqkv = (unsigned short*)(ws + 6291456);
  unsigned short* wob  = (unsigned short*)(ws + 9830400);
  unsigned short* qbuf = (unsigned short*)(ws + 11010048);  // [12][4096][64]
  unsigned short* kbuf = (unsigned short*)(ws + 17301504);  // [12][4096][64]
  unsigned short* vbuf = (unsigned short*)(ws + 23592960);  // [12][4096][64]
  unsigned short* ctx  = (unsigned short*)(ws + 0);         // aliases xb (safe)

  convert_all<<<dim3(1024), dim3(256), 0, stream>>>(x, Wq, Wk, Wv, Wo, xb, wqkv, wob);
  gemm_bt<0><<<dim3(18, 32), dim3(256), 0, stream>>>(xb, wqkv, qbuf, kbuf, vbuf,
                                                     bq, bk, bv, nullptr, nullptr);
  attn_band2<<<dim3(SEQ / 4, NH), dim3(256), 0, stream>>>(qbuf, kbuf, vbuf, ctx);
  attn_global12<<<dim3(NH), dim3(256), 0, stream>>>(qbuf, kbuf, vbuf, ctx);
  gemm_bt<1><<<dim3(6, 32), dim3(256), 0, stream>>>(ctx, wob, nullptr, nullptr, nullptr,
                                                    nullptr, nullptr, nullptr, bo, out);
}

// Round 13
// 511.851 us; speedup vs baseline: 18.7740x; 1.4519x over previous
//
#include <hip/hip_runtime.h>
#include <cstdint>

#define SEQ   4096
#define DM    768
#define NH    12
#define HD    64
#define KD    768

typedef float  f32x4  __attribute__((ext_vector_type(4)));
typedef short  bf16x8 __attribute__((ext_vector_type(8)));

typedef __attribute__((address_space(1))) const unsigned int gu32;
typedef __attribute__((address_space(3))) unsigned int lu32;

__device__ __forceinline__ unsigned short f2b(float f) {
  unsigned int u = __builtin_bit_cast(unsigned int, f);
  u += 0x7fffu + ((u >> 16) & 1u);
  return (unsigned short)(u >> 16);
}
__device__ __forceinline__ float b2f(unsigned short s) {
  return __builtin_bit_cast(float, ((unsigned int)s) << 16);
}

__device__ __forceinline__ void gload_lds16(const void* g, void* l) {
  gu32* gp = reinterpret_cast<gu32*>(reinterpret_cast<uintptr_t>(g));
  lu32* lp = reinterpret_cast<lu32*>(reinterpret_cast<uintptr_t>(l));
  __builtin_amdgcn_global_load_lds(gp, lp, 16, 0, 0);
}

// ---------------- pack/convert: f32 -> bf16 (R3-verified) ----------------
__global__ void convert_all(const float* __restrict__ x,
                            const float* __restrict__ wq,
                            const float* __restrict__ wk,
                            const float* __restrict__ wv,
                            const float* __restrict__ wo,
                            unsigned short* __restrict__ xb,
                            unsigned short* __restrict__ wqkv,
                            unsigned short* __restrict__ wob)
{
  const int XN = SEQ * DM;
  const int WN = DM * DM;
  const int total4 = (XN + 4 * WN) >> 2;
  for (int i = blockIdx.x * blockDim.x + threadIdx.x; i < total4;
       i += gridDim.x * blockDim.x) {
    const int base = i << 2;
    const float* src;
    unsigned short* dst;
    if (base < XN)                 { src = x  + base;               dst = xb   + base; }
    else if (base < XN + WN)       { src = wq + (base - XN);        dst = wqkv + (base - XN); }
    else if (base < XN + 2 * WN)   { src = wk + (base - XN - WN);   dst = wqkv + (base - XN); }
    else if (base < XN + 3 * WN)   { src = wv + (base - XN - 2*WN); dst = wqkv + (base - XN); }
    else                           { src = wo + (base - XN - 3*WN); dst = wob  + (base - XN - 3*WN); }
    const float4 v = *(const float4*)src;
    *(ushort4*)dst = make_ushort4(f2b(v.x), f2b(v.y), f2b(v.z), f2b(v.w));
  }
}

// ---------------- GEMM C = A[M,K] * B[N,K]^T (R3-verified) ----------------
template<int EPI>
__global__ __launch_bounds__(256, 2)
void gemm_bt(const unsigned short* __restrict__ A,
             const unsigned short* __restrict__ B,
             unsigned short* __restrict__ qb,
             unsigned short* __restrict__ kb,
             unsigned short* __restrict__ vb,
             const float* __restrict__ bq,
             const float* __restrict__ bk,
             const float* __restrict__ bv,
             const float* __restrict__ bo,
             float* __restrict__ outf)
{
  __shared__ __align__(16) unsigned short As[128 * 32];
  __shared__ __align__(16) unsigned short Bs[128 * 32];
  const int t  = threadIdx.x;
  const int w  = t >> 6;
  const int l  = t & 63;
  const int m0 = blockIdx.y * 128;
  const int n0 = blockIdx.x * 128;
  const int wr = (w >> 1) * 64;
  const int wc = (w & 1) * 64;
  const int lr = l & 15;
  const int lk = (l >> 4) * 8;

  const int row1 = t >> 2;
  const int row2 = row1 + 64;
  const int seg  = t & 3;

  f32x4 acc[4][4];
#pragma unroll
  for (int i = 0; i < 4; i++)
#pragma unroll
    for (int j = 0; j < 4; j++) acc[i][j] = (f32x4){0.f, 0.f, 0.f, 0.f};

  char* ldsA0 = (char*)As + (size_t)(w * 64) * 16;
  char* ldsA1 = (char*)As + (size_t)(w * 64 + 256) * 16;
  char* ldsB0 = (char*)Bs + (size_t)(w * 64) * 16;
  char* ldsB1 = (char*)Bs + (size_t)(w * 64 + 256) * 16;

  for (int k0 = 0; k0 < KD; k0 += 32) {
    gload_lds16(A + (size_t)(m0 + row1) * KD + k0 + seg * 8, ldsA0);
    gload_lds16(A + (size_t)(m0 + row2) * KD + k0 + seg * 8, ldsA1);
    gload_lds16(B + (size_t)(n0 + row1) * KD + k0 + seg * 8, ldsB0);
    gload_lds16(B + (size_t)(n0 + row2) * KD + k0 + seg * 8, ldsB1);
    __syncthreads();
    bf16x8 af[4], bfv[4];
#pragma unroll
    for (int fi = 0; fi < 4; fi++)
      af[fi] = *(const bf16x8*)(As + (wr + fi * 16 + lr) * 32 + lk);
#pragma unroll
    for (int fj = 0; fj < 4; fj++)
      bfv[fj] = *(const bf16x8*)(Bs + (wc + fj * 16 + lr) * 32 + lk);
#pragma unroll
    for (int fi = 0; fi < 4; fi++)
#pragma unroll
      for (int fj = 0; fj < 4; fj++)
        acc[fi][fj] = __builtin_amdgcn_mfma_f32_16x16x32_bf16(af[fi], bfv[fj], acc[fi][fj], 0, 0, 0);
    __syncthreads();
  }

#pragma unroll
  for (int fi = 0; fi < 4; fi++) {
    const int mbase = m0 + wr + fi * 16 + (l >> 4) * 4;
#pragma unroll
    for (int fj = 0; fj < 4; fj++) {
      const int n = n0 + wc + fj * 16 + lr;
      if (EPI == 1) {
        const float bb = bo[n];
#pragma unroll
        for (int r = 0; r < 4; r++)
          outf[(size_t)(mbase + r) * DM + n] = acc[fi][fj][r] + bb;
      } else if (n < DM) {                       // Q (scaled by 1/8)
        const int hh = n >> 6, dk = n & 63;
        const float bb = bq[n];
#pragma unroll
        for (int r = 0; r < 4; r++)
          qb[((size_t)hh * SEQ + mbase + r) * HD + dk] = f2b((acc[fi][fj][r] + bb) * 0.125f);
      } else if (n < 2 * DM) {                   // K row-major [h][s][dk]
        const int n2 = n - DM, hh = n2 >> 6, dk = n2 & 63;
        const float bb = bk[n2];
#pragma unroll
        for (int r = 0; r < 4; r++)
          kb[((size_t)hh * SEQ + mbase + r) * HD + dk] = f2b(acc[fi][fj][r] + bb);
      } else {                                   // V row-major [h][s][dk]
        const int n3 = n - 2 * DM, hh = n3 >> 6, dk = n3 & 63;
        const float bb = bv[n3];
#pragma unroll
        for (int r = 0; r < 4; r++)
          vb[((size_t)hh * SEQ + mbase + r) * HD + dk] = f2b(acc[fi][fj][r] + bb);
      }
    }
  }
}

// ---------------- standalone V transpose: [h][s][dk] -> [h][dk][s] (R4) ------
__global__ __launch_bounds__(256)
void transpose_v(const unsigned short* __restrict__ vb,
                 unsigned short* __restrict__ vt)
{
  __shared__ unsigned short tile[64][65];
  const int h  = blockIdx.y;
  const int s0 = blockIdx.x * 64;
  const int t  = threadIdx.x;
  const int tc = t & 63;
  const int t4 = t >> 6;
  const unsigned short* Vh  = vb + (size_t)h * SEQ * HD;
  unsigned short*       Vth = vt + (size_t)h * HD * SEQ;
#pragma unroll
  for (int rr = 0; rr < 64; rr += 4)
    tile[rr + t4][tc] = Vh[(size_t)(s0 + rr + t4) * HD + tc];
  __syncthreads();
#pragma unroll
  for (int rr = 0; rr < 64; rr += 4) {
    const int d = rr + t4;
    Vth[(size_t)d * SEQ + s0 + tc] = tile[tc][d];
  }
}

// ------ band attention: block-cooperative LDS-staged K/V^T, scalar math ------
// 4 queries per block (one per wave), union chunk list (chunk 0 first).
// Swizzle invariant: LDS row r, slot s holds global 16B-block (s ^ (r&7)).
// Read slot (d0 ^ (r&7)) -> contents block d0 -> pair with qf[d0*8] (R12 bug:
// paired with slot index instead of contents block).
// mask: valid(qi, j) = (qi==0) || (j==0) || |qi-j| <= 256
// Row 0 band-only here; attn_global12 overwrites it afterwards.
__global__ __launch_bounds__(256)
void attn_band3(const unsigned short* __restrict__ qb,
                const unsigned short* __restrict__ kb,
                const unsigned short* __restrict__ vt,
                unsigned short* __restrict__ ctx)
{
  __shared__ __align__(16) unsigned short Ks[64 * 64];
  __shared__ __align__(16) unsigned short Vts[64 * 64];
  __shared__ __align__(16) float plds[4][64];
  const int h    = blockIdx.y;
  const int B    = blockIdx.x;          // queries B*4 .. B*4+3
  const int t    = threadIdx.x;
  const int w    = t >> 6;
  const int lane = t & 63;
  const int qi   = B * 4 + w;

  const unsigned short* Qh  = qb + (size_t)h * SEQ * HD;
  const unsigned short* Kh  = kb + (size_t)h * SEQ * HD;
  const unsigned short* Vth = vt + (size_t)h * HD * SEQ;

  const int srow = t >> 3;
  const int scol = (t & 7) ^ (srow & 7);    // pre-swizzled source 16B-slot
  const int swz  = lane & 7;                // read-side XOR for row=lane

  // q row -> 64 f32 regs (uniform across lanes; q pre-scaled by 1/8)
  float qf[64];
#pragma unroll
  for (int d0 = 0; d0 < 8; d0++) {
    const bf16x8 qv = *(const bf16x8*)(Qh + (size_t)qi * HD + d0 * 8);
#pragma unroll
    for (int e = 0; e < 8; e++) qf[d0 * 8 + e] = b2f((unsigned short)qv[e]);
  }

  // union chunk range for the block's 4 queries
  int lo = B * 4 - 256; if (lo < 0) lo = 0;
  int hi = B * 4 + 3 + 257; if (hi > SEQ) hi = SEQ;
  const int cbeg = lo >> 6, cend = (hi - 1) >> 6;
  const int cfirst = (cbeg > 0) ? (cbeg - 1) : cbeg;   // chunk 0 first

  float o = 0.f, m = -1e30f, lsum = 0.f;

  for (int cc = cfirst; cc <= cend; cc++) {
    const int c  = (cc < cbeg) ? 0 : cc;
    const int j0 = c * 64;

    // ---- stage K[64][64] and V^T[64][64] (pre-swizzled source columns)
    {
      char* kd0 = (char*)Ks  + (size_t)(w * 64) * 16;
      char* kd1 = (char*)Ks  + (size_t)(w * 64 + 256) * 16;
      gload_lds16(Kh + (size_t)(j0 + srow) * HD + scol * 8, kd0);
      gload_lds16(Kh + (size_t)(j0 + 32 + srow) * HD + scol * 8, kd1);
      char* vd0 = (char*)Vts + (size_t)(w * 64) * 16;
      char* vd1 = (char*)Vts + (size_t)(w * 64 + 256) * 16;
      gload_lds16(Vth + (size_t)srow * SEQ + j0 + scol * 8, vd0);
      gload_lds16(Vth + (size_t)(32 + srow) * SEQ + j0 + scol * 8, vd1);
    }
    __syncthreads();

    // ---- s_j = q . k_j from LDS (lane = key j0+lane), 4-way ILP
    const unsigned short* Kp = Ks + lane * 64;
    float s0 = 0.f, s1 = 0.f, s2 = 0.f, s3 = 0.f;
#pragma unroll
    for (int d0 = 0; d0 < 8; d0++) {
      const bf16x8 kv = *(const bf16x8*)(Kp + ((d0 ^ swz) * 8));  // contents: block d0
      const int db = d0 * 8;                                      // FIX: contents index
      s0 += qf[db + 0] * b2f((unsigned short)kv[0]);
      s1 += qf[db + 1] * b2f((unsigned short)kv[1]);
      s2 += qf[db + 2] * b2f((unsigned short)kv[2]);
      s3 += qf[db + 3] * b2f((unsigned short)kv[3]);
      s0 += qf[db + 4] * b2f((unsigned short)kv[4]);
      s1 += qf[db + 5] * b2f((unsigned short)kv[5]);
      s2 += qf[db + 6] * b2f((unsigned short)kv[6]);
      s3 += qf[db + 7] * b2f((unsigned short)kv[7]);
    }
    float s = (s0 + s1) + (s2 + s3);
    const int j = j0 + lane;
    const bool valid = (qi == 0) || (j == 0) ||
                       ((j - qi) <= 256 && (qi - j) <= 256);
    s = valid ? s : -1e30f;

    // ---- wave-wide online softmax (R11-verified pattern)
    float mx = s;
    for (int d = 1; d < 64; d <<= 1) mx = fmaxf(mx, __shfl_xor(mx, d));
    const float mnew = fmaxf(m, mx);
    const float esc  = __expf(m - mnew);
    const float p    = __expf(s - mnew);
    float psum = p;
    for (int d = 1; d < 64; d <<= 1) psum += __shfl_xor(psum, d);
    lsum = lsum * esc + psum;
    o   *= esc;
    m    = mnew;

    // ---- p -> wave-private LDS; PV from V^T in LDS (lane = dim d)
    plds[w][lane] = p;
    const unsigned short* Vp = Vts + lane * 64;
    float pv0 = 0.f, pv1 = 0.f, pv2 = 0.f, pv3 = 0.f;
#pragma unroll
    for (int q8 = 0; q8 < 8; q8++) {
      const bf16x8 vv = *(const bf16x8*)(Vp + ((q8 ^ swz) * 8)); // contents: block q8
      const int jb = q8 * 8;                                     // FIX: contents index
      const f32x4 pa = *(const f32x4*)&plds[w][jb];
      const f32x4 pb = *(const f32x4*)&plds[w][jb + 4];
      pv0 += pa[0] * b2f((unsigned short)vv[0]);
      pv1 += pa[1] * b2f((unsigned short)vv[1]);
      pv2 += pa[2] * b2f((unsigned short)vv[2]);
      pv3 += pa[3] * b2f((unsigned short)vv[3]);
      pv0 += pb[0] * b2f((unsigned short)vv[4]);
      pv1 += pb[1] * b2f((unsigned short)vv[5]);
      pv2 += pb[2] * b2f((unsigned short)vv[6]);
      pv3 += pb[3] * b2f((unsigned short)vv[7]);
    }
    o += (pv0 + pv1) + (pv2 + pv3);

    __syncthreads();   // protect Ks/Vts before next chunk's staging
  }

  ctx[(size_t)qi * DM + h * HD + lane] = f2b(o / lsum);
}

// ---------------- global row: query 0 attends to ALL keys (row-major V) ------
__global__ __launch_bounds__(256)
void attn_global12(const unsigned short* __restrict__ qb,
                   const unsigned short* __restrict__ kb,
                   const unsigned short* __restrict__ vb,
                   unsigned short* __restrict__ ctx)
{
  __shared__ float sc[SEQ];
  __shared__ float q0[HD];
  __shared__ float red[4];
  __shared__ float accl[4][HD];
  const int t = threadIdx.x;
  const int h = blockIdx.x;
  const unsigned short* Qh = qb + (size_t)h * SEQ * HD;
  const unsigned short* Kh = kb + (size_t)h * SEQ * HD;
  const unsigned short* Vh = vb + (size_t)h * SEQ * HD;

  if (t < HD) q0[t] = b2f(Qh[t]);   // pre-scaled by 1/8
  __syncthreads();

  for (int j = t; j < SEQ; j += 256) {
    const unsigned short* Kp = Kh + (size_t)j * HD;
    float a0 = 0.f, a1 = 0.f;
    for (int d0 = 0; d0 < 8; d0++) {
      const bf16x8 kv = *(const bf16x8*)(Kp + d0 * 8);
#pragma unroll
      for (int e = 0; e < 8; e += 2) {
        a0 += q0[d0 * 8 + e]     * b2f((unsigned short)kv[e]);
        a1 += q0[d0 * 8 + e + 1] * b2f((unsigned short)kv[e + 1]);
      }
    }
    sc[j] = a0 + a1;
  }
  __syncthreads();

  float mx = -1e30f;
  for (int j = t; j < SEQ; j += 256) mx = fmaxf(mx, sc[j]);
  for (int d = 1; d < 64; d <<= 1) mx = fmaxf(mx, __shfl_xor(mx, d));
  if ((t & 63) == 0) red[t >> 6] = mx;
  __syncthreads();
  mx = fmaxf(fmaxf(red[0], red[1]), fmaxf(red[2], red[3]));
  __syncthreads();

  float sum = 0.f;
  for (int j = t; j < SEQ; j += 256) {
    const float p = __expf(sc[j] - mx);
    sc[j] = p;
    sum += p;
  }
  for (int d = 1; d < 64; d <<= 1) sum += __shfl_xor(sum, d);
  __syncthreads();
  if ((t & 63) == 0) red[t >> 6] = sum;
  __syncthreads();
  const float inv = 1.f / (red[0] + red[1] + red[2] + red[3]);

  const int dd = t & 63, part = t >> 6;
  float a0 = 0.f, a1 = 0.f, a2 = 0.f, a3 = 0.f;
  const int jb = part * 1024;
  for (int j = 0; j < 1024; j += 4) {
    a0 += sc[jb + j + 0] * b2f(Vh[(size_t)(jb + j + 0) * HD + dd]);
    a1 += sc[jb + j + 1] * b2f(Vh[(size_t)(jb + j + 1) * HD + dd]);
    a2 += sc[jb + j + 2] * b2f(Vh[(size_t)(jb + j + 2) * HD + dd]);
    a3 += sc[jb + j + 3] * b2f(Vh[(size_t)(jb + j + 3) * HD + dd]);
  }
  accl[part][dd] = (a0 + a1) + (a2 + a3);
  __syncthreads();
  if (part == 0) {
    const float v = (accl[0][dd] + accl[1][dd] + accl[2][dd] + accl[3][dd]) * inv;
    ctx[(size_t)h * HD + dd] = f2b(v);   // row 0
  }
}

// ---------------- launch ----------------
extern "C" void kernel_launch(void* const* d_in, const int* in_sizes, int n_in,
                              void* d_out, int out_size, void* d_ws, size_t ws_size,
                              hipStream_t stream)
{
  (void)in_sizes; (void)n_in; (void)out_size; (void)ws_size;
  const float* x  = (const float*)d_in[0];
  const float* Wq = (const float*)d_in[1];
  const float* bq = (const float*)d_in[2];
  const float* Wk = (const float*)d_in[3];
  const float* bk = (const float*)d_in[4];
  const float* Wv = (const float*)d_in[5];
  const float* bv = (const float*)d_in[6];
  const float* Wo = (const float*)d_in[7];
  const float* bo = (const float*)d_in[8];
  float* out = (float*)d_out;

  char* ws = (char*)d_ws;
  unsigned short* xb   = (unsigned short*)(ws + 0);         // dead after gemm<0>
  unsigned short* wqkv = (unsigned short*)(ws + 6291456);
  unsigned short* wob  = (unsigned short*)(ws + 9830400);
  unsigned short* qbuf = (unsigned short*)(ws + 11010048);  // [12][4096][64]
  unsigned short* kbuf = (unsigned short*)(ws + 17301504);  // [12][4096][64]
  unsigned short* vbuf = (unsigned short*)(ws + 23592960);  // [12][4096][64]
  unsigned short* vtb  = (unsigned short*)(ws + 29884416);  // [12][64][4096]
  unsigned short* ctx  = (unsigned short*)(ws + 0);         // aliases xb (safe)

  convert_all<<<dim3(1024), dim3(256), 0, stream>>>(x, Wq, Wk, Wv, Wo, xb, wqkv, wob);
  gemm_bt<0><<<dim3(18, 32), dim3(256), 0, stream>>>(xb, wqkv, qbuf, kbuf, vbuf,
                                                     bq, bk, bv, nullptr, nullptr);
  transpose_v<<<dim3(SEQ / 64, NH), dim3(256), 0, stream>>>(vbuf, vtb);
  attn_band3<<<dim3(SEQ / 4, NH), dim3(256), 0, stream>>>(qbuf, kbuf, vtb, ctx);
  attn_global12<<<dim3(NH), dim3(256), 0, stream>>>(qbuf, kbuf, vbuf, ctx);
  gemm_bt<1><<<dim3(6, 32), dim3(256), 0, stream>>>(ctx, wob, nullptr, nullptr, nullptr,
                                                    nullptr, nullptr, nullptr, bo, out);
}

// Round 14
// 418.492 us; speedup vs baseline: 22.9622x; 1.2231x over previous
//
#include <hip/hip_runtime.h>
#include <cstdint>

#define SEQ   4096
#define DM    768
#define NH    12
#define HD    64
#define KD    768

typedef float  f32x4  __attribute__((ext_vector_type(4)));
typedef short  bf16x8 __attribute__((ext_vector_type(8)));

typedef __attribute__((address_space(1))) const unsigned int gu32;
typedef __attribute__((address_space(3))) unsigned int lu32;

__device__ __forceinline__ unsigned short f2b(float f) {
  unsigned int u = __builtin_bit_cast(unsigned int, f);
  u += 0x7fffu + ((u >> 16) & 1u);
  return (unsigned short)(u >> 16);
}
__device__ __forceinline__ float b2f(unsigned short s) {
  return __builtin_bit_cast(float, ((unsigned int)s) << 16);
}

__device__ __forceinline__ void gload_lds16(const void* g, void* l) {
  gu32* gp = reinterpret_cast<gu32*>(reinterpret_cast<uintptr_t>(g));
  lu32* lp = reinterpret_cast<lu32*>(reinterpret_cast<uintptr_t>(l));
  __builtin_amdgcn_global_load_lds(gp, lp, 16, 0, 0);
}

// ---------------- pack/convert: f32 -> bf16 (R3-verified) ----------------
__global__ void convert_all(const float* __restrict__ x,
                            const float* __restrict__ wq,
                            const float* __restrict__ wk,
                            const float* __restrict__ wv,
                            const float* __restrict__ wo,
                            unsigned short* __restrict__ xb,
                            unsigned short* __restrict__ wqkv,
                            unsigned short* __restrict__ wob)
{
  const int XN = SEQ * DM;
  const int WN = DM * DM;
  const int total4 = (XN + 4 * WN) >> 2;
  for (int i = blockIdx.x * blockDim.x + threadIdx.x; i < total4;
       i += gridDim.x * blockDim.x) {
    const int base = i << 2;
    const float* src;
    unsigned short* dst;
    if (base < XN)                 { src = x  + base;               dst = xb   + base; }
    else if (base < XN + WN)       { src = wq + (base - XN);        dst = wqkv + (base - XN); }
    else if (base < XN + 2 * WN)   { src = wk + (base - XN - WN);   dst = wqkv + (base - XN); }
    else if (base < XN + 3 * WN)   { src = wv + (base - XN - 2*WN); dst = wqkv + (base - XN); }
    else                           { src = wo + (base - XN - 3*WN); dst = wob  + (base - XN - 3*WN); }
    const float4 v = *(const float4*)src;
    *(ushort4*)dst = make_ushort4(f2b(v.x), f2b(v.y), f2b(v.z), f2b(v.w));
  }
}

// ---------------- GEMM C = A[M,K] * B[N,K]^T (R3-verified) ----------------
template<int EPI>
__global__ __launch_bounds__(256, 2)
void gemm_bt(const unsigned short* __restrict__ A,
             const unsigned short* __restrict__ B,
             unsigned short* __restrict__ qb,
             unsigned short* __restrict__ kb,
             unsigned short* __restrict__ vb,
             const float* __restrict__ bq,
             const float* __restrict__ bk,
             const float* __restrict__ bv,
             const float* __restrict__ bo,
             float* __restrict__ outf)
{
  __shared__ __align__(16) unsigned short As[128 * 32];
  __shared__ __align__(16) unsigned short Bs[128 * 32];
  const int t  = threadIdx.x;
  const int w  = t >> 6;
  const int l  = t & 63;
  const int m0 = blockIdx.y * 128;
  const int n0 = blockIdx.x * 128;
  const int wr = (w >> 1) * 64;
  const int wc = (w & 1) * 64;
  const int lr = l & 15;
  const int lk = (l >> 4) * 8;

  const int row1 = t >> 2;
  const int row2 = row1 + 64;
  const int seg  = t & 3;

  f32x4 acc[4][4];
#pragma unroll
  for (int i = 0; i < 4; i++)
#pragma unroll
    for (int j = 0; j < 4; j++) acc[i][j] = (f32x4){0.f, 0.f, 0.f, 0.f};

  char* ldsA0 = (char*)As + (size_t)(w * 64) * 16;
  char* ldsA1 = (char*)As + (size_t)(w * 64 + 256) * 16;
  char* ldsB0 = (char*)Bs + (size_t)(w * 64) * 16;
  char* ldsB1 = (char*)Bs + (size_t)(w * 64 + 256) * 16;

  for (int k0 = 0; k0 < KD; k0 += 32) {
    gload_lds16(A + (size_t)(m0 + row1) * KD + k0 + seg * 8, ldsA0);
    gload_lds16(A + (size_t)(m0 + row2) * KD + k0 + seg * 8, ldsA1);
    gload_lds16(B + (size_t)(n0 + row1) * KD + k0 + seg * 8, ldsB0);
    gload_lds16(B + (size_t)(n0 + row2) * KD + k0 + seg * 8, ldsB1);
    __syncthreads();
    bf16x8 af[4], bfv[4];
#pragma unroll
    for (int fi = 0; fi < 4; fi++)
      af[fi] = *(const bf16x8*)(As + (wr + fi * 16 + lr) * 32 + lk);
#pragma unroll
    for (int fj = 0; fj < 4; fj++)
      bfv[fj] = *(const bf16x8*)(Bs + (wc + fj * 16 + lr) * 32 + lk);
#pragma unroll
    for (int fi = 0; fi < 4; fi++)
#pragma unroll
      for (int fj = 0; fj < 4; fj++)
        acc[fi][fj] = __builtin_amdgcn_mfma_f32_16x16x32_bf16(af[fi], bfv[fj], acc[fi][fj], 0, 0, 0);
    __syncthreads();
  }

#pragma unroll
  for (int fi = 0; fi < 4; fi++) {
    const int mbase = m0 + wr + fi * 16 + (l >> 4) * 4;
#pragma unroll
    for (int fj = 0; fj < 4; fj++) {
      const int n = n0 + wc + fj * 16 + lr;
      if (EPI == 1) {
        const float bb = bo[n];
#pragma unroll
        for (int r = 0; r < 4; r++)
          outf[(size_t)(mbase + r) * DM + n] = acc[fi][fj][r] + bb;
      } else if (n < DM) {                       // Q (scaled by 1/8)
        const int hh = n >> 6, dk = n & 63;
        const float bb = bq[n];
#pragma unroll
        for (int r = 0; r < 4; r++)
          qb[((size_t)hh * SEQ + mbase + r) * HD + dk] = f2b((acc[fi][fj][r] + bb) * 0.125f);
      } else if (n < 2 * DM) {                   // K row-major [h][s][dk]
        const int n2 = n - DM, hh = n2 >> 6, dk = n2 & 63;
        const float bb = bk[n2];
#pragma unroll
        for (int r = 0; r < 4; r++)
          kb[((size_t)hh * SEQ + mbase + r) * HD + dk] = f2b(acc[fi][fj][r] + bb);
      } else {                                   // V row-major [h][s][dk]
        const int n3 = n - 2 * DM, hh = n3 >> 6, dk = n3 & 63;
        const float bb = bv[n3];
#pragma unroll
        for (int r = 0; r < 4; r++)
          vb[((size_t)hh * SEQ + mbase + r) * HD + dk] = f2b(acc[fi][fj][r] + bb);
      }
    }
  }
}

// ---------------- standalone V transpose: [h][s][dk] -> [h][dk][s] (R4) ------
__global__ __launch_bounds__(256)
void transpose_v(const unsigned short* __restrict__ vb,
                 unsigned short* __restrict__ vt)
{
  __shared__ unsigned short tile[64][65];
  const int h  = blockIdx.y;
  const int s0 = blockIdx.x * 64;
  const int t  = threadIdx.x;
  const int tc = t & 63;
  const int t4 = t >> 6;
  const unsigned short* Vh  = vb + (size_t)h * SEQ * HD;
  unsigned short*       Vth = vt + (size_t)h * HD * SEQ;
#pragma unroll
  for (int rr = 0; rr < 64; rr += 4)
    tile[rr + t4][tc] = Vh[(size_t)(s0 + rr + t4) * HD + tc];
  __syncthreads();
#pragma unroll
  for (int rr = 0; rr < 64; rr += 4) {
    const int d = rr + t4;
    Vth[(size_t)d * SEQ + s0 + tc] = tile[tc][d];
  }
}

// ------ band attention: double-buffered LDS K/V^T prefetch, scalar math ------
// 4 queries per block (one per wave), union chunk list (chunk 0 first).
// 2-phase pipeline: stage(chunk it+1 -> buf^1) BEFORE compute(chunk it, buf),
// ONE barrier per chunk (drains prefetch + protects buffer reuse).
// Swizzle invariant (R13-verified): LDS row r slot s holds global block s^(r&7).
// mask: valid(qi, j) = (qi==0) || (j==0) || |qi-j| <= 256
// Row 0 band-only here; attn_global12 overwrites it afterwards.
__global__ __launch_bounds__(256)
void attn_band4(const unsigned short* __restrict__ qb,
                const unsigned short* __restrict__ kb,
                const unsigned short* __restrict__ vt,
                unsigned short* __restrict__ ctx)
{
  __shared__ __align__(16) unsigned short Ks[2][64 * 64];
  __shared__ __align__(16) unsigned short Vts[2][64 * 64];
  __shared__ __align__(16) float plds[4][64];
  const int h    = blockIdx.y;
  const int B    = blockIdx.x;          // queries B*4 .. B*4+3
  const int t    = threadIdx.x;
  const int w    = t >> 6;
  const int lane = t & 63;
  const int qi   = B * 4 + w;

  const unsigned short* Qh  = qb + (size_t)h * SEQ * HD;
  const unsigned short* Kh  = kb + (size_t)h * SEQ * HD;
  const unsigned short* Vth = vt + (size_t)h * HD * SEQ;

  const int srow = t >> 3;
  const int scol = (t & 7) ^ (srow & 7);    // pre-swizzled source 16B-slot
  const int swz  = lane & 7;                // read-side XOR for row=lane

  // q row -> 64 f32 regs (uniform across lanes; q pre-scaled by 1/8)
  float qf[64];
#pragma unroll
  for (int d0 = 0; d0 < 8; d0++) {
    const bf16x8 qv = *(const bf16x8*)(Qh + (size_t)qi * HD + d0 * 8);
#pragma unroll
    for (int e = 0; e < 8; e++) qf[d0 * 8 + e] = b2f((unsigned short)qv[e]);
  }

  // union chunk range for the block's 4 queries; chunk 0 prepended if absent
  int lo = B * 4 - 256; if (lo < 0) lo = 0;
  int hi = B * 4 + 3 + 257; if (hi > SEQ) hi = SEQ;
  const int cbeg = lo >> 6, cend = (hi - 1) >> 6;
  const int pre  = (cbeg > 0) ? 1 : 0;
  const int nch  = cend - cbeg + 1 + pre;

  auto chunkof = [&](int it) -> int {
    return (pre && it == 0) ? 0 : (cbeg + it - pre);
  };
  auto stage = [&](int bsel, int cch) {
    const int jj0 = cch * 64;
    char* kbase = (char*)(&Ks[bsel][0]);
    char* vbase = (char*)(&Vts[bsel][0]);
    gload_lds16(Kh + (size_t)(jj0 + srow) * HD + scol * 8,
                kbase + (size_t)(w * 64) * 16);
    gload_lds16(Kh + (size_t)(jj0 + 32 + srow) * HD + scol * 8,
                kbase + (size_t)(w * 64 + 256) * 16);
    gload_lds16(Vth + (size_t)srow * SEQ + jj0 + scol * 8,
                vbase + (size_t)(w * 64) * 16);
    gload_lds16(Vth + (size_t)(32 + srow) * SEQ + jj0 + scol * 8,
                vbase + (size_t)(w * 64 + 256) * 16);
  };

  stage(0, chunkof(0));
  __syncthreads();

  float o = 0.f, m = -1e30f, lsum = 0.f;

  for (int it = 0; it < nch; ++it) {
    if (it + 1 < nch) stage((it + 1) & 1, chunkof(it + 1));  // async prefetch

    const int c  = chunkof(it);
    const int j0 = c * 64;
    const unsigned short* Kp = &Ks[it & 1][0] + lane * 64;
    const unsigned short* Vp = &Vts[it & 1][0] + lane * 64;

    // ---- s_j = q . k_j from LDS (lane = key j0+lane), 4-way ILP
    float s0 = 0.f, s1 = 0.f, s2 = 0.f, s3 = 0.f;
#pragma unroll
    for (int d0 = 0; d0 < 8; d0++) {
      const bf16x8 kv = *(const bf16x8*)(Kp + ((d0 ^ swz) * 8));  // contents: block d0
      const int db = d0 * 8;
      s0 += qf[db + 0] * b2f((unsigned short)kv[0]);
      s1 += qf[db + 1] * b2f((unsigned short)kv[1]);
      s2 += qf[db + 2] * b2f((unsigned short)kv[2]);
      s3 += qf[db + 3] * b2f((unsigned short)kv[3]);
      s0 += qf[db + 4] * b2f((unsigned short)kv[4]);
      s1 += qf[db + 5] * b2f((unsigned short)kv[5]);
      s2 += qf[db + 6] * b2f((unsigned short)kv[6]);
      s3 += qf[db + 7] * b2f((unsigned short)kv[7]);
    }
    float s = (s0 + s1) + (s2 + s3);
    const int j = j0 + lane;
    const bool valid = (qi == 0) || (j == 0) ||
                       ((j - qi) <= 256 && (qi - j) <= 256);
    s = valid ? s : -1e30f;

    // ---- wave-wide online softmax (R13-verified pattern)
    float mx = s;
    for (int d = 1; d < 64; d <<= 1) mx = fmaxf(mx, __shfl_xor(mx, d));
    const float mnew = fmaxf(m, mx);
    const float esc  = __expf(m - mnew);
    const float p    = __expf(s - mnew);
    float psum = p;
    for (int d = 1; d < 64; d <<= 1) psum += __shfl_xor(psum, d);
    lsum = lsum * esc + psum;
    o   *= esc;
    m    = mnew;

    // ---- p -> wave-private LDS; PV from V^T in LDS (lane = dim d)
    plds[w][lane] = p;
    float pv0 = 0.f, pv1 = 0.f, pv2 = 0.f, pv3 = 0.f;
#pragma unroll
    for (int q8 = 0; q8 < 8; q8++) {
      const bf16x8 vv = *(const bf16x8*)(Vp + ((q8 ^ swz) * 8)); // contents: block q8
      const int jb = q8 * 8;
      const f32x4 pa = *(const f32x4*)&plds[w][jb];
      const f32x4 pb = *(const f32x4*)&plds[w][jb + 4];
      pv0 += pa[0] * b2f((unsigned short)vv[0]);
      pv1 += pa[1] * b2f((unsigned short)vv[1]);
      pv2 += pa[2] * b2f((unsigned short)vv[2]);
      pv3 += pa[3] * b2f((unsigned short)vv[3]);
      pv0 += pb[0] * b2f((unsigned short)vv[4]);
      pv1 += pb[1] * b2f((unsigned short)vv[5]);
      pv2 += pb[2] * b2f((unsigned short)vv[6]);
      pv3 += pb[3] * b2f((unsigned short)vv[7]);
    }
    o += (pv0 + pv1) + (pv2 + pv3);

    __syncthreads();   // prefetch landed + all waves done with buf[it&1]
  }

  ctx[(size_t)qi * DM + h * HD + lane] = f2b(o / lsum);
}

// ---------------- global row: query 0 attends to ALL keys (row-major V) ------
__global__ __launch_bounds__(256)
void attn_global12(const unsigned short* __restrict__ qb,
                   const unsigned short* __restrict__ kb,
                   const unsigned short* __restrict__ vb,
                   unsigned short* __restrict__ ctx)
{
  __shared__ float sc[SEQ];
  __shared__ float q0[HD];
  __shared__ float red[4];
  __shared__ float accl[4][HD];
  const int t = threadIdx.x;
  const int h = blockIdx.x;
  const unsigned short* Qh = qb + (size_t)h * SEQ * HD;
  const unsigned short* Kh = kb + (size_t)h * SEQ * HD;
  const unsigned short* Vh = vb + (size_t)h * SEQ * HD;

  if (t < HD) q0[t] = b2f(Qh[t]);   // pre-scaled by 1/8
  __syncthreads();

  for (int j = t; j < SEQ; j += 256) {
    const unsigned short* Kp = Kh + (size_t)j * HD;
    float a0 = 0.f, a1 = 0.f;
    for (int d0 = 0; d0 < 8; d0++) {
      const bf16x8 kv = *(const bf16x8*)(Kp + d0 * 8);
#pragma unroll
      for (int e = 0; e < 8; e += 2) {
        a0 += q0[d0 * 8 + e]     * b2f((unsigned short)kv[e]);
        a1 += q0[d0 * 8 + e + 1] * b2f((unsigned short)kv[e + 1]);
      }
    }
    sc[j] = a0 + a1;
  }
  __syncthreads();

  float mx = -1e30f;
  for (int j = t; j < SEQ; j += 256) mx = fmaxf(mx, sc[j]);
  for (int d = 1; d < 64; d <<= 1) mx = fmaxf(mx, __shfl_xor(mx, d));
  if ((t & 63) == 0) red[t >> 6] = mx;
  __syncthreads();
  mx = fmaxf(fmaxf(red[0], red[1]), fmaxf(red[2], red[3]));
  __syncthreads();

  float sum = 0.f;
  for (int j = t; j < SEQ; j += 256) {
    const float p = __expf(sc[j] - mx);
    sc[j] = p;
    sum += p;
  }
  for (int d = 1; d < 64; d <<= 1) sum += __shfl_xor(sum, d);
  __syncthreads();
  if ((t & 63) == 0) red[t >> 6] = sum;
  __syncthreads();
  const float inv = 1.f / (red[0] + red[1] + red[2] + red[3]);

  const int dd = t & 63, part = t >> 6;
  float a0 = 0.f, a1 = 0.f, a2 = 0.f, a3 = 0.f;
  const int jb = part * 1024;
  for (int j = 0; j < 1024; j += 4) {
    a0 += sc[jb + j + 0] * b2f(Vh[(size_t)(jb + j + 0) * HD + dd]);
    a1 += sc[jb + j + 1] * b2f(Vh[(size_t)(jb + j + 1) * HD + dd]);
    a2 += sc[jb + j + 2] * b2f(Vh[(size_t)(jb + j + 2) * HD + dd]);
    a3 += sc[jb + j + 3] * b2f(Vh[(size_t)(jb + j + 3) * HD + dd]);
  }
  accl[part][dd] = (a0 + a1) + (a2 + a3);
  __syncthreads();
  if (part == 0) {
    const float v = (accl[0][dd] + accl[1][dd] + accl[2][dd] + accl[3][dd]) * inv;
    ctx[(size_t)h * HD + dd] = f2b(v);   // row 0
  }
}

// ---------------- launch ----------------
extern "C" void kernel_launch(void* const* d_in, const int* in_sizes, int n_in,
                              void* d_out, int out_size, void* d_ws, size_t ws_size,
                              hipStream_t stream)
{
  (void)in_sizes; (void)n_in; (void)out_size; (void)ws_size;
  const float* x  = (const float*)d_in[0];
  const float* Wq = (const float*)d_in[1];
  const float* bq = (const float*)d_in[2];
  const float* Wk = (const float*)d_in[3];
  const float* bk = (const float*)d_in[4];
  const float* Wv = (const float*)d_in[5];
  const float* bv = (const float*)d_in[6];
  const float* Wo = (const float*)d_in[7];
  const float* bo = (const float*)d_in[8];
  float* out = (float*)d_out;

  char* ws = (char*)d_ws;
  unsigned short* xb   = (unsigned short*)(ws + 0);         // dead after gemm<0>
  unsigned short* wqkv = (unsigned short*)(ws + 6291456);
  unsigned short* wob  = (unsigned short*)(ws + 9830400);
  unsigned short* qbuf = (unsigned short*)(ws + 11010048);  // [12][4096][64]
  unsigned short* kbuf = (unsigned short*)(ws + 17301504);  // [12][4096][64]
  unsigned short* vbuf = (unsigned short*)(ws + 23592960);  // [12][4096][64]
  unsigned short* vtb  = (unsigned short*)(ws + 29884416);  // [12][64][4096]
  unsigned short* ctx  = (unsigned short*)(ws + 0);         // aliases xb (safe)

  convert_all<<<dim3(1024), dim3(256), 0, stream>>>(x, Wq, Wk, Wv, Wo, xb, wqkv, wob);
  gemm_bt<0><<<dim3(18, 32), dim3(256), 0, stream>>>(xb, wqkv, qbuf, kbuf, vbuf,
                                                     bq, bk, bv, nullptr, nullptr);
  transpose_v<<<dim3(SEQ / 64, NH), dim3(256), 0, stream>>>(vbuf, vtb);
  attn_band4<<<dim3(SEQ / 4, NH), dim3(256), 0, stream>>>(qbuf, kbuf, vtb, ctx);
  attn_global12<<<dim3(NH), dim3(256), 0, stream>>>(qbuf, kbuf, vbuf, ctx);
  gemm_bt<1><<<dim3(6, 32), dim3(256), 0, stream>>>(ctx, wob, nullptr, nullptr, nullptr,
                                                    nullptr, nullptr, nullptr, bo, out);
}

// Round 15
// 334.250 us; speedup vs baseline: 28.7494x; 1.2520x over previous
//
#include <hip/hip_runtime.h>
#include <cstdint>

#define SEQ   4096
#define DM    768
#define NH    12
#define HD    64
#define KD    768

typedef float  f32x4  __attribute__((ext_vector_type(4)));
typedef short  bf16x8 __attribute__((ext_vector_type(8)));
typedef _Float16 h16x2 __attribute__((ext_vector_type(2)));
typedef unsigned int u32;

typedef __attribute__((address_space(1))) const unsigned int gu32;
typedef __attribute__((address_space(3))) unsigned int lu32;

__device__ __forceinline__ unsigned short f2b(float f) {
  unsigned int u = __builtin_bit_cast(unsigned int, f);
  u += 0x7fffu + ((u >> 16) & 1u);
  return (unsigned short)(u >> 16);
}
__device__ __forceinline__ float b2f(unsigned short s) {
  return __builtin_bit_cast(float, ((unsigned int)s) << 16);
}
__device__ __forceinline__ unsigned short f2h(float f) {
  _Float16 h = (_Float16)f;
  return __builtin_bit_cast(unsigned short, h);
}
__device__ __forceinline__ float h2f(unsigned short s) {
  return (float)__builtin_bit_cast(_Float16, s);
}

// packed f16 dot2 with f32 accumulator (v_dot2_f32_f16); scalar fallback
__device__ __forceinline__ float dot2f(u32 a, u32 b, float c) {
#if __has_builtin(__builtin_amdgcn_fdot2)
  return __builtin_amdgcn_fdot2(__builtin_bit_cast(h16x2, a),
                                __builtin_bit_cast(h16x2, b), c, false);
#else
  const h16x2 ha = __builtin_bit_cast(h16x2, a);
  const h16x2 hb = __builtin_bit_cast(h16x2, b);
  return c + (float)ha[0] * (float)hb[0] + (float)ha[1] * (float)hb[1];
#endif
}

__device__ __forceinline__ void gload_lds16(const void* g, void* l) {
  gu32* gp = reinterpret_cast<gu32*>(reinterpret_cast<uintptr_t>(g));
  lu32* lp = reinterpret_cast<lu32*>(reinterpret_cast<uintptr_t>(l));
  __builtin_amdgcn_global_load_lds(gp, lp, 16, 0, 0);
}

// ---------------- pack/convert: f32 -> bf16 (R3-verified) ----------------
__global__ void convert_all(const float* __restrict__ x,
                            const float* __restrict__ wq,
                            const float* __restrict__ wk,
                            const float* __restrict__ wv,
                            const float* __restrict__ wo,
                            unsigned short* __restrict__ xb,
                            unsigned short* __restrict__ wqkv,
                            unsigned short* __restrict__ wob)
{
  const int XN = SEQ * DM;
  const int WN = DM * DM;
  const int total4 = (XN + 4 * WN) >> 2;
  for (int i = blockIdx.x * blockDim.x + threadIdx.x; i < total4;
       i += gridDim.x * blockDim.x) {
    const int base = i << 2;
    const float* src;
    unsigned short* dst;
    if (base < XN)                 { src = x  + base;               dst = xb   + base; }
    else if (base < XN + WN)       { src = wq + (base - XN);        dst = wqkv + (base - XN); }
    else if (base < XN + 2 * WN)   { src = wk + (base - XN - WN);   dst = wqkv + (base - XN); }
    else if (base < XN + 3 * WN)   { src = wv + (base - XN - 2*WN); dst = wqkv + (base - XN); }
    else                           { src = wo + (base - XN - 3*WN); dst = wob  + (base - XN - 3*WN); }
    const float4 v = *(const float4*)src;
    *(ushort4*)dst = make_ushort4(f2b(v.x), f2b(v.y), f2b(v.z), f2b(v.w));
  }
}

// ---------------- GEMM C = A[M,K] * B[N,K]^T (R3-verified, bf16 MFMA) --------
// EPI 0: Q/K/V epilogue now emits F16 (exact f32 acc -> f16, better than bf16)
template<int EPI>
__global__ __launch_bounds__(256, 2)
void gemm_bt(const unsigned short* __restrict__ A,
             const unsigned short* __restrict__ B,
             unsigned short* __restrict__ qb,
             unsigned short* __restrict__ kb,
             unsigned short* __restrict__ vb,
             const float* __restrict__ bq,
             const float* __restrict__ bk,
             const float* __restrict__ bv,
             const float* __restrict__ bo,
             float* __restrict__ outf)
{
  __shared__ __align__(16) unsigned short As[128 * 32];
  __shared__ __align__(16) unsigned short Bs[128 * 32];
  const int t  = threadIdx.x;
  const int w  = t >> 6;
  const int l  = t & 63;
  const int m0 = blockIdx.y * 128;
  const int n0 = blockIdx.x * 128;
  const int wr = (w >> 1) * 64;
  const int wc = (w & 1) * 64;
  const int lr = l & 15;
  const int lk = (l >> 4) * 8;

  const int row1 = t >> 2;
  const int row2 = row1 + 64;
  const int seg  = t & 3;

  f32x4 acc[4][4];
#pragma unroll
  for (int i = 0; i < 4; i++)
#pragma unroll
    for (int j = 0; j < 4; j++) acc[i][j] = (f32x4){0.f, 0.f, 0.f, 0.f};

  char* ldsA0 = (char*)As + (size_t)(w * 64) * 16;
  char* ldsA1 = (char*)As + (size_t)(w * 64 + 256) * 16;
  char* ldsB0 = (char*)Bs + (size_t)(w * 64) * 16;
  char* ldsB1 = (char*)Bs + (size_t)(w * 64 + 256) * 16;

  for (int k0 = 0; k0 < KD; k0 += 32) {
    gload_lds16(A + (size_t)(m0 + row1) * KD + k0 + seg * 8, ldsA0);
    gload_lds16(A + (size_t)(m0 + row2) * KD + k0 + seg * 8, ldsA1);
    gload_lds16(B + (size_t)(n0 + row1) * KD + k0 + seg * 8, ldsB0);
    gload_lds16(B + (size_t)(n0 + row2) * KD + k0 + seg * 8, ldsB1);
    __syncthreads();
    bf16x8 af[4], bfv[4];
#pragma unroll
    for (int fi = 0; fi < 4; fi++)
      af[fi] = *(const bf16x8*)(As + (wr + fi * 16 + lr) * 32 + lk);
#pragma unroll
    for (int fj = 0; fj < 4; fj++)
      bfv[fj] = *(const bf16x8*)(Bs + (wc + fj * 16 + lr) * 32 + lk);
#pragma unroll
    for (int fi = 0; fi < 4; fi++)
#pragma unroll
      for (int fj = 0; fj < 4; fj++)
        acc[fi][fj] = __builtin_amdgcn_mfma_f32_16x16x32_bf16(af[fi], bfv[fj], acc[fi][fj], 0, 0, 0);
    __syncthreads();
  }

#pragma unroll
  for (int fi = 0; fi < 4; fi++) {
    const int mbase = m0 + wr + fi * 16 + (l >> 4) * 4;
#pragma unroll
    for (int fj = 0; fj < 4; fj++) {
      const int n = n0 + wc + fj * 16 + lr;
      if (EPI == 1) {
        const float bb = bo[n];
#pragma unroll
        for (int r = 0; r < 4; r++)
          outf[(size_t)(mbase + r) * DM + n] = acc[fi][fj][r] + bb;
      } else if (n < DM) {                       // Q (scaled by 1/8) -> f16
        const int hh = n >> 6, dk = n & 63;
        const float bb = bq[n];
#pragma unroll
        for (int r = 0; r < 4; r++)
          qb[((size_t)hh * SEQ + mbase + r) * HD + dk] = f2h((acc[fi][fj][r] + bb) * 0.125f);
      } else if (n < 2 * DM) {                   // K row-major [h][s][dk] -> f16
        const int n2 = n - DM, hh = n2 >> 6, dk = n2 & 63;
        const float bb = bk[n2];
#pragma unroll
        for (int r = 0; r < 4; r++)
          kb[((size_t)hh * SEQ + mbase + r) * HD + dk] = f2h(acc[fi][fj][r] + bb);
      } else {                                   // V row-major [h][s][dk] -> f16
        const int n3 = n - 2 * DM, hh = n3 >> 6, dk = n3 & 63;
        const float bb = bv[n3];
#pragma unroll
        for (int r = 0; r < 4; r++)
          vb[((size_t)hh * SEQ + mbase + r) * HD + dk] = f2h(acc[fi][fj][r] + bb);
      }
    }
  }
}

// ---------------- standalone V transpose: [h][s][dk] -> [h][dk][s] (R4) ------
__global__ __launch_bounds__(256)
void transpose_v(const unsigned short* __restrict__ vb,
                 unsigned short* __restrict__ vt)
{
  __shared__ unsigned short tile[64][65];
  const int h  = blockIdx.y;
  const int s0 = blockIdx.x * 64;
  const int t  = threadIdx.x;
  const int tc = t & 63;
  const int t4 = t >> 6;
  const unsigned short* Vh  = vb + (size_t)h * SEQ * HD;
  unsigned short*       Vth = vt + (size_t)h * HD * SEQ;
#pragma unroll
  for (int rr = 0; rr < 64; rr += 4)
    tile[rr + t4][tc] = Vh[(size_t)(s0 + rr + t4) * HD + tc];
  __syncthreads();
#pragma unroll
  for (int rr = 0; rr < 64; rr += 4) {
    const int d = rr + t4;
    Vth[(size_t)d * SEQ + s0 + tc] = tile[tc][d];
  }
}

// ------ band attention: dbuf LDS K/V^T prefetch + f16 dot2 math --------------
// 4 queries per block (one per wave), union chunk list (chunk 0 first).
// Swizzle invariant (R13-verified): LDS row r slot s holds global block s^(r&7)
// -> read slot (i ^ (r&7)), pair with CONTENTS index i (R12 lesson).
// QK: dot2(K-pair along d, q-pair). PV: P as packed f16 in LDS; dot2 along j
// pairs matching V^T row layout. mask: valid = (qi==0)||(j==0)||(|qi-j|<=256).
// Row 0 band-only here; attn_global12 overwrites it afterwards.
__global__ __launch_bounds__(256)
void attn_band5(const unsigned short* __restrict__ qb,
                const unsigned short* __restrict__ kb,
                const unsigned short* __restrict__ vt,
                unsigned short* __restrict__ ctx)
{
  __shared__ __align__(16) unsigned short Ks[2][64 * 64];
  __shared__ __align__(16) unsigned short Vts[2][64 * 64];
  __shared__ __align__(16) unsigned short plds[4][64];   // P as f16
  const int h    = blockIdx.y;
  const int B    = blockIdx.x;          // queries B*4 .. B*4+3
  const int t    = threadIdx.x;
  const int w    = t >> 6;
  const int lane = t & 63;
  const int qi   = B * 4 + w;

  const unsigned short* Qh  = qb + (size_t)h * SEQ * HD;
  const unsigned short* Kh  = kb + (size_t)h * SEQ * HD;
  const unsigned short* Vth = vt + (size_t)h * HD * SEQ;

  const int srow = t >> 3;
  const int scol = (t & 7) ^ (srow & 7);    // pre-swizzled source 16B-slot
  const int swz  = lane & 7;                // read-side XOR for row=lane

  // q row (f16, pre-scaled by 1/8) -> 32 packed half2 regs
  h16x2 qp[32];
  {
    const u32* Qp32 = (const u32*)(Qh + (size_t)qi * HD);
#pragma unroll
    for (int i = 0; i < 32; i++) qp[i] = __builtin_bit_cast(h16x2, Qp32[i]);
  }

  // union chunk range for the block's 4 queries; chunk 0 prepended if absent
  int lo = B * 4 - 256; if (lo < 0) lo = 0;
  int hi = B * 4 + 3 + 257; if (hi > SEQ) hi = SEQ;
  const int cbeg = lo >> 6, cend = (hi - 1) >> 6;
  const int pre  = (cbeg > 0) ? 1 : 0;
  const int nch  = cend - cbeg + 1 + pre;

  auto chunkof = [&](int it) -> int {
    return (pre && it == 0) ? 0 : (cbeg + it - pre);
  };
  auto stage = [&](int bsel, int cch) {
    const int jj0 = cch * 64;
    char* kbase = (char*)(&Ks[bsel][0]);
    char* vbase = (char*)(&Vts[bsel][0]);
    gload_lds16(Kh + (size_t)(jj0 + srow) * HD + scol * 8,
                kbase + (size_t)(w * 64) * 16);
    gload_lds16(Kh + (size_t)(jj0 + 32 + srow) * HD + scol * 8,
                kbase + (size_t)(w * 64 + 256) * 16);
    gload_lds16(Vth + (size_t)srow * SEQ + jj0 + scol * 8,
                vbase + (size_t)(w * 64) * 16);
    gload_lds16(Vth + (size_t)(32 + srow) * SEQ + jj0 + scol * 8,
                vbase + (size_t)(w * 64 + 256) * 16);
  };

  stage(0, chunkof(0));
  __syncthreads();

  float o = 0.f, m = -1e30f, lsum = 0.f;

  for (int it = 0; it < nch; ++it) {
    if (it + 1 < nch) stage((it + 1) & 1, chunkof(it + 1));  // async prefetch

    const int c  = chunkof(it);
    const int j0 = c * 64;
    const unsigned short* Kp = &Ks[it & 1][0] + lane * 64;
    const unsigned short* Vp = &Vts[it & 1][0] + lane * 64;

    // ---- s_j = q . k_j : 32 packed dot2 (lane = key j0+lane)
    float s0 = 0.f, s1 = 0.f, s2 = 0.f, s3 = 0.f;
#pragma unroll
    for (int d0 = 0; d0 < 8; d0++) {
      const uint4 kv = *(const uint4*)(Kp + ((d0 ^ swz) * 8));  // contents: block d0
      const int qb4 = d0 * 4;                                   // contents index
      s0 = dot2f(kv.x, __builtin_bit_cast(u32, qp[qb4 + 0]), s0);
      s1 = dot2f(kv.y, __builtin_bit_cast(u32, qp[qb4 + 1]), s1);
      s2 = dot2f(kv.z, __builtin_bit_cast(u32, qp[qb4 + 2]), s2);
      s3 = dot2f(kv.w, __builtin_bit_cast(u32, qp[qb4 + 3]), s3);
    }
    float s = (s0 + s1) + (s2 + s3);
    const int j = j0 + lane;
    const bool valid = (qi == 0) || (j == 0) ||
                       ((j - qi) <= 256 && (qi - j) <= 256);
    s = valid ? s : -1e30f;

    // ---- wave-wide online softmax (R13-verified pattern)
    float mx = s;
    for (int d = 1; d < 64; d <<= 1) mx = fmaxf(mx, __shfl_xor(mx, d));
    const float mnew = fmaxf(m, mx);
    const float esc  = __expf(m - mnew);
    const float p    = __expf(s - mnew);
    float psum = p;
    for (int d = 1; d < 64; d <<= 1) psum += __shfl_xor(psum, d);
    lsum = lsum * esc + psum;
    o   *= esc;
    m    = mnew;

    // ---- p (f16) -> wave-private LDS; PV: 32 dot2 from V^T rows (lane = dim)
    plds[w][lane] = f2h(p);
    float pv0 = 0.f, pv1 = 0.f, pv2 = 0.f, pv3 = 0.f;
#pragma unroll
    for (int q8 = 0; q8 < 8; q8++) {
      const uint4 vv = *(const uint4*)(Vp + ((q8 ^ swz) * 8));  // contents: block q8
      const uint4 pq = *(const uint4*)&plds[w][q8 * 8];         // contents index
      pv0 = dot2f(vv.x, pq.x, pv0);
      pv1 = dot2f(vv.y, pq.y, pv1);
      pv2 = dot2f(vv.z, pq.z, pv2);
      pv3 = dot2f(vv.w, pq.w, pv3);
    }
    o += (pv0 + pv1) + (pv2 + pv3);

    __syncthreads();   // prefetch landed + all waves done with buf[it&1]
  }

  ctx[(size_t)qi * DM + h * HD + lane] = f2b(o / lsum);
}

// ---------------- global row: query 0 attends to ALL keys (f16 in) -----------
__global__ __launch_bounds__(256)
void attn_global12(const unsigned short* __restrict__ qb,
                   const unsigned short* __restrict__ kb,
                   const unsigned short* __restrict__ vb,
                   unsigned short* __restrict__ ctx)
{
  __shared__ float sc[SEQ];
  __shared__ float q0[HD];
  __shared__ float red[4];
  __shared__ float accl[4][HD];
  const int t = threadIdx.x;
  const int h = blockIdx.x;
  const unsigned short* Qh = qb + (size_t)h * SEQ * HD;
  const unsigned short* Kh = kb + (size_t)h * SEQ * HD;
  const unsigned short* Vh = vb + (size_t)h * SEQ * HD;

  if (t < HD) q0[t] = h2f(Qh[t]);   // pre-scaled by 1/8
  __syncthreads();

  for (int j = t; j < SEQ; j += 256) {
    const unsigned short* Kp = Kh + (size_t)j * HD;
    float a0 = 0.f, a1 = 0.f;
    for (int d0 = 0; d0 < 8; d0++) {
      const bf16x8 kv = *(const bf16x8*)(Kp + d0 * 8);
#pragma unroll
      for (int e = 0; e < 8; e += 2) {
        a0 += q0[d0 * 8 + e]     * h2f((unsigned short)kv[e]);
        a1 += q0[d0 * 8 + e + 1] * h2f((unsigned short)kv[e + 1]);
      }
    }
    sc[j] = a0 + a1;
  }
  __syncthreads();

  float mx = -1e30f;
  for (int j = t; j < SEQ; j += 256) mx = fmaxf(mx, sc[j]);
  for (int d = 1; d < 64; d <<= 1) mx = fmaxf(mx, __shfl_xor(mx, d));
  if ((t & 63) == 0) red[t >> 6] = mx;
  __syncthreads();
  mx = fmaxf(fmaxf(red[0], red[1]), fmaxf(red[2], red[3]));
  __syncthreads();

  float sum = 0.f;
  for (int j = t; j < SEQ; j += 256) {
    const float p = __expf(sc[j] - mx);
    sc[j] = p;
    sum += p;
  }
  for (int d = 1; d < 64; d <<= 1) sum += __shfl_xor(sum, d);
  __syncthreads();
  if ((t & 63) == 0) red[t >> 6] = sum;
  __syncthreads();
  const float inv = 1.f / (red[0] + red[1] + red[2] + red[3]);

  const int dd = t & 63, part = t >> 6;
  float a0 = 0.f, a1 = 0.f, a2 = 0.f, a3 = 0.f;
  const int jb = part * 1024;
  for (int j = 0; j < 1024; j += 4) {
    a0 += sc[jb + j + 0] * h2f(Vh[(size_t)(jb + j + 0) * HD + dd]);
    a1 += sc[jb + j + 1] * h2f(Vh[(size_t)(jb + j + 1) * HD + dd]);
    a2 += sc[jb + j + 2] * h2f(Vh[(size_t)(jb + j + 2) * HD + dd]);
    a3 += sc[jb + j + 3] * h2f(Vh[(size_t)(jb + j + 3) * HD + dd]);
  }
  accl[part][dd] = (a0 + a1) + (a2 + a3);
  __syncthreads();
  if (part == 0) {
    const float v = (accl[0][dd] + accl[1][dd] + accl[2][dd] + accl[3][dd]) * inv;
    ctx[(size_t)h * HD + dd] = f2b(v);   // row 0 (bf16, like the band kernel)
  }
}

// ---------------- launch ----------------
extern "C" void kernel_launch(void* const* d_in, const int* in_sizes, int n_in,
                              void* d_out, int out_size, void* d_ws, size_t ws_size,
                              hipStream_t stream)
{
  (void)in_sizes; (void)n_in; (void)out_size; (void)ws_size;
  const float* x  = (const float*)d_in[0];
  const float* Wq = (const float*)d_in[1];
  const float* bq = (const float*)d_in[2];
  const float* Wk = (const float*)d_in[3];
  const float* bk = (const float*)d_in[4];
  const float* Wv = (const float*)d_in[5];
  const float* bv = (const float*)d_in[6];
  const float* Wo = (const float*)d_in[7];
  const float* bo = (const float*)d_in[8];
  float* out = (float*)d_out;

  char* ws = (char*)d_ws;
  unsigned short* xb   = (unsigned short*)(ws + 0);         // dead after gemm<0>
  unsigned short* wqkv = (unsigned short*)(ws + 6291456);
  unsigned short* wob  = (unsigned short*)(ws + 9830400);
  unsigned short* qbuf = (unsigned short*)(ws + 11010048);  // [12][4096][64] f16
  unsigned short* kbuf = (unsigned short*)(ws + 17301504);  // [12][4096][64] f16
  unsigned short* vbuf = (unsigned short*)(ws + 23592960);  // [12][4096][64] f16
  unsigned short* vtb  = (unsigned short*)(ws + 29884416);  // [12][64][4096] f16
  unsigned short* ctx  = (unsigned short*)(ws + 0);         // bf16, aliases xb

  convert_all<<<dim3(1024), dim3(256), 0, stream>>>(x, Wq, Wk, Wv, Wo, xb, wqkv, wob);
  gemm_bt<0><<<dim3(18, 32), dim3(256), 0, stream>>>(xb, wqkv, qbuf, kbuf, vbuf,
                                                     bq, bk, bv, nullptr, nullptr);
  transpose_v<<<dim3(SEQ / 64, NH), dim3(256), 0, stream>>>(vbuf, vtb);
  attn_band5<<<dim3(SEQ / 4, NH), dim3(256), 0, stream>>>(qbuf, kbuf, vtb, ctx);
  attn_global12<<<dim3(NH), dim3(256), 0, stream>>>(qbuf, kbuf, vbuf, ctx);
  gemm_bt<1><<<dim3(6, 32), dim3(256), 0, stream>>>(ctx, wob, nullptr, nullptr, nullptr,
                                                    nullptr, nullptr, nullptr, bo, out);
}

// Round 16
// 273.991 us; speedup vs baseline: 35.0722x; 1.2199x over previous
//
#include <hip/hip_runtime.h>
#include <cstdint>

#define SEQ   4096
#define DM    768
#define NH    12
#define HD    64
#define KD    768

typedef float  f32x4  __attribute__((ext_vector_type(4)));
typedef short  bf16x8 __attribute__((ext_vector_type(8)));
typedef _Float16 h16x2 __attribute__((ext_vector_type(2)));
typedef unsigned int u32;

typedef __attribute__((address_space(1))) const unsigned int gu32;
typedef __attribute__((address_space(3))) unsigned int lu32;

__device__ __forceinline__ unsigned short f2b(float f) {
  unsigned int u = __builtin_bit_cast(unsigned int, f);
  u += 0x7fffu + ((u >> 16) & 1u);
  return (unsigned short)(u >> 16);
}
__device__ __forceinline__ float b2f(unsigned short s) {
  return __builtin_bit_cast(float, ((unsigned int)s) << 16);
}
__device__ __forceinline__ unsigned short f2h(float f) {
  _Float16 h = (_Float16)f;
  return __builtin_bit_cast(unsigned short, h);
}
__device__ __forceinline__ float h2f(unsigned short s) {
  return (float)__builtin_bit_cast(_Float16, s);
}

// packed f16 dot2 with f32 accumulator (v_dot2_f32_f16); scalar fallback
__device__ __forceinline__ float dot2f(u32 a, u32 b, float c) {
#if __has_builtin(__builtin_amdgcn_fdot2)
  return __builtin_amdgcn_fdot2(__builtin_bit_cast(h16x2, a),
                                __builtin_bit_cast(h16x2, b), c, false);
#else
  const h16x2 ha = __builtin_bit_cast(h16x2, a);
  const h16x2 hb = __builtin_bit_cast(h16x2, b);
  return c + (float)ha[0] * (float)hb[0] + (float)ha[1] * (float)hb[1];
#endif
}

__device__ __forceinline__ void gload_lds16(const void* g, void* l) {
  gu32* gp = reinterpret_cast<gu32*>(reinterpret_cast<uintptr_t>(g));
  lu32* lp = reinterpret_cast<lu32*>(reinterpret_cast<uintptr_t>(l));
  __builtin_amdgcn_global_load_lds(gp, lp, 16, 0, 0);
}

// ---------------- pack/convert: f32 -> bf16 (R3-verified) ----------------
__global__ void convert_all(const float* __restrict__ x,
                            const float* __restrict__ wq,
                            const float* __restrict__ wk,
                            const float* __restrict__ wv,
                            const float* __restrict__ wo,
                            unsigned short* __restrict__ xb,
                            unsigned short* __restrict__ wqkv,
                            unsigned short* __restrict__ wob)
{
  const int XN = SEQ * DM;
  const int WN = DM * DM;
  const int total4 = (XN + 4 * WN) >> 2;
  for (int i = blockIdx.x * blockDim.x + threadIdx.x; i < total4;
       i += gridDim.x * blockDim.x) {
    const int base = i << 2;
    const float* src;
    unsigned short* dst;
    if (base < XN)                 { src = x  + base;               dst = xb   + base; }
    else if (base < XN + WN)       { src = wq + (base - XN);        dst = wqkv + (base - XN); }
    else if (base < XN + 2 * WN)   { src = wk + (base - XN - WN);   dst = wqkv + (base - XN); }
    else if (base < XN + 3 * WN)   { src = wv + (base - XN - 2*WN); dst = wqkv + (base - XN); }
    else                           { src = wo + (base - XN - 3*WN); dst = wob  + (base - XN - 3*WN); }
    const float4 v = *(const float4*)src;
    *(ushort4*)dst = make_ushort4(f2b(v.x), f2b(v.y), f2b(v.z), f2b(v.w));
  }
}

// ---------------- GEMM C = A[M,K] * B[N,K]^T (R3-verified, bf16 MFMA) --------
// EPI 0: Q/K/V epilogue emits F16
template<int EPI>
__global__ __launch_bounds__(256, 2)
void gemm_bt(const unsigned short* __restrict__ A,
             const unsigned short* __restrict__ B,
             unsigned short* __restrict__ qb,
             unsigned short* __restrict__ kb,
             unsigned short* __restrict__ vb,
             const float* __restrict__ bq,
             const float* __restrict__ bk,
             const float* __restrict__ bv,
             const float* __restrict__ bo,
             float* __restrict__ outf)
{
  __shared__ __align__(16) unsigned short As[128 * 32];
  __shared__ __align__(16) unsigned short Bs[128 * 32];
  const int t  = threadIdx.x;
  const int w  = t >> 6;
  const int l  = t & 63;
  const int m0 = blockIdx.y * 128;
  const int n0 = blockIdx.x * 128;
  const int wr = (w >> 1) * 64;
  const int wc = (w & 1) * 64;
  const int lr = l & 15;
  const int lk = (l >> 4) * 8;

  const int row1 = t >> 2;
  const int row2 = row1 + 64;
  const int seg  = t & 3;

  f32x4 acc[4][4];
#pragma unroll
  for (int i = 0; i < 4; i++)
#pragma unroll
    for (int j = 0; j < 4; j++) acc[i][j] = (f32x4){0.f, 0.f, 0.f, 0.f};

  char* ldsA0 = (char*)As + (size_t)(w * 64) * 16;
  char* ldsA1 = (char*)As + (size_t)(w * 64 + 256) * 16;
  char* ldsB0 = (char*)Bs + (size_t)(w * 64) * 16;
  char* ldsB1 = (char*)Bs + (size_t)(w * 64 + 256) * 16;

  for (int k0 = 0; k0 < KD; k0 += 32) {
    gload_lds16(A + (size_t)(m0 + row1) * KD + k0 + seg * 8, ldsA0);
    gload_lds16(A + (size_t)(m0 + row2) * KD + k0 + seg * 8, ldsA1);
    gload_lds16(B + (size_t)(n0 + row1) * KD + k0 + seg * 8, ldsB0);
    gload_lds16(B + (size_t)(n0 + row2) * KD + k0 + seg * 8, ldsB1);
    __syncthreads();
    bf16x8 af[4], bfv[4];
#pragma unroll
    for (int fi = 0; fi < 4; fi++)
      af[fi] = *(const bf16x8*)(As + (wr + fi * 16 + lr) * 32 + lk);
#pragma unroll
    for (int fj = 0; fj < 4; fj++)
      bfv[fj] = *(const bf16x8*)(Bs + (wc + fj * 16 + lr) * 32 + lk);
#pragma unroll
    for (int fi = 0; fi < 4; fi++)
#pragma unroll
      for (int fj = 0; fj < 4; fj++)
        acc[fi][fj] = __builtin_amdgcn_mfma_f32_16x16x32_bf16(af[fi], bfv[fj], acc[fi][fj], 0, 0, 0);
    __syncthreads();
  }

#pragma unroll
  for (int fi = 0; fi < 4; fi++) {
    const int mbase = m0 + wr + fi * 16 + (l >> 4) * 4;
#pragma unroll
    for (int fj = 0; fj < 4; fj++) {
      const int n = n0 + wc + fj * 16 + lr;
      if (EPI == 1) {
        const float bb = bo[n];
#pragma unroll
        for (int r = 0; r < 4; r++)
          outf[(size_t)(mbase + r) * DM + n] = acc[fi][fj][r] + bb;
      } else if (n < DM) {                       // Q (scaled by 1/8) -> f16
        const int hh = n >> 6, dk = n & 63;
        const float bb = bq[n];
#pragma unroll
        for (int r = 0; r < 4; r++)
          qb[((size_t)hh * SEQ + mbase + r) * HD + dk] = f2h((acc[fi][fj][r] + bb) * 0.125f);
      } else if (n < 2 * DM) {                   // K row-major [h][s][dk] -> f16
        const int n2 = n - DM, hh = n2 >> 6, dk = n2 & 63;
        const float bb = bk[n2];
#pragma unroll
        for (int r = 0; r < 4; r++)
          kb[((size_t)hh * SEQ + mbase + r) * HD + dk] = f2h(acc[fi][fj][r] + bb);
      } else {                                   // V row-major [h][s][dk] -> f16
        const int n3 = n - 2 * DM, hh = n3 >> 6, dk = n3 & 63;
        const float bb = bv[n3];
#pragma unroll
        for (int r = 0; r < 4; r++)
          vb[((size_t)hh * SEQ + mbase + r) * HD + dk] = f2h(acc[fi][fj][r] + bb);
      }
    }
  }
}

// ---------------- standalone V transpose: [h][s][dk] -> [h][dk][s] (R4) ------
__global__ __launch_bounds__(256)
void transpose_v(const unsigned short* __restrict__ vb,
                 unsigned short* __restrict__ vt)
{
  __shared__ unsigned short tile[64][65];
  const int h  = blockIdx.y;
  const int s0 = blockIdx.x * 64;
  const int t  = threadIdx.x;
  const int tc = t & 63;
  const int t4 = t >> 6;
  const unsigned short* Vh  = vb + (size_t)h * SEQ * HD;
  unsigned short*       Vth = vt + (size_t)h * HD * SEQ;
#pragma unroll
  for (int rr = 0; rr < 64; rr += 4)
    tile[rr + t4][tc] = Vh[(size_t)(s0 + rr + t4) * HD + tc];
  __syncthreads();
#pragma unroll
  for (int rr = 0; rr < 64; rr += 4) {
    const int d = rr + t4;
    Vth[(size_t)d * SEQ + s0 + tc] = tile[tc][d];
  }
}

// ------ band attention: dbuf LDS + f16 dot2 + DEFER-MAX softmax --------------
// 4 queries per block (one per wave), union chunk list (chunk 0 first).
// Defer-max (T13): wave max-reduce only when __any(s > m+8); P bounded by e^8
// (safe in f16/f32). lsum is PER-LANE partial, reduced ONCE at the end.
// Swizzle invariant (R13-verified): read slot (i^(r&7)), pair with CONTENTS i.
// mask: valid = (qi==0)||(j==0)||(|qi-j|<=256). Row 0 overwritten after.
__global__ __launch_bounds__(256)
void attn_band6(const unsigned short* __restrict__ qb,
                const unsigned short* __restrict__ kb,
                const unsigned short* __restrict__ vt,
                unsigned short* __restrict__ ctx)
{
  __shared__ __align__(16) unsigned short Ks[2][64 * 64];
  __shared__ __align__(16) unsigned short Vts[2][64 * 64];
  __shared__ __align__(16) unsigned short plds[4][64];   // P as f16
  const int h    = blockIdx.y;
  const int B    = blockIdx.x;          // queries B*4 .. B*4+3
  const int t    = threadIdx.x;
  const int w    = t >> 6;
  const int lane = t & 63;
  const int qi   = B * 4 + w;

  const unsigned short* Qh  = qb + (size_t)h * SEQ * HD;
  const unsigned short* Kh  = kb + (size_t)h * SEQ * HD;
  const unsigned short* Vth = vt + (size_t)h * HD * SEQ;

  const int srow = t >> 3;
  const int scol = (t & 7) ^ (srow & 7);    // pre-swizzled source 16B-slot
  const int swz  = lane & 7;                // read-side XOR for row=lane

  // q row (f16, pre-scaled by 1/8) -> 32 packed half2 regs
  h16x2 qp[32];
  {
    const u32* Qp32 = (const u32*)(Qh + (size_t)qi * HD);
#pragma unroll
    for (int i = 0; i < 32; i++) qp[i] = __builtin_bit_cast(h16x2, Qp32[i]);
  }

  // union chunk range for the block's 4 queries; chunk 0 prepended if absent
  int lo = B * 4 - 256; if (lo < 0) lo = 0;
  int hi = B * 4 + 3 + 257; if (hi > SEQ) hi = SEQ;
  const int cbeg = lo >> 6, cend = (hi - 1) >> 6;
  const int pre  = (cbeg > 0) ? 1 : 0;
  const int nch  = cend - cbeg + 1 + pre;

  auto chunkof = [&](int it) -> int {
    return (pre && it == 0) ? 0 : (cbeg + it - pre);
  };
  auto stage = [&](int bsel, int cch) {
    const int jj0 = cch * 64;
    char* kbase = (char*)(&Ks[bsel][0]);
    char* vbase = (char*)(&Vts[bsel][0]);
    gload_lds16(Kh + (size_t)(jj0 + srow) * HD + scol * 8,
                kbase + (size_t)(w * 64) * 16);
    gload_lds16(Kh + (size_t)(jj0 + 32 + srow) * HD + scol * 8,
                kbase + (size_t)(w * 64 + 256) * 16);
    gload_lds16(Vth + (size_t)srow * SEQ + jj0 + scol * 8,
                vbase + (size_t)(w * 64) * 16);
    gload_lds16(Vth + (size_t)(32 + srow) * SEQ + jj0 + scol * 8,
                vbase + (size_t)(w * 64 + 256) * 16);
  };

  stage(0, chunkof(0));
  __syncthreads();

  float o = 0.f, m = -1e30f, lsum = 0.f;   // lsum: per-lane partial

  for (int it = 0; it < nch; ++it) {
    if (it + 1 < nch) stage((it + 1) & 1, chunkof(it + 1));  // async prefetch

    const int c  = chunkof(it);
    const int j0 = c * 64;
    const unsigned short* Kp = &Ks[it & 1][0] + lane * 64;
    const unsigned short* Vp = &Vts[it & 1][0] + lane * 64;

    // ---- s_j = q . k_j : 32 packed dot2 (lane = key j0+lane)
    float s0 = 0.f, s1 = 0.f, s2 = 0.f, s3 = 0.f;
#pragma unroll
    for (int d0 = 0; d0 < 8; d0++) {
      const uint4 kv = *(const uint4*)(Kp + ((d0 ^ swz) * 8));  // contents: block d0
      const int qb4 = d0 * 4;                                   // contents index
      s0 = dot2f(kv.x, __builtin_bit_cast(u32, qp[qb4 + 0]), s0);
      s1 = dot2f(kv.y, __builtin_bit_cast(u32, qp[qb4 + 1]), s1);
      s2 = dot2f(kv.z, __builtin_bit_cast(u32, qp[qb4 + 2]), s2);
      s3 = dot2f(kv.w, __builtin_bit_cast(u32, qp[qb4 + 3]), s3);
    }
    float s = (s0 + s1) + (s2 + s3);
    const int j = j0 + lane;
    const bool valid = (qi == 0) || (j == 0) ||
                       ((j - qi) <= 256 && (qi - j) <= 256);
    s = valid ? s : -1e30f;

    // ---- defer-max online softmax: reduce only when the max may grow
    if (__any(s > m + 8.f)) {
      float mx = s;
      for (int d = 1; d < 64; d <<= 1) mx = fmaxf(mx, __shfl_xor(mx, d));
      const float mnew = fmaxf(m, mx);
      const float esc  = __expf(m - mnew);
      lsum *= esc;
      o    *= esc;
      m     = mnew;
    }
    const float p = __expf(s - m);   // bounded by e^8
    lsum += p;                       // this lane's key only; reduced at end

    // ---- p (f16) -> wave-private LDS; PV: 32 dot2 from V^T rows (lane = dim)
    plds[w][lane] = f2h(p);
    float pv0 = 0.f, pv1 = 0.f, pv2 = 0.f, pv3 = 0.f;
#pragma unroll
    for (int q8 = 0; q8 < 8; q8++) {
      const uint4 vv = *(const uint4*)(Vp + ((q8 ^ swz) * 8));  // contents: block q8
      const uint4 pq = *(const uint4*)&plds[w][q8 * 8];         // contents index
      pv0 = dot2f(vv.x, pq.x, pv0);
      pv1 = dot2f(vv.y, pq.y, pv1);
      pv2 = dot2f(vv.z, pq.z, pv2);
      pv3 = dot2f(vv.w, pq.w, pv3);
    }
    o += (pv0 + pv1) + (pv2 + pv3);

    __syncthreads();   // prefetch landed + all waves done with buf[it&1]
  }

  // final: one butterfly reduce of the per-lane lsum partials
  for (int d = 1; d < 64; d <<= 1) lsum += __shfl_xor(lsum, d);

  ctx[(size_t)qi * DM + h * HD + lane] = f2b(o / lsum);
}

// ---------------- global row: query 0 attends to ALL keys (f16 in) -----------
__global__ __launch_bounds__(256)
void attn_global12(const unsigned short* __restrict__ qb,
                   const unsigned short* __restrict__ kb,
                   const unsigned short* __restrict__ vb,
                   unsigned short* __restrict__ ctx)
{
  __shared__ float sc[SEQ];
  __shared__ float q0[HD];
  __shared__ float red[4];
  __shared__ float accl[4][HD];
  const int t = threadIdx.x;
  const int h = blockIdx.x;
  const unsigned short* Qh = qb + (size_t)h * SEQ * HD;
  const unsigned short* Kh = kb + (size_t)h * SEQ * HD;
  const unsigned short* Vh = vb + (size_t)h * SEQ * HD;

  if (t < HD) q0[t] = h2f(Qh[t]);   // pre-scaled by 1/8
  __syncthreads();

  for (int j = t; j < SEQ; j += 256) {
    const unsigned short* Kp = Kh + (size_t)j * HD;
    float a0 = 0.f, a1 = 0.f;
    for (int d0 = 0; d0 < 8; d0++) {
      const bf16x8 kv = *(const bf16x8*)(Kp + d0 * 8);
#pragma unroll
      for (int e = 0; e < 8; e += 2) {
        a0 += q0[d0 * 8 + e]     * h2f((unsigned short)kv[e]);
        a1 += q0[d0 * 8 + e + 1] * h2f((unsigned short)kv[e + 1]);
      }
    }
    sc[j] = a0 + a1;
  }
  __syncthreads();

  float mx = -1e30f;
  for (int j = t; j < SEQ; j += 256) mx = fmaxf(mx, sc[j]);
  for (int d = 1; d < 64; d <<= 1) mx = fmaxf(mx, __shfl_xor(mx, d));
  if ((t & 63) == 0) red[t >> 6] = mx;
  __syncthreads();
  mx = fmaxf(fmaxf(red[0], red[1]), fmaxf(red[2], red[3]));
  __syncthreads();

  float sum = 0.f;
  for (int j = t; j < SEQ; j += 256) {
    const float p = __expf(sc[j] - mx);
    sc[j] = p;
    sum += p;
  }
  for (int d = 1; d < 64; d <<= 1) sum += __shfl_xor(sum, d);
  __syncthreads();
  if ((t & 63) == 0) red[t >> 6] = sum;
  __syncthreads();
  const float inv = 1.f / (red[0] + red[1] + red[2] + red[3]);

  const int dd = t & 63, part = t >> 6;
  float a0 = 0.f, a1 = 0.f, a2 = 0.f, a3 = 0.f;
  const int jb = part * 1024;
  for (int j = 0; j < 1024; j += 4) {
    a0 += sc[jb + j + 0] * h2f(Vh[(size_t)(jb + j + 0) * HD + dd]);
    a1 += sc[jb + j + 1] * h2f(Vh[(size_t)(jb + j + 1) * HD + dd]);
    a2 += sc[jb + j + 2] * h2f(Vh[(size_t)(jb + j + 2) * HD + dd]);
    a3 += sc[jb + j + 3] * h2f(Vh[(size_t)(jb + j + 3) * HD + dd]);
  }
  accl[part][dd] = (a0 + a1) + (a2 + a3);
  __syncthreads();
  if (part == 0) {
    const float v = (accl[0][dd] + accl[1][dd] + accl[2][dd] + accl[3][dd]) * inv;
    ctx[(size_t)h * HD + dd] = f2b(v);   // row 0 (bf16, like the band kernel)
  }
}

// ---------------- launch ----------------
extern "C" void kernel_launch(void* const* d_in, const int* in_sizes, int n_in,
                              void* d_out, int out_size, void* d_ws, size_t ws_size,
                              hipStream_t stream)
{
  (void)in_sizes; (void)n_in; (void)out_size; (void)ws_size;
  const float* x  = (const float*)d_in[0];
  const float* Wq = (const float*)d_in[1];
  const float* bq = (const float*)d_in[2];
  const float* Wk = (const float*)d_in[3];
  const float* bk = (const float*)d_in[4];
  const float* Wv = (const float*)d_in[5];
  const float* bv = (const float*)d_in[6];
  const float* Wo = (const float*)d_in[7];
  const float* bo = (const float*)d_in[8];
  float* out = (float*)d_out;

  char* ws = (char*)d_ws;
  unsigned short* xb   = (unsigned short*)(ws + 0);         // dead after gemm<0>
  unsigned short* wqkv = (unsigned short*)(ws + 6291456);
  unsigned short* wob  = (unsigned short*)(ws + 9830400);
  unsigned short* qbuf = (unsigned short*)(ws + 11010048);  // [12][4096][64] f16
  unsigned short* kbuf = (unsigned short*)(ws + 17301504);  // [12][4096][64] f16
  unsigned short* vbuf = (unsigned short*)(ws + 23592960);  // [12][4096][64] f16
  unsigned short* vtb  = (unsigned short*)(ws + 29884416);  // [12][64][4096] f16
  unsigned short* ctx  = (unsigned short*)(ws + 0);         // bf16, aliases xb

  convert_all<<<dim3(1024), dim3(256), 0, stream>>>(x, Wq, Wk, Wv, Wo, xb, wqkv, wob);
  gemm_bt<0><<<dim3(18, 32), dim3(256), 0, stream>>>(xb, wqkv, qbuf, kbuf, vbuf,
                                                     bq, bk, bv, nullptr, nullptr);
  transpose_v<<<dim3(SEQ / 64, NH), dim3(256), 0, stream>>>(vbuf, vtb);
  attn_band6<<<dim3(SEQ / 4, NH), dim3(256), 0, stream>>>(qbuf, kbuf, vtb, ctx);
  attn_global12<<<dim3(NH), dim3(256), 0, stream>>>(qbuf, kbuf, vbuf, ctx);
  gemm_bt<1><<<dim3(6, 32), dim3(256), 0, stream>>>(ctx, wob, nullptr, nullptr, nullptr,
                                                    nullptr, nullptr, nullptr, bo, out);
}

// Round 17
// 265.184 us; speedup vs baseline: 36.2370x; 1.0332x over previous
//
#include <hip/hip_runtime.h>
#include <cstdint>

#define SEQ   4096
#define DM    768
#define NH    12
#define HD    64
#define KD    768

typedef float  f32x4  __attribute__((ext_vector_type(4)));
typedef short  bf16x8 __attribute__((ext_vector_type(8)));
typedef _Float16 h16x2 __attribute__((ext_vector_type(2)));
typedef unsigned int u32;

typedef __attribute__((address_space(1))) const unsigned int gu32;
typedef __attribute__((address_space(3))) unsigned int lu32;

__device__ __forceinline__ unsigned short f2b(float f) {
  unsigned int u = __builtin_bit_cast(unsigned int, f);
  u += 0x7fffu + ((u >> 16) & 1u);
  return (unsigned short)(u >> 16);
}
__device__ __forceinline__ float b2f(unsigned short s) {
  return __builtin_bit_cast(float, ((unsigned int)s) << 16);
}
__device__ __forceinline__ unsigned short f2h(float f) {
  _Float16 h = (_Float16)f;
  return __builtin_bit_cast(unsigned short, h);
}
__device__ __forceinline__ float h2f(unsigned short s) {
  return (float)__builtin_bit_cast(_Float16, s);
}

// packed f16 dot2 with f32 accumulator (v_dot2_f32_f16); scalar fallback
__device__ __forceinline__ float dot2f(u32 a, u32 b, float c) {
#if __has_builtin(__builtin_amdgcn_fdot2)
  return __builtin_amdgcn_fdot2(__builtin_bit_cast(h16x2, a),
                                __builtin_bit_cast(h16x2, b), c, false);
#else
  const h16x2 ha = __builtin_bit_cast(h16x2, a);
  const h16x2 hb = __builtin_bit_cast(h16x2, b);
  return c + (float)ha[0] * (float)hb[0] + (float)ha[1] * (float)hb[1];
#endif
}

__device__ __forceinline__ void gload_lds16(const void* g, void* l) {
  gu32* gp = reinterpret_cast<gu32*>(reinterpret_cast<uintptr_t>(g));
  lu32* lp = reinterpret_cast<lu32*>(reinterpret_cast<uintptr_t>(l));
  __builtin_amdgcn_global_load_lds(gp, lp, 16, 0, 0);
}

// ---------------- pack/convert: f32 -> bf16 (R3-verified) ----------------
__global__ void convert_all(const float* __restrict__ x,
                            const float* __restrict__ wq,
                            const float* __restrict__ wk,
                            const float* __restrict__ wv,
                            const float* __restrict__ wo,
                            unsigned short* __restrict__ xb,
                            unsigned short* __restrict__ wqkv,
                            unsigned short* __restrict__ wob)
{
  const int XN = SEQ * DM;
  const int WN = DM * DM;
  const int total4 = (XN + 4 * WN) >> 2;
  for (int i = blockIdx.x * blockDim.x + threadIdx.x; i < total4;
       i += gridDim.x * blockDim.x) {
    const int base = i << 2;
    const float* src;
    unsigned short* dst;
    if (base < XN)                 { src = x  + base;               dst = xb   + base; }
    else if (base < XN + WN)       { src = wq + (base - XN);        dst = wqkv + (base - XN); }
    else if (base < XN + 2 * WN)   { src = wk + (base - XN - WN);   dst = wqkv + (base - XN); }
    else if (base < XN + 3 * WN)   { src = wv + (base - XN - 2*WN); dst = wqkv + (base - XN); }
    else                           { src = wo + (base - XN - 3*WN); dst = wob  + (base - XN - 3*WN); }
    const float4 v = *(const float4*)src;
    *(ushort4*)dst = make_ushort4(f2b(v.x), f2b(v.y), f2b(v.z), f2b(v.w));
  }
}

// ---------------- GEMM C = A[M,K] * B[N,K]^T (R3-verified, bf16 MFMA) --------
// EPI 0: Q/K row-major f16; V written TRANSPOSED [h][dk][s] f16 (R2≡R4 verified)
template<int EPI>
__global__ __launch_bounds__(256, 2)
void gemm_bt(const unsigned short* __restrict__ A,
             const unsigned short* __restrict__ B,
             unsigned short* __restrict__ qb,
             unsigned short* __restrict__ kb,
             unsigned short* __restrict__ vt,
             const float* __restrict__ bq,
             const float* __restrict__ bk,
             const float* __restrict__ bv,
             const float* __restrict__ bo,
             float* __restrict__ outf)
{
  __shared__ __align__(16) unsigned short As[128 * 32];
  __shared__ __align__(16) unsigned short Bs[128 * 32];
  const int t  = threadIdx.x;
  const int w  = t >> 6;
  const int l  = t & 63;
  const int m0 = blockIdx.y * 128;
  const int n0 = blockIdx.x * 128;
  const int wr = (w >> 1) * 64;
  const int wc = (w & 1) * 64;
  const int lr = l & 15;
  const int lk = (l >> 4) * 8;

  const int row1 = t >> 2;
  const int row2 = row1 + 64;
  const int seg  = t & 3;

  f32x4 acc[4][4];
#pragma unroll
  for (int i = 0; i < 4; i++)
#pragma unroll
    for (int j = 0; j < 4; j++) acc[i][j] = (f32x4){0.f, 0.f, 0.f, 0.f};

  char* ldsA0 = (char*)As + (size_t)(w * 64) * 16;
  char* ldsA1 = (char*)As + (size_t)(w * 64 + 256) * 16;
  char* ldsB0 = (char*)Bs + (size_t)(w * 64) * 16;
  char* ldsB1 = (char*)Bs + (size_t)(w * 64 + 256) * 16;

  for (int k0 = 0; k0 < KD; k0 += 32) {
    gload_lds16(A + (size_t)(m0 + row1) * KD + k0 + seg * 8, ldsA0);
    gload_lds16(A + (size_t)(m0 + row2) * KD + k0 + seg * 8, ldsA1);
    gload_lds16(B + (size_t)(n0 + row1) * KD + k0 + seg * 8, ldsB0);
    gload_lds16(B + (size_t)(n0 + row2) * KD + k0 + seg * 8, ldsB1);
    __syncthreads();
    bf16x8 af[4], bfv[4];
#pragma unroll
    for (int fi = 0; fi < 4; fi++)
      af[fi] = *(const bf16x8*)(As + (wr + fi * 16 + lr) * 32 + lk);
#pragma unroll
    for (int fj = 0; fj < 4; fj++)
      bfv[fj] = *(const bf16x8*)(Bs + (wc + fj * 16 + lr) * 32 + lk);
#pragma unroll
    for (int fi = 0; fi < 4; fi++)
#pragma unroll
      for (int fj = 0; fj < 4; fj++)
        acc[fi][fj] = __builtin_amdgcn_mfma_f32_16x16x32_bf16(af[fi], bfv[fj], acc[fi][fj], 0, 0, 0);
    __syncthreads();
  }

#pragma unroll
  for (int fi = 0; fi < 4; fi++) {
    const int mbase = m0 + wr + fi * 16 + (l >> 4) * 4;
#pragma unroll
    for (int fj = 0; fj < 4; fj++) {
      const int n = n0 + wc + fj * 16 + lr;
      if (EPI == 1) {
        const float bb = bo[n];
#pragma unroll
        for (int r = 0; r < 4; r++)
          outf[(size_t)(mbase + r) * DM + n] = acc[fi][fj][r] + bb;
      } else if (n < DM) {                       // Q (scaled by 1/8) -> f16
        const int hh = n >> 6, dk = n & 63;
        const float bb = bq[n];
#pragma unroll
        for (int r = 0; r < 4; r++)
          qb[((size_t)hh * SEQ + mbase + r) * HD + dk] = f2h((acc[fi][fj][r] + bb) * 0.125f);
      } else if (n < 2 * DM) {                   // K row-major [h][s][dk] -> f16
        const int n2 = n - DM, hh = n2 >> 6, dk = n2 & 63;
        const float bb = bk[n2];
#pragma unroll
        for (int r = 0; r < 4; r++)
          kb[((size_t)hh * SEQ + mbase + r) * HD + dk] = f2h(acc[fi][fj][r] + bb);
      } else {                                   // V -> transposed [h][dk][s] f16
        const int n3 = n - 2 * DM, hh = n3 >> 6, dk = n3 & 63;
        const float bb = bv[n3];
        ushort4 ov = make_ushort4(f2h(acc[fi][fj][0] + bb), f2h(acc[fi][fj][1] + bb),
                                  f2h(acc[fi][fj][2] + bb), f2h(acc[fi][fj][3] + bb));
        *(ushort4*)(vt + ((size_t)hh * HD + dk) * SEQ + mbase) = ov;
      }
    }
  }
}

// ------ band attention: 8 waves/8 queries per block, dbuf LDS, f16 dot2 ------
// Defer-max softmax (R16-verified). Swizzle invariant (R13-verified): LDS row r
// slot s holds global block s^(r&7); read slot (i^(r&7)), pair with CONTENTS i.
// mask: valid = (qi==0)||(j==0)||(|qi-j|<=256). Row 0 overwritten after.
__global__ __launch_bounds__(512)
void attn_band7(const unsigned short* __restrict__ qb,
                const unsigned short* __restrict__ kb,
                const unsigned short* __restrict__ vt,
                unsigned short* __restrict__ ctx)
{
  __shared__ __align__(16) unsigned short Ks[2][64 * 64];
  __shared__ __align__(16) unsigned short Vts[2][64 * 64];
  __shared__ __align__(16) unsigned short plds[8][64];   // P as f16
  const int h    = blockIdx.y;
  const int B    = blockIdx.x;          // queries B*8 .. B*8+7
  const int t    = threadIdx.x;
  const int w    = t >> 6;
  const int lane = t & 63;
  const int qi   = B * 8 + w;

  const unsigned short* Qh  = qb + (size_t)h * SEQ * HD;
  const unsigned short* Kh  = kb + (size_t)h * SEQ * HD;
  const unsigned short* Vth = vt + (size_t)h * HD * SEQ;

  const int srow = t >> 3;                  // 512 threads cover all 64 rows
  const int scol = (t & 7) ^ (srow & 7);    // pre-swizzled source 16B-slot
  const int swz  = lane & 7;                // read-side XOR for row=lane

  // q row (f16, pre-scaled by 1/8) -> 32 packed half2 regs
  h16x2 qp[32];
  {
    const u32* Qp32 = (const u32*)(Qh + (size_t)qi * HD);
#pragma unroll
    for (int i = 0; i < 32; i++) qp[i] = __builtin_bit_cast(h16x2, Qp32[i]);
  }

  // union chunk range for the block's 8 queries; chunk 0 prepended if absent
  int lo = B * 8 - 256; if (lo < 0) lo = 0;
  int hi = B * 8 + 7 + 257; if (hi > SEQ) hi = SEQ;
  const int cbeg = lo >> 6, cend = (hi - 1) >> 6;
  const int pre  = (cbeg > 0) ? 1 : 0;
  const int nch  = cend - cbeg + 1 + pre;

  auto chunkof = [&](int it) -> int {
    return (pre && it == 0) ? 0 : (cbeg + it - pre);
  };
  auto stage = [&](int bsel, int cch) {
    const int jj0 = cch * 64;
    char* kbase = (char*)(&Ks[bsel][0])  + (size_t)(w * 64) * 16;
    char* vbase = (char*)(&Vts[bsel][0]) + (size_t)(w * 64) * 16;
    gload_lds16(Kh + (size_t)(jj0 + srow) * HD + scol * 8, kbase);
    gload_lds16(Vth + (size_t)srow * SEQ + jj0 + scol * 8, vbase);
  };

  stage(0, chunkof(0));
  __syncthreads();

  float o = 0.f, m = -1e30f, lsum = 0.f;   // lsum: per-lane partial

  for (int it = 0; it < nch; ++it) {
    if (it + 1 < nch) stage((it + 1) & 1, chunkof(it + 1));  // async prefetch

    const int c  = chunkof(it);
    const int j0 = c * 64;
    const unsigned short* Kp = &Ks[it & 1][0] + lane * 64;
    const unsigned short* Vp = &Vts[it & 1][0] + lane * 64;

    // ---- s_j = q . k_j : 32 packed dot2 (lane = key j0+lane)
    float s0 = 0.f, s1 = 0.f, s2 = 0.f, s3 = 0.f;
#pragma unroll
    for (int d0 = 0; d0 < 8; d0++) {
      const uint4 kv = *(const uint4*)(Kp + ((d0 ^ swz) * 8));  // contents: block d0
      const int qb4 = d0 * 4;                                   // contents index
      s0 = dot2f(kv.x, __builtin_bit_cast(u32, qp[qb4 + 0]), s0);
      s1 = dot2f(kv.y, __builtin_bit_cast(u32, qp[qb4 + 1]), s1);
      s2 = dot2f(kv.z, __builtin_bit_cast(u32, qp[qb4 + 2]), s2);
      s3 = dot2f(kv.w, __builtin_bit_cast(u32, qp[qb4 + 3]), s3);
    }
    float s = (s0 + s1) + (s2 + s3);
    const int j = j0 + lane;
    const bool valid = (qi == 0) || (j == 0) ||
                       ((j - qi) <= 256 && (qi - j) <= 256);
    s = valid ? s : -1e30f;

    // ---- defer-max online softmax: reduce only when the max may grow
    if (__any(s > m + 8.f)) {
      float mx = s;
      for (int d = 1; d < 64; d <<= 1) mx = fmaxf(mx, __shfl_xor(mx, d));
      const float mnew = fmaxf(m, mx);
      const float esc  = __expf(m - mnew);
      lsum *= esc;
      o    *= esc;
      m     = mnew;
    }
    const float p = __expf(s - m);   // bounded by e^8
    lsum += p;                       // this lane's key only; reduced at end

    // ---- p (f16) -> wave-private LDS; PV: 32 dot2 from V^T rows (lane = dim)
    plds[w][lane] = f2h(p);
    float pv0 = 0.f, pv1 = 0.f, pv2 = 0.f, pv3 = 0.f;
#pragma unroll
    for (int q8 = 0; q8 < 8; q8++) {
      const uint4 vv = *(const uint4*)(Vp + ((q8 ^ swz) * 8));  // contents: block q8
      const uint4 pq = *(const uint4*)&plds[w][q8 * 8];         // contents index
      pv0 = dot2f(vv.x, pq.x, pv0);
      pv1 = dot2f(vv.y, pq.y, pv1);
      pv2 = dot2f(vv.z, pq.z, pv2);
      pv3 = dot2f(vv.w, pq.w, pv3);
    }
    o += (pv0 + pv1) + (pv2 + pv3);

    __syncthreads();   // prefetch landed + all waves done with buf[it&1]
  }

  // final: one butterfly reduce of the per-lane lsum partials
  for (int d = 1; d < 64; d <<= 1) lsum += __shfl_xor(lsum, d);

  ctx[(size_t)qi * DM + h * HD + lane] = f2b(o / lsum);
}

// ---------------- global row: query 0 attends to ALL keys (V^T input) --------
__global__ __launch_bounds__(256)
void attn_global12(const unsigned short* __restrict__ qb,
                   const unsigned short* __restrict__ kb,
                   const unsigned short* __restrict__ vt,
                   unsigned short* __restrict__ ctx)
{
  __shared__ float sc[SEQ];
  __shared__ float q0[HD];
  __shared__ float red[4];
  __shared__ float accl[4][HD];
  const int t = threadIdx.x;
  const int h = blockIdx.x;
  const unsigned short* Qh  = qb + (size_t)h * SEQ * HD;
  const unsigned short* Kh  = kb + (size_t)h * SEQ * HD;
  const unsigned short* Vth = vt + (size_t)h * HD * SEQ;

  if (t < HD) q0[t] = h2f(Qh[t]);   // pre-scaled by 1/8
  __syncthreads();

  for (int j = t; j < SEQ; j += 256) {
    const unsigned short* Kp = Kh + (size_t)j * HD;
    float a0 = 0.f, a1 = 0.f;
    for (int d0 = 0; d0 < 8; d0++) {
      const bf16x8 kv = *(const bf16x8*)(Kp + d0 * 8);
#pragma unroll
      for (int e = 0; e < 8; e += 2) {
        a0 += q0[d0 * 8 + e]     * h2f((unsigned short)kv[e]);
        a1 += q0[d0 * 8 + e + 1] * h2f((unsigned short)kv[e + 1]);
      }
    }
    sc[j] = a0 + a1;
  }
  __syncthreads();

  float mx = -1e30f;
  for (int j = t; j < SEQ; j += 256) mx = fmaxf(mx, sc[j]);
  for (int d = 1; d < 64; d <<= 1) mx = fmaxf(mx, __shfl_xor(mx, d));
  if ((t & 63) == 0) red[t >> 6] = mx;
  __syncthreads();
  mx = fmaxf(fmaxf(red[0], red[1]), fmaxf(red[2], red[3]));
  __syncthreads();

  float sum = 0.f;
  for (int j = t; j < SEQ; j += 256) {
    const float p = __expf(sc[j] - mx);
    sc[j] = p;
    sum += p;
  }
  for (int d = 1; d < 64; d <<= 1) sum += __shfl_xor(sum, d);
  __syncthreads();
  if ((t & 63) == 0) red[t >> 6] = sum;
  __syncthreads();
  const float inv = 1.f / (red[0] + red[1] + red[2] + red[3]);

  const int dd = t & 63, part = t >> 6;
  const unsigned short* Vp = Vth + (size_t)dd * SEQ;   // row dd, contiguous in j
  float a0 = 0.f, a1 = 0.f, a2 = 0.f, a3 = 0.f;
  const int jb = part * 1024;
  for (int j = 0; j < 1024; j += 4) {
    a0 += sc[jb + j + 0] * h2f(Vp[jb + j + 0]);
    a1 += sc[jb + j + 1] * h2f(Vp[jb + j + 1]);
    a2 += sc[jb + j + 2] * h2f(Vp[jb + j + 2]);
    a3 += sc[jb + j + 3] * h2f(Vp[jb + j + 3]);
  }
  accl[part][dd] = (a0 + a1) + (a2 + a3);
  __syncthreads();
  if (part == 0) {
    const float v = (accl[0][dd] + accl[1][dd] + accl[2][dd] + accl[3][dd]) * inv;
    ctx[(size_t)h * HD + dd] = f2b(v);   // row 0 (bf16, like the band kernel)
  }
}

// ---------------- launch ----------------
extern "C" void kernel_launch(void* const* d_in, const int* in_sizes, int n_in,
                              void* d_out, int out_size, void* d_ws, size_t ws_size,
                              hipStream_t stream)
{
  (void)in_sizes; (void)n_in; (void)out_size; (void)ws_size;
  const float* x  = (const float*)d_in[0];
  const float* Wq = (const float*)d_in[1];
  const float* bq = (const float*)d_in[2];
  const float* Wk = (const float*)d_in[3];
  const float* bk = (const float*)d_in[4];
  const float* Wv = (const float*)d_in[5];
  const float* bv = (const float*)d_in[6];
  const float* Wo = (const float*)d_in[7];
  const float* bo = (const float*)d_in[8];
  float* out = (float*)d_out;

  char* ws = (char*)d_ws;
  unsigned short* xb   = (unsigned short*)(ws + 0);         // dead after gemm<0>
  unsigned short* wqkv = (unsigned short*)(ws + 6291456);
  unsigned short* wob  = (unsigned short*)(ws + 9830400);
  unsigned short* qbuf = (unsigned short*)(ws + 11010048);  // [12][4096][64] f16
  unsigned short* kbuf = (unsigned short*)(ws + 17301504);  // [12][4096][64] f16
  unsigned short* vtb  = (unsigned short*)(ws + 23592960);  // [12][64][4096] f16
  unsigned short* ctx  = (unsigned short*)(ws + 0);         // bf16, aliases xb

  convert_all<<<dim3(1024), dim3(256), 0, stream>>>(x, Wq, Wk, Wv, Wo, xb, wqkv, wob);
  gemm_bt<0><<<dim3(18, 32), dim3(256), 0, stream>>>(xb, wqkv, qbuf, kbuf, vtb,
                                                     bq, bk, bv, nullptr, nullptr);
  attn_band7<<<dim3(SEQ / 8, NH), dim3(512), 0, stream>>>(qbuf, kbuf, vtb, ctx);
  attn_global12<<<dim3(NH), dim3(256), 0, stream>>>(qbuf, kbuf, vtb, ctx);
  gemm_bt<1><<<dim3(6, 32), dim3(256), 0, stream>>>(ctx, wob, nullptr, nullptr, nullptr,
                                                    nullptr, nullptr, nullptr, bo, out);
}

// Round 18
// 233.200 us; speedup vs baseline: 41.2070x; 1.1372x over previous
//
#include <hip/hip_runtime.h>
#include <cstdint>

#define SEQ   4096
#define DM    768
#define NH    12
#define HD    64
#define KD    768

typedef float  f32x4  __attribute__((ext_vector_type(4)));
typedef short  bf16x8 __attribute__((ext_vector_type(8)));
typedef _Float16 h16x2 __attribute__((ext_vector_type(2)));
typedef unsigned int u32;

typedef __attribute__((address_space(1))) const unsigned int gu32;
typedef __attribute__((address_space(3))) unsigned int lu32;

__device__ __forceinline__ unsigned short f2b(float f) {
  unsigned int u = __builtin_bit_cast(unsigned int, f);
  u += 0x7fffu + ((u >> 16) & 1u);
  return (unsigned short)(u >> 16);
}
__device__ __forceinline__ float b2f(unsigned short s) {
  return __builtin_bit_cast(float, ((unsigned int)s) << 16);
}
__device__ __forceinline__ unsigned short f2h(float f) {
  _Float16 h = (_Float16)f;
  return __builtin_bit_cast(unsigned short, h);
}
__device__ __forceinline__ float h2f(unsigned short s) {
  return (float)__builtin_bit_cast(_Float16, s);
}

// packed f16 dot2 with f32 accumulator (v_dot2_f32_f16); scalar fallback
__device__ __forceinline__ float dot2f(u32 a, u32 b, float c) {
#if __has_builtin(__builtin_amdgcn_fdot2)
  return __builtin_amdgcn_fdot2(__builtin_bit_cast(h16x2, a),
                                __builtin_bit_cast(h16x2, b), c, false);
#else
  const h16x2 ha = __builtin_bit_cast(h16x2, a);
  const h16x2 hb = __builtin_bit_cast(h16x2, b);
  return c + (float)ha[0] * (float)hb[0] + (float)ha[1] * (float)hb[1];
#endif
}

__device__ __forceinline__ void gload_lds16(const void* g, void* l) {
  gu32* gp = reinterpret_cast<gu32*>(reinterpret_cast<uintptr_t>(g));
  lu32* lp = reinterpret_cast<lu32*>(reinterpret_cast<uintptr_t>(l));
  __builtin_amdgcn_global_load_lds(gp, lp, 16, 0, 0);
}

// ---------------- pack/convert: f32 -> bf16 (R3-verified) ----------------
__global__ void convert_all(const float* __restrict__ x,
                            const float* __restrict__ wq,
                            const float* __restrict__ wk,
                            const float* __restrict__ wv,
                            const float* __restrict__ wo,
                            unsigned short* __restrict__ xb,
                            unsigned short* __restrict__ wqkv,
                            unsigned short* __restrict__ wob)
{
  const int XN = SEQ * DM;
  const int WN = DM * DM;
  const int total4 = (XN + 4 * WN) >> 2;
  for (int i = blockIdx.x * blockDim.x + threadIdx.x; i < total4;
       i += gridDim.x * blockDim.x) {
    const int base = i << 2;
    const float* src;
    unsigned short* dst;
    if (base < XN)                 { src = x  + base;               dst = xb   + base; }
    else if (base < XN + WN)       { src = wq + (base - XN);        dst = wqkv + (base - XN); }
    else if (base < XN + 2 * WN)   { src = wk + (base - XN - WN);   dst = wqkv + (base - XN); }
    else if (base < XN + 3 * WN)   { src = wv + (base - XN - 2*WN); dst = wqkv + (base - XN); }
    else                           { src = wo + (base - XN - 3*WN); dst = wob  + (base - XN - 3*WN); }
    const float4 v = *(const float4*)src;
    *(ushort4*)dst = make_ushort4(f2b(v.x), f2b(v.y), f2b(v.z), f2b(v.w));
  }
}

// ---------------- GEMM C = A[M,K] * B[N,K]^T (R3-verified, bf16 MFMA) --------
// EPI 0: Q/K row-major f16; V written TRANSPOSED [h][dk][s] f16 (R2≡R4 verified)
template<int EPI>
__global__ __launch_bounds__(256, 2)
void gemm_bt(const unsigned short* __restrict__ A,
             const unsigned short* __restrict__ B,
             unsigned short* __restrict__ qb,
             unsigned short* __restrict__ kb,
             unsigned short* __restrict__ vt,
             const float* __restrict__ bq,
             const float* __restrict__ bk,
             const float* __restrict__ bv,
             const float* __restrict__ bo,
             float* __restrict__ outf)
{
  __shared__ __align__(16) unsigned short As[128 * 32];
  __shared__ __align__(16) unsigned short Bs[128 * 32];
  const int t  = threadIdx.x;
  const int w  = t >> 6;
  const int l  = t & 63;
  const int m0 = blockIdx.y * 128;
  const int n0 = blockIdx.x * 128;
  const int wr = (w >> 1) * 64;
  const int wc = (w & 1) * 64;
  const int lr = l & 15;
  const int lk = (l >> 4) * 8;

  const int row1 = t >> 2;
  const int row2 = row1 + 64;
  const int seg  = t & 3;

  f32x4 acc[4][4];
#pragma unroll
  for (int i = 0; i < 4; i++)
#pragma unroll
    for (int j = 0; j < 4; j++) acc[i][j] = (f32x4){0.f, 0.f, 0.f, 0.f};

  char* ldsA0 = (char*)As + (size_t)(w * 64) * 16;
  char* ldsA1 = (char*)As + (size_t)(w * 64 + 256) * 16;
  char* ldsB0 = (char*)Bs + (size_t)(w * 64) * 16;
  char* ldsB1 = (char*)Bs + (size_t)(w * 64 + 256) * 16;

  for (int k0 = 0; k0 < KD; k0 += 32) {
    gload_lds16(A + (size_t)(m0 + row1) * KD + k0 + seg * 8, ldsA0);
    gload_lds16(A + (size_t)(m0 + row2) * KD + k0 + seg * 8, ldsA1);
    gload_lds16(B + (size_t)(n0 + row1) * KD + k0 + seg * 8, ldsB0);
    gload_lds16(B + (size_t)(n0 + row2) * KD + k0 + seg * 8, ldsB1);
    __syncthreads();
    bf16x8 af[4], bfv[4];
#pragma unroll
    for (int fi = 0; fi < 4; fi++)
      af[fi] = *(const bf16x8*)(As + (wr + fi * 16 + lr) * 32 + lk);
#pragma unroll
    for (int fj = 0; fj < 4; fj++)
      bfv[fj] = *(const bf16x8*)(Bs + (wc + fj * 16 + lr) * 32 + lk);
#pragma unroll
    for (int fi = 0; fi < 4; fi++)
#pragma unroll
      for (int fj = 0; fj < 4; fj++)
        acc[fi][fj] = __builtin_amdgcn_mfma_f32_16x16x32_bf16(af[fi], bfv[fj], acc[fi][fj], 0, 0, 0);
    __syncthreads();
  }

#pragma unroll
  for (int fi = 0; fi < 4; fi++) {
    const int mbase = m0 + wr + fi * 16 + (l >> 4) * 4;
#pragma unroll
    for (int fj = 0; fj < 4; fj++) {
      const int n = n0 + wc + fj * 16 + lr;
      if (EPI == 1) {
        const float bb = bo[n];
#pragma unroll
        for (int r = 0; r < 4; r++)
          outf[(size_t)(mbase + r) * DM + n] = acc[fi][fj][r] + bb;
      } else if (n < DM) {                       // Q (scaled by 1/8) -> f16
        const int hh = n >> 6, dk = n & 63;
        const float bb = bq[n];
#pragma unroll
        for (int r = 0; r < 4; r++)
          qb[((size_t)hh * SEQ + mbase + r) * HD + dk] = f2h((acc[fi][fj][r] + bb) * 0.125f);
      } else if (n < 2 * DM) {                   // K row-major [h][s][dk] -> f16
        const int n2 = n - DM, hh = n2 >> 6, dk = n2 & 63;
        const float bb = bk[n2];
#pragma unroll
        for (int r = 0; r < 4; r++)
          kb[((size_t)hh * SEQ + mbase + r) * HD + dk] = f2h(acc[fi][fj][r] + bb);
      } else {                                   // V -> transposed [h][dk][s] f16
        const int n3 = n - 2 * DM, hh = n3 >> 6, dk = n3 & 63;
        const float bb = bv[n3];
        ushort4 ov = make_ushort4(f2h(acc[fi][fj][0] + bb), f2h(acc[fi][fj][1] + bb),
                                  f2h(acc[fi][fj][2] + bb), f2h(acc[fi][fj][3] + bb));
        *(ushort4*)(vt + ((size_t)hh * HD + dk) * SEQ + mbase) = ov;
      }
    }
  }
}

// ------ band attention: 2 QUERIES PER WAVE, 4 waves/block, dbuf LDS ----------
// Each K/V uint4 LDS read feeds dot2s for TWO queries -> LDS-pipe traffic
// per dot halves (R17 was LDS-read-throughput-bound at ~154us).
// Defer-max softmax (R16-verified). Swizzle invariant (R13-verified).
// mask: valid = (qi==0)||(j==0)||(|qi-j|<=256). Row 0 overwritten after.
__global__ __launch_bounds__(256)
void attn_band8(const unsigned short* __restrict__ qb,
                const unsigned short* __restrict__ kb,
                const unsigned short* __restrict__ vt,
                unsigned short* __restrict__ ctx)
{
  __shared__ __align__(16) unsigned short Ks[2][64 * 64];
  __shared__ __align__(16) unsigned short Vts[2][64 * 64];
  __shared__ __align__(16) unsigned short plds[8][64];   // P as f16, 2 lines/wave
  const int h    = blockIdx.y;
  const int B    = blockIdx.x;          // queries B*8 .. B*8+7
  const int t    = threadIdx.x;
  const int w    = t >> 6;
  const int lane = t & 63;
  const int qiA  = B * 8 + w * 2;
  const int qiB  = qiA + 1;

  const unsigned short* Qh  = qb + (size_t)h * SEQ * HD;
  const unsigned short* Kh  = kb + (size_t)h * SEQ * HD;
  const unsigned short* Vth = vt + (size_t)h * HD * SEQ;

  const int srow = t >> 3;                  // 0..31; (srow+32)&7 == srow&7
  const int scol = (t & 7) ^ (srow & 7);    // pre-swizzled source 16B-slot
  const int swz  = lane & 7;                // read-side XOR for row=lane

  // two q rows (f16, pre-scaled by 1/8) -> 2 x 32 packed half2 regs
  h16x2 qpA[32], qpB[32];
  {
    const u32* QA = (const u32*)(Qh + (size_t)qiA * HD);
    const u32* QB = (const u32*)(Qh + (size_t)qiB * HD);
#pragma unroll
    for (int i = 0; i < 32; i++) {
      qpA[i] = __builtin_bit_cast(h16x2, QA[i]);
      qpB[i] = __builtin_bit_cast(h16x2, QB[i]);
    }
  }

  // union chunk range for the block's 8 queries; chunk 0 prepended if absent
  int lo = B * 8 - 256; if (lo < 0) lo = 0;
  int hi = B * 8 + 7 + 257; if (hi > SEQ) hi = SEQ;
  const int cbeg = lo >> 6, cend = (hi - 1) >> 6;
  const int pre  = (cbeg > 0) ? 1 : 0;
  const int nch  = cend - cbeg + 1 + pre;

  auto chunkof = [&](int it) -> int {
    return (pre && it == 0) ? 0 : (cbeg + it - pre);
  };
  auto stage = [&](int bsel, int cch) {
    const int jj0 = cch * 64;
    char* kbase = (char*)(&Ks[bsel][0]);
    char* vbase = (char*)(&Vts[bsel][0]);
    gload_lds16(Kh + (size_t)(jj0 + srow) * HD + scol * 8,
                kbase + (size_t)(w * 64) * 16);
    gload_lds16(Kh + (size_t)(jj0 + 32 + srow) * HD + scol * 8,
                kbase + (size_t)(w * 64 + 256) * 16);
    gload_lds16(Vth + (size_t)srow * SEQ + jj0 + scol * 8,
                vbase + (size_t)(w * 64) * 16);
    gload_lds16(Vth + (size_t)(32 + srow) * SEQ + jj0 + scol * 8,
                vbase + (size_t)(w * 64 + 256) * 16);
  };

  stage(0, chunkof(0));
  __syncthreads();

  float oA = 0.f, mA = -1e30f, lsA = 0.f;
  float oB = 0.f, mB = -1e30f, lsB = 0.f;

  for (int it = 0; it < nch; ++it) {
    if (it + 1 < nch) stage((it + 1) & 1, chunkof(it + 1));  // async prefetch

    const int c  = chunkof(it);
    const int j0 = c * 64;
    const unsigned short* Kp = &Ks[it & 1][0] + lane * 64;
    const unsigned short* Vp = &Vts[it & 1][0] + lane * 64;

    // ---- s_j = q . k_j for BOTH queries from one K read stream
    float sA0 = 0.f, sA1 = 0.f, sA2 = 0.f, sA3 = 0.f;
    float sB0 = 0.f, sB1 = 0.f, sB2 = 0.f, sB3 = 0.f;
#pragma unroll
    for (int d0 = 0; d0 < 8; d0++) {
      const uint4 kv = *(const uint4*)(Kp + ((d0 ^ swz) * 8));  // contents: block d0
      const int qb4 = d0 * 4;                                   // contents index
      sA0 = dot2f(kv.x, __builtin_bit_cast(u32, qpA[qb4 + 0]), sA0);
      sA1 = dot2f(kv.y, __builtin_bit_cast(u32, qpA[qb4 + 1]), sA1);
      sA2 = dot2f(kv.z, __builtin_bit_cast(u32, qpA[qb4 + 2]), sA2);
      sA3 = dot2f(kv.w, __builtin_bit_cast(u32, qpA[qb4 + 3]), sA3);
      sB0 = dot2f(kv.x, __builtin_bit_cast(u32, qpB[qb4 + 0]), sB0);
      sB1 = dot2f(kv.y, __builtin_bit_cast(u32, qpB[qb4 + 1]), sB1);
      sB2 = dot2f(kv.z, __builtin_bit_cast(u32, qpB[qb4 + 2]), sB2);
      sB3 = dot2f(kv.w, __builtin_bit_cast(u32, qpB[qb4 + 3]), sB3);
    }
    float sA = (sA0 + sA1) + (sA2 + sA3);
    float sB = (sB0 + sB1) + (sB2 + sB3);
    const int j = j0 + lane;
    const bool vA = (qiA == 0) || (j == 0) ||
                    ((j - qiA) <= 256 && (qiA - j) <= 256);
    const bool vB = (j == 0) || ((j - qiB) <= 256 && (qiB - j) <= 256);
    sA = vA ? sA : -1e30f;
    sB = vB ? sB : -1e30f;

    // ---- defer-max online softmax, per query
    if (__any(sA > mA + 8.f)) {
      float mx = sA;
      for (int d = 1; d < 64; d <<= 1) mx = fmaxf(mx, __shfl_xor(mx, d));
      const float mnew = fmaxf(mA, mx);
      const float esc  = __expf(mA - mnew);
      lsA *= esc; oA *= esc; mA = mnew;
    }
    if (__any(sB > mB + 8.f)) {
      float mx = sB;
      for (int d = 1; d < 64; d <<= 1) mx = fmaxf(mx, __shfl_xor(mx, d));
      const float mnew = fmaxf(mB, mx);
      const float esc  = __expf(mB - mnew);
      lsB *= esc; oB *= esc; mB = mnew;
    }
    const float pA = __expf(sA - mA);   // bounded by e^8
    const float pB = __expf(sB - mB);
    lsA += pA;
    lsB += pB;

    // ---- p (f16) -> wave LDS lines; PV for BOTH queries from one V stream
    plds[w * 2 + 0][lane] = f2h(pA);
    plds[w * 2 + 1][lane] = f2h(pB);
    float aA0 = 0.f, aA1 = 0.f, aA2 = 0.f, aA3 = 0.f;
    float aB0 = 0.f, aB1 = 0.f, aB2 = 0.f, aB3 = 0.f;
#pragma unroll
    for (int q8 = 0; q8 < 8; q8++) {
      const uint4 vv  = *(const uint4*)(Vp + ((q8 ^ swz) * 8)); // contents: block q8
      const uint4 pqA = *(const uint4*)&plds[w * 2 + 0][q8 * 8];
      const uint4 pqB = *(const uint4*)&plds[w * 2 + 1][q8 * 8];
      aA0 = dot2f(vv.x, pqA.x, aA0);
      aA1 = dot2f(vv.y, pqA.y, aA1);
      aA2 = dot2f(vv.z, pqA.z, aA2);
      aA3 = dot2f(vv.w, pqA.w, aA3);
      aB0 = dot2f(vv.x, pqB.x, aB0);
      aB1 = dot2f(vv.y, pqB.y, aB1);
      aB2 = dot2f(vv.z, pqB.z, aB2);
      aB3 = dot2f(vv.w, pqB.w, aB3);
    }
    oA += (aA0 + aA1) + (aA2 + aA3);
    oB += (aB0 + aB1) + (aB2 + aB3);

    __syncthreads();   // prefetch landed + all waves done with buf[it&1]
  }

  // final: butterfly reduce per-lane lsum partials (once per query)
  for (int d = 1; d < 64; d <<= 1) lsA += __shfl_xor(lsA, d);
  for (int d = 1; d < 64; d <<= 1) lsB += __shfl_xor(lsB, d);

  ctx[(size_t)qiA * DM + h * HD + lane] = f2b(oA / lsA);
  ctx[(size_t)qiB * DM + h * HD + lane] = f2b(oB / lsB);
}

// ---------------- global row: query 0 attends to ALL keys (V^T input) --------
__global__ __launch_bounds__(256)
void attn_global12(const unsigned short* __restrict__ qb,
                   const unsigned short* __restrict__ kb,
                   const unsigned short* __restrict__ vt,
                   unsigned short* __restrict__ ctx)
{
  __shared__ float sc[SEQ];
  __shared__ float q0[HD];
  __shared__ float red[4];
  __shared__ float accl[4][HD];
  const int t = threadIdx.x;
  const int h = blockIdx.x;
  const unsigned short* Qh  = qb + (size_t)h * SEQ * HD;
  const unsigned short* Kh  = kb + (size_t)h * SEQ * HD;
  const unsigned short* Vth = vt + (size_t)h * HD * SEQ;

  if (t < HD) q0[t] = h2f(Qh[t]);   // pre-scaled by 1/8
  __syncthreads();

  for (int j = t; j < SEQ; j += 256) {
    const unsigned short* Kp = Kh + (size_t)j * HD;
    float a0 = 0.f, a1 = 0.f;
    for (int d0 = 0; d0 < 8; d0++) {
      const bf16x8 kv = *(const bf16x8*)(Kp + d0 * 8);
#pragma unroll
      for (int e = 0; e < 8; e += 2) {
        a0 += q0[d0 * 8 + e]     * h2f((unsigned short)kv[e]);
        a1 += q0[d0 * 8 + e + 1] * h2f((unsigned short)kv[e + 1]);
      }
    }
    sc[j] = a0 + a1;
  }
  __syncthreads();

  float mx = -1e30f;
  for (int j = t; j < SEQ; j += 256) mx = fmaxf(mx, sc[j]);
  for (int d = 1; d < 64; d <<= 1) mx = fmaxf(mx, __shfl_xor(mx, d));
  if ((t & 63) == 0) red[t >> 6] = mx;
  __syncthreads();
  mx = fmaxf(fmaxf(red[0], red[1]), fmaxf(red[2], red[3]));
  __syncthreads();

  float sum = 0.f;
  for (int j = t; j < SEQ; j += 256) {
    const float p = __expf(sc[j] - mx);
    sc[j] = p;
    sum += p;
  }
  for (int d = 1; d < 64; d <<= 1) sum += __shfl_xor(sum, d);
  __syncthreads();
  if ((t & 63) == 0) red[t >> 6] = sum;
  __syncthreads();
  const float inv = 1.f / (red[0] + red[1] + red[2] + red[3]);

  const int dd = t & 63, part = t >> 6;
  const unsigned short* Vp = Vth + (size_t)dd * SEQ;   // row dd, contiguous in j
  float a0 = 0.f, a1 = 0.f, a2 = 0.f, a3 = 0.f;
  const int jb = part * 1024;
  for (int j = 0; j < 1024; j += 4) {
    a0 += sc[jb + j + 0] * h2f(Vp[jb + j + 0]);
    a1 += sc[jb + j + 1] * h2f(Vp[jb + j + 1]);
    a2 += sc[jb + j + 2] * h2f(Vp[jb + j + 2]);
    a3 += sc[jb + j + 3] * h2f(Vp[jb + j + 3]);
  }
  accl[part][dd] = (a0 + a1) + (a2 + a3);
  __syncthreads();
  if (part == 0) {
    const float v = (accl[0][dd] + accl[1][dd] + accl[2][dd] + accl[3][dd]) * inv;
    ctx[(size_t)h * HD + dd] = f2b(v);   // row 0 (bf16, like the band kernel)
  }
}

// ---------------- launch ----------------
extern "C" void kernel_launch(void* const* d_in, const int* in_sizes, int n_in,
                              void* d_out, int out_size, void* d_ws, size_t ws_size,
                              hipStream_t stream)
{
  (void)in_sizes; (void)n_in; (void)out_size; (void)ws_size;
  const float* x  = (const float*)d_in[0];
  const float* Wq = (const float*)d_in[1];
  const float* bq = (const float*)d_in[2];
  const float* Wk = (const float*)d_in[3];
  const float* bk = (const float*)d_in[4];
  const float* Wv = (const float*)d_in[5];
  const float* bv = (const float*)d_in[6];
  const float* Wo = (const float*)d_in[7];
  const float* bo = (const float*)d_in[8];
  float* out = (float*)d_out;

  char* ws = (char*)d_ws;
  unsigned short* xb   = (unsigned short*)(ws + 0);         // dead after gemm<0>
  unsigned short* wqkv = (unsigned short*)(ws + 6291456);
  unsigned short* wob  = (unsigned short*)(ws + 9830400);
  unsigned short* qbuf = (unsigned short*)(ws + 11010048);  // [12][4096][64] f16
  unsigned short* kbuf = (unsigned short*)(ws + 17301504);  // [12][4096][64] f16
  unsigned short* vtb  = (unsigned short*)(ws + 23592960);  // [12][64][4096] f16
  unsigned short* ctx  = (unsigned short*)(ws + 0);         // bf16, aliases xb

  convert_all<<<dim3(1024), dim3(256), 0, stream>>>(x, Wq, Wk, Wv, Wo, xb, wqkv, wob);
  gemm_bt<0><<<dim3(18, 32), dim3(256), 0, stream>>>(xb, wqkv, qbuf, kbuf, vtb,
                                                     bq, bk, bv, nullptr, nullptr);
  attn_band8<<<dim3(SEQ / 8, NH), dim3(256), 0, stream>>>(qbuf, kbuf, vtb, ctx);
  attn_global12<<<dim3(NH), dim3(256), 0, stream>>>(qbuf, kbuf, vtb, ctx);
  gemm_bt<1><<<dim3(6, 32), dim3(256), 0, stream>>>(ctx, wob, nullptr, nullptr, nullptr,
                                                    nullptr, nullptr, nullptr, bo, out);
}

// Round 19
// 227.535 us; speedup vs baseline: 42.2330x; 1.0249x over previous
//
#include <hip/hip_runtime.h>
#include <cstdint>

#define SEQ   4096
#define DM    768
#define NH    12
#define HD    64
#define KD    768

typedef float  f32x4  __attribute__((ext_vector_type(4)));
typedef short  bf16x8 __attribute__((ext_vector_type(8)));
typedef _Float16 h16x2 __attribute__((ext_vector_type(2)));
typedef unsigned int u32;

typedef __attribute__((address_space(1))) const unsigned int gu32;
typedef __attribute__((address_space(3))) unsigned int lu32;

__device__ __forceinline__ unsigned short f2b(float f) {
  unsigned int u = __builtin_bit_cast(unsigned int, f);
  u += 0x7fffu + ((u >> 16) & 1u);
  return (unsigned short)(u >> 16);
}
__device__ __forceinline__ float b2f(unsigned short s) {
  return __builtin_bit_cast(float, ((unsigned int)s) << 16);
}
__device__ __forceinline__ unsigned short f2h(float f) {
  _Float16 h = (_Float16)f;
  return __builtin_bit_cast(unsigned short, h);
}
__device__ __forceinline__ float h2f(unsigned short s) {
  return (float)__builtin_bit_cast(_Float16, s);
}

// packed f16 dot2 with f32 accumulator (v_dot2_f32_f16); scalar fallback
__device__ __forceinline__ float dot2f(u32 a, u32 b, float c) {
#if __has_builtin(__builtin_amdgcn_fdot2)
  return __builtin_amdgcn_fdot2(__builtin_bit_cast(h16x2, a),
                                __builtin_bit_cast(h16x2, b), c, false);
#else
  const h16x2 ha = __builtin_bit_cast(h16x2, a);
  const h16x2 hb = __builtin_bit_cast(h16x2, b);
  return c + (float)ha[0] * (float)hb[0] + (float)ha[1] * (float)hb[1];
#endif
}

__device__ __forceinline__ void gload_lds16(const void* g, void* l) {
  gu32* gp = reinterpret_cast<gu32*>(reinterpret_cast<uintptr_t>(g));
  lu32* lp = reinterpret_cast<lu32*>(reinterpret_cast<uintptr_t>(l));
  __builtin_amdgcn_global_load_lds(gp, lp, 16, 0, 0);
}

// ---------------- pack/convert: f32 -> bf16 (R3-verified) ----------------
__global__ void convert_all(const float* __restrict__ x,
                            const float* __restrict__ wq,
                            const float* __restrict__ wk,
                            const float* __restrict__ wv,
                            const float* __restrict__ wo,
                            unsigned short* __restrict__ xb,
                            unsigned short* __restrict__ wqkv,
                            unsigned short* __restrict__ wob)
{
  const int XN = SEQ * DM;
  const int WN = DM * DM;
  const int total4 = (XN + 4 * WN) >> 2;
  for (int i = blockIdx.x * blockDim.x + threadIdx.x; i < total4;
       i += gridDim.x * blockDim.x) {
    const int base = i << 2;
    const float* src;
    unsigned short* dst;
    if (base < XN)                 { src = x  + base;               dst = xb   + base; }
    else if (base < XN + WN)       { src = wq + (base - XN);        dst = wqkv + (base - XN); }
    else if (base < XN + 2 * WN)   { src = wk + (base - XN - WN);   dst = wqkv + (base - XN); }
    else if (base < XN + 3 * WN)   { src = wv + (base - XN - 2*WN); dst = wqkv + (base - XN); }
    else                           { src = wo + (base - XN - 3*WN); dst = wob  + (base - XN - 3*WN); }
    const float4 v = *(const float4*)src;
    *(ushort4*)dst = make_ushort4(f2b(v.x), f2b(v.y), f2b(v.z), f2b(v.w));
  }
}

// ---------------- GEMM C = A[M,K] * B[N,K]^T (R3-verified, bf16 MFMA) --------
// EPI 0: Q/K row-major f16; V written TRANSPOSED [h][dk][s] f16 (R2≡R4 verified)
template<int EPI>
__global__ __launch_bounds__(256, 2)
void gemm_bt(const unsigned short* __restrict__ A,
             const unsigned short* __restrict__ B,
             unsigned short* __restrict__ qb,
             unsigned short* __restrict__ kb,
             unsigned short* __restrict__ vt,
             const float* __restrict__ bq,
             const float* __restrict__ bk,
             const float* __restrict__ bv,
             const float* __restrict__ bo,
             float* __restrict__ outf)
{
  __shared__ __align__(16) unsigned short As[128 * 32];
  __shared__ __align__(16) unsigned short Bs[128 * 32];
  const int t  = threadIdx.x;
  const int w  = t >> 6;
  const int l  = t & 63;
  const int m0 = blockIdx.y * 128;
  const int n0 = blockIdx.x * 128;
  const int wr = (w >> 1) * 64;
  const int wc = (w & 1) * 64;
  const int lr = l & 15;
  const int lk = (l >> 4) * 8;

  const int row1 = t >> 2;
  const int row2 = row1 + 64;
  const int seg  = t & 3;

  f32x4 acc[4][4];
#pragma unroll
  for (int i = 0; i < 4; i++)
#pragma unroll
    for (int j = 0; j < 4; j++) acc[i][j] = (f32x4){0.f, 0.f, 0.f, 0.f};

  char* ldsA0 = (char*)As + (size_t)(w * 64) * 16;
  char* ldsA1 = (char*)As + (size_t)(w * 64 + 256) * 16;
  char* ldsB0 = (char*)Bs + (size_t)(w * 64) * 16;
  char* ldsB1 = (char*)Bs + (size_t)(w * 64 + 256) * 16;

  for (int k0 = 0; k0 < KD; k0 += 32) {
    gload_lds16(A + (size_t)(m0 + row1) * KD + k0 + seg * 8, ldsA0);
    gload_lds16(A + (size_t)(m0 + row2) * KD + k0 + seg * 8, ldsA1);
    gload_lds16(B + (size_t)(n0 + row1) * KD + k0 + seg * 8, ldsB0);
    gload_lds16(B + (size_t)(n0 + row2) * KD + k0 + seg * 8, ldsB1);
    __syncthreads();
    bf16x8 af[4], bfv[4];
#pragma unroll
    for (int fi = 0; fi < 4; fi++)
      af[fi] = *(const bf16x8*)(As + (wr + fi * 16 + lr) * 32 + lk);
#pragma unroll
    for (int fj = 0; fj < 4; fj++)
      bfv[fj] = *(const bf16x8*)(Bs + (wc + fj * 16 + lr) * 32 + lk);
#pragma unroll
    for (int fi = 0; fi < 4; fi++)
#pragma unroll
      for (int fj = 0; fj < 4; fj++)
        acc[fi][fj] = __builtin_amdgcn_mfma_f32_16x16x32_bf16(af[fi], bfv[fj], acc[fi][fj], 0, 0, 0);
    __syncthreads();
  }

#pragma unroll
  for (int fi = 0; fi < 4; fi++) {
    const int mbase = m0 + wr + fi * 16 + (l >> 4) * 4;
#pragma unroll
    for (int fj = 0; fj < 4; fj++) {
      const int n = n0 + wc + fj * 16 + lr;
      if (EPI == 1) {
        const float bb = bo[n];
#pragma unroll
        for (int r = 0; r < 4; r++)
          outf[(size_t)(mbase + r) * DM + n] = acc[fi][fj][r] + bb;
      } else if (n < DM) {                       // Q (scaled by 1/8) -> f16
        const int hh = n >> 6, dk = n & 63;
        const float bb = bq[n];
#pragma unroll
        for (int r = 0; r < 4; r++)
          qb[((size_t)hh * SEQ + mbase + r) * HD + dk] = f2h((acc[fi][fj][r] + bb) * 0.125f);
      } else if (n < 2 * DM) {                   // K row-major [h][s][dk] -> f16
        const int n2 = n - DM, hh = n2 >> 6, dk = n2 & 63;
        const float bb = bk[n2];
#pragma unroll
        for (int r = 0; r < 4; r++)
          kb[((size_t)hh * SEQ + mbase + r) * HD + dk] = f2h(acc[fi][fj][r] + bb);
      } else {                                   // V -> transposed [h][dk][s] f16
        const int n3 = n - 2 * DM, hh = n3 >> 6, dk = n3 & 63;
        const float bb = bv[n3];
        ushort4 ov = make_ushort4(f2h(acc[fi][fj][0] + bb), f2h(acc[fi][fj][1] + bb),
                                  f2h(acc[fi][fj][2] + bb), f2h(acc[fi][fj][3] + bb));
        *(ushort4*)(vt + ((size_t)hh * HD + dk) * SEQ + mbase) = ov;
      }
    }
  }
}

// ------ band attention: 4 QUERIES PER WAVE, 4 waves/block, dbuf LDS ----------
// Each K/V uint4 LDS read feeds dot2s for FOUR queries (tile traffic/query
// halves vs R18). Defer-max softmax (R16-verified); swizzle (R13-verified).
// mask: valid = (qi==0)||(j==0)||(|qi-j|<=256). Row 0 overwritten after.
__global__ __launch_bounds__(256, 2)
void attn_band9(const unsigned short* __restrict__ qb,
                const unsigned short* __restrict__ kb,
                const unsigned short* __restrict__ vt,
                unsigned short* __restrict__ ctx)
{
  __shared__ __align__(16) unsigned short Ks[2][64 * 64];
  __shared__ __align__(16) unsigned short Vts[2][64 * 64];
  __shared__ __align__(16) unsigned short plds[16][64];   // P f16, 4 lines/wave
  const int h    = blockIdx.y;
  const int B    = blockIdx.x;          // queries B*16 .. B*16+15
  const int t    = threadIdx.x;
  const int w    = t >> 6;
  const int lane = t & 63;
  const int qi0  = B * 16 + w * 4;      // this wave's 4 queries

  const unsigned short* Qh  = qb + (size_t)h * SEQ * HD;
  const unsigned short* Kh  = kb + (size_t)h * SEQ * HD;
  const unsigned short* Vth = vt + (size_t)h * HD * SEQ;

  const int srow = t >> 3;                  // 0..31; (srow+32)&7 == srow&7
  const int scol = (t & 7) ^ (srow & 7);    // pre-swizzled source 16B-slot
  const int swz  = lane & 7;                // read-side XOR for row=lane

  // four q rows (f16, pre-scaled by 1/8) -> 4 x 32 packed half2 regs
  h16x2 qp[4][32];
#pragma unroll
  for (int qq = 0; qq < 4; qq++) {
    const u32* Qp32 = (const u32*)(Qh + (size_t)(qi0 + qq) * HD);
#pragma unroll
    for (int i = 0; i < 32; i++) qp[qq][i] = __builtin_bit_cast(h16x2, Qp32[i]);
  }

  // union chunk range for the block's 16 queries; chunk 0 prepended if absent
  int lo = B * 16 - 256; if (lo < 0) lo = 0;
  int hi = B * 16 + 15 + 257; if (hi > SEQ) hi = SEQ;
  const int cbeg = lo >> 6, cend = (hi - 1) >> 6;
  const int pre  = (cbeg > 0) ? 1 : 0;
  const int nch  = cend - cbeg + 1 + pre;

  auto chunkof = [&](int it) -> int {
    return (pre && it == 0) ? 0 : (cbeg + it - pre);
  };
  auto stage = [&](int bsel, int cch) {
    const int jj0 = cch * 64;
    char* kbase = (char*)(&Ks[bsel][0]);
    char* vbase = (char*)(&Vts[bsel][0]);
    gload_lds16(Kh + (size_t)(jj0 + srow) * HD + scol * 8,
                kbase + (size_t)(w * 64) * 16);
    gload_lds16(Kh + (size_t)(jj0 + 32 + srow) * HD + scol * 8,
                kbase + (size_t)(w * 64 + 256) * 16);
    gload_lds16(Vth + (size_t)srow * SEQ + jj0 + scol * 8,
                vbase + (size_t)(w * 64) * 16);
    gload_lds16(Vth + (size_t)(32 + srow) * SEQ + jj0 + scol * 8,
                vbase + (size_t)(w * 64 + 256) * 16);
  };

  stage(0, chunkof(0));
  __syncthreads();

  float o[4]  = {0.f, 0.f, 0.f, 0.f};
  float m[4]  = {-1e30f, -1e30f, -1e30f, -1e30f};
  float ls[4] = {0.f, 0.f, 0.f, 0.f};

  for (int it = 0; it < nch; ++it) {
    if (it + 1 < nch) stage((it + 1) & 1, chunkof(it + 1));  // async prefetch

    const int c  = chunkof(it);
    const int j0 = c * 64;
    const unsigned short* Kp = &Ks[it & 1][0] + lane * 64;
    const unsigned short* Vp = &Vts[it & 1][0] + lane * 64;

    // ---- s_j = q . k_j for FOUR queries from one K read stream
    float sa[4][4];
#pragma unroll
    for (int qq = 0; qq < 4; qq++)
#pragma unroll
      for (int e = 0; e < 4; e++) sa[qq][e] = 0.f;
#pragma unroll
    for (int d0 = 0; d0 < 8; d0++) {
      const uint4 kv = *(const uint4*)(Kp + ((d0 ^ swz) * 8));  // contents: block d0
      const int qb4 = d0 * 4;                                   // contents index
#pragma unroll
      for (int qq = 0; qq < 4; qq++) {
        sa[qq][0] = dot2f(kv.x, __builtin_bit_cast(u32, qp[qq][qb4 + 0]), sa[qq][0]);
        sa[qq][1] = dot2f(kv.y, __builtin_bit_cast(u32, qp[qq][qb4 + 1]), sa[qq][1]);
        sa[qq][2] = dot2f(kv.z, __builtin_bit_cast(u32, qp[qq][qb4 + 2]), sa[qq][2]);
        sa[qq][3] = dot2f(kv.w, __builtin_bit_cast(u32, qp[qq][qb4 + 3]), sa[qq][3]);
      }
    }
    const int j = j0 + lane;

    // ---- mask + defer-max softmax + P store, per query (static unroll)
    float p[4];
#pragma unroll
    for (int qq = 0; qq < 4; qq++) {
      const int qi = qi0 + qq;
      float s = (sa[qq][0] + sa[qq][1]) + (sa[qq][2] + sa[qq][3]);
      const bool valid = (qi == 0) || (j == 0) ||
                         ((j - qi) <= 256 && (qi - j) <= 256);
      s = valid ? s : -1e30f;
      if (__any(s > m[qq] + 8.f)) {
        float mx = s;
        for (int d = 1; d < 64; d <<= 1) mx = fmaxf(mx, __shfl_xor(mx, d));
        const float mnew = fmaxf(m[qq], mx);
        const float esc  = __expf(m[qq] - mnew);
        ls[qq] *= esc; o[qq] *= esc; m[qq] = mnew;
      }
      p[qq] = __expf(s - m[qq]);   // bounded by e^8
      ls[qq] += p[qq];
      plds[w * 4 + qq][lane] = f2h(p[qq]);
    }

    // ---- PV for FOUR queries from one V read stream (lane = dim d)
    float aa[4][4];
#pragma unroll
    for (int qq = 0; qq < 4; qq++)
#pragma unroll
      for (int e = 0; e < 4; e++) aa[qq][e] = 0.f;
#pragma unroll
    for (int q8 = 0; q8 < 8; q8++) {
      const uint4 vv = *(const uint4*)(Vp + ((q8 ^ swz) * 8));  // contents: block q8
#pragma unroll
      for (int qq = 0; qq < 4; qq++) {
        const uint4 pq = *(const uint4*)&plds[w * 4 + qq][q8 * 8];
        aa[qq][0] = dot2f(vv.x, pq.x, aa[qq][0]);
        aa[qq][1] = dot2f(vv.y, pq.y, aa[qq][1]);
        aa[qq][2] = dot2f(vv.z, pq.z, aa[qq][2]);
        aa[qq][3] = dot2f(vv.w, pq.w, aa[qq][3]);
      }
    }
#pragma unroll
    for (int qq = 0; qq < 4; qq++)
      o[qq] += (aa[qq][0] + aa[qq][1]) + (aa[qq][2] + aa[qq][3]);

    __syncthreads();   // prefetch landed + all waves done with buf[it&1]
  }

  // final: butterfly reduce per-lane lsum partials (once per query)
#pragma unroll
  for (int qq = 0; qq < 4; qq++) {
    float l = ls[qq];
    for (int d = 1; d < 64; d <<= 1) l += __shfl_xor(l, d);
    ctx[(size_t)(qi0 + qq) * DM + h * HD + lane] = f2b(o[qq] / l);
  }
}

// ---------------- global row: query 0 attends to ALL keys (V^T input) --------
__global__ __launch_bounds__(256)
void attn_global12(const unsigned short* __restrict__ qb,
                   const unsigned short* __restrict__ kb,
                   const unsigned short* __restrict__ vt,
                   unsigned short* __restrict__ ctx)
{
  __shared__ float sc[SEQ];
  __shared__ float q0[HD];
  __shared__ float red[4];
  __shared__ float accl[4][HD];
  const int t = threadIdx.x;
  const int h = blockIdx.x;
  const unsigned short* Qh  = qb + (size_t)h * SEQ * HD;
  const unsigned short* Kh  = kb + (size_t)h * SEQ * HD;
  const unsigned short* Vth = vt + (size_t)h * HD * SEQ;

  if (t < HD) q0[t] = h2f(Qh[t]);   // pre-scaled by 1/8
  __syncthreads();

  for (int j = t; j < SEQ; j += 256) {
    const unsigned short* Kp = Kh + (size_t)j * HD;
    float a0 = 0.f, a1 = 0.f;
    for (int d0 = 0; d0 < 8; d0++) {
      const bf16x8 kv = *(const bf16x8*)(Kp + d0 * 8);
#pragma unroll
      for (int e = 0; e < 8; e += 2) {
        a0 += q0[d0 * 8 + e]     * h2f((unsigned short)kv[e]);
        a1 += q0[d0 * 8 + e + 1] * h2f((unsigned short)kv[e + 1]);
      }
    }
    sc[j] = a0 + a1;
  }
  __syncthreads();

  float mx = -1e30f;
  for (int j = t; j < SEQ; j += 256) mx = fmaxf(mx, sc[j]);
  for (int d = 1; d < 64; d <<= 1) mx = fmaxf(mx, __shfl_xor(mx, d));
  if ((t & 63) == 0) red[t >> 6] = mx;
  __syncthreads();
  mx = fmaxf(fmaxf(red[0], red[1]), fmaxf(red[2], red[3]));
  __syncthreads();

  float sum = 0.f;
  for (int j = t; j < SEQ; j += 256) {
    const float p = __expf(sc[j] - mx);
    sc[j] = p;
    sum += p;
  }
  for (int d = 1; d < 64; d <<= 1) sum += __shfl_xor(sum, d);
  __syncthreads();
  if ((t & 63) == 0) red[t >> 6] = sum;
  __syncthreads();
  const float inv = 1.f / (red[0] + red[1] + red[2] + red[3]);

  const int dd = t & 63, part = t >> 6;
  const unsigned short* Vp = Vth + (size_t)dd * SEQ;   // row dd, contiguous in j
  float a0 = 0.f, a1 = 0.f, a2 = 0.f, a3 = 0.f;
  const int jb = part * 1024;
  for (int j = 0; j < 1024; j += 4) {
    a0 += sc[jb + j + 0] * h2f(Vp[jb + j + 0]);
    a1 += sc[jb + j + 1] * h2f(Vp[jb + j + 1]);
    a2 += sc[jb + j + 2] * h2f(Vp[jb + j + 2]);
    a3 += sc[jb + j + 3] * h2f(Vp[jb + j + 3]);
  }
  accl[part][dd] = (a0 + a1) + (a2 + a3);
  __syncthreads();
  if (part == 0) {
    const float v = (accl[0][dd] + accl[1][dd] + accl[2][dd] + accl[3][dd]) * inv;
    ctx[(size_t)h * HD + dd] = f2b(v);   // row 0 (bf16, like the band kernel)
  }
}

// ---------------- launch ----------------
extern "C" void kernel_launch(void* const* d_in, const int* in_sizes, int n_in,
                              void* d_out, int out_size, void* d_ws, size_t ws_size,
                              hipStream_t stream)
{
  (void)in_sizes; (void)n_in; (void)out_size; (void)ws_size;
  const float* x  = (const float*)d_in[0];
  const float* Wq = (const float*)d_in[1];
  const float* bq = (const float*)d_in[2];
  const float* Wk = (const float*)d_in[3];
  const float* bk = (const float*)d_in[4];
  const float* Wv = (const float*)d_in[5];
  const float* bv = (const float*)d_in[6];
  const float* Wo = (const float*)d_in[7];
  const float* bo = (const float*)d_in[8];
  float* out = (float*)d_out;

  char* ws = (char*)d_ws;
  unsigned short* xb   = (unsigned short*)(ws + 0);         // dead after gemm<0>
  unsigned short* wqkv = (unsigned short*)(ws + 6291456);
  unsigned short* wob  = (unsigned short*)(ws + 9830400);
  unsigned short* qbuf = (unsigned short*)(ws + 11010048);  // [12][4096][64] f16
  unsigned short* kbuf = (unsigned short*)(ws + 17301504);  // [12][4096][64] f16
  unsigned short* vtb  = (unsigned short*)(ws + 23592960);  // [12][64][4096] f16
  unsigned short* ctx  = (unsigned short*)(ws + 0);         // bf16, aliases xb

  convert_all<<<dim3(1024), dim3(256), 0, stream>>>(x, Wq, Wk, Wv, Wo, xb, wqkv, wob);
  gemm_bt<0><<<dim3(18, 32), dim3(256), 0, stream>>>(xb, wqkv, qbuf, kbuf, vtb,
                                                     bq, bk, bv, nullptr, nullptr);
  attn_band9<<<dim3(SEQ / 16, NH), dim3(256), 0, stream>>>(qbuf, kbuf, vtb, ctx);
  attn_global12<<<dim3(NH), dim3(256), 0, stream>>>(qbuf, kbuf, vtb, ctx);
  gemm_bt<1><<<dim3(6, 32), dim3(256), 0, stream>>>(ctx, wob, nullptr, nullptr, nullptr,
                                                    nullptr, nullptr, nullptr, bo, out);
}

// Round 20
// 127.262 us; speedup vs baseline: 75.5097x; 1.7879x over previous
//
#include <hip/hip_runtime.h>
#include <cstdint>

#define SEQ   4096
#define DM    768
#define NH    12
#define HD    64
#define KD    768

typedef float  f32x4  __attribute__((ext_vector_type(4)));
typedef short  bf16x8 __attribute__((ext_vector_type(8)));
typedef _Float16 f16x8 __attribute__((ext_vector_type(8)));
typedef _Float16 h16x2 __attribute__((ext_vector_type(2)));
typedef unsigned int u32;

typedef __attribute__((address_space(1))) const unsigned int gu32;
typedef __attribute__((address_space(3))) unsigned int lu32;

__device__ __forceinline__ unsigned short f2b(float f) {
  unsigned int u = __builtin_bit_cast(unsigned int, f);
  u += 0x7fffu + ((u >> 16) & 1u);
  return (unsigned short)(u >> 16);
}
__device__ __forceinline__ float b2f(unsigned short s) {
  return __builtin_bit_cast(float, ((unsigned int)s) << 16);
}
__device__ __forceinline__ unsigned short f2h(float f) {
  _Float16 h = (_Float16)f;
  return __builtin_bit_cast(unsigned short, h);
}
__device__ __forceinline__ float h2f(unsigned short s) {
  return (float)__builtin_bit_cast(_Float16, s);
}

__device__ __forceinline__ void gload_lds16(const void* g, void* l) {
  gu32* gp = reinterpret_cast<gu32*>(reinterpret_cast<uintptr_t>(g));
  lu32* lp = reinterpret_cast<lu32*>(reinterpret_cast<uintptr_t>(l));
  __builtin_amdgcn_global_load_lds(gp, lp, 16, 0, 0);
}

// Real-time guard between MFMA acc writes and first VALU/DPP consumer:
// 4x s_nop 7 = 32 cycles of genuine delay (R10's v_mov fence failed because
// the movs themselves read acc inside the hazard window; R9's probe passed
// because its global-load compare chain inserted real time).
__device__ __forceinline__ void mfma_guard() {
  __builtin_amdgcn_sched_barrier(0);
  asm volatile("s_nop 7\n\ts_nop 7\n\ts_nop 7\n\ts_nop 7");
  __builtin_amdgcn_sched_barrier(0);
}

// ---------------- pack/convert: f32 -> bf16 (R3-verified) ----------------
__global__ void convert_all(const float* __restrict__ x,
                            const float* __restrict__ wq,
                            const float* __restrict__ wk,
                            const float* __restrict__ wv,
                            const float* __restrict__ wo,
                            unsigned short* __restrict__ xb,
                            unsigned short* __restrict__ wqkv,
                            unsigned short* __restrict__ wob)
{
  const int XN = SEQ * DM;
  const int WN = DM * DM;
  const int total4 = (XN + 4 * WN) >> 2;
  for (int i = blockIdx.x * blockDim.x + threadIdx.x; i < total4;
       i += gridDim.x * blockDim.x) {
    const int base = i << 2;
    const float* src;
    unsigned short* dst;
    if (base < XN)                 { src = x  + base;               dst = xb   + base; }
    else if (base < XN + WN)       { src = wq + (base - XN);        dst = wqkv + (base - XN); }
    else if (base < XN + 2 * WN)   { src = wk + (base - XN - WN);   dst = wqkv + (base - XN); }
    else if (base < XN + 3 * WN)   { src = wv + (base - XN - 2*WN); dst = wqkv + (base - XN); }
    else                           { src = wo + (base - XN - 3*WN); dst = wob  + (base - XN - 3*WN); }
    const float4 v = *(const float4*)src;
    *(ushort4*)dst = make_ushort4(f2b(v.x), f2b(v.y), f2b(v.z), f2b(v.w));
  }
}

// ---------------- GEMM C = A[M,K] * B[N,K]^T (R3-verified, bf16 MFMA) --------
// EPI 0: Q/K row-major f16; V written TRANSPOSED [h][dk][s] f16 (R2≡R4 verified)
template<int EPI>
__global__ __launch_bounds__(256, 2)
void gemm_bt(const unsigned short* __restrict__ A,
             const unsigned short* __restrict__ B,
             unsigned short* __restrict__ qb,
             unsigned short* __restrict__ kb,
             unsigned short* __restrict__ vt,
             const float* __restrict__ bq,
             const float* __restrict__ bk,
             const float* __restrict__ bv,
             const float* __restrict__ bo,
             float* __restrict__ outf)
{
  __shared__ __align__(16) unsigned short As[128 * 32];
  __shared__ __align__(16) unsigned short Bs[128 * 32];
  const int t  = threadIdx.x;
  const int w  = t >> 6;
  const int l  = t & 63;
  const int m0 = blockIdx.y * 128;
  const int n0 = blockIdx.x * 128;
  const int wr = (w >> 1) * 64;
  const int wc = (w & 1) * 64;
  const int lr = l & 15;
  const int lk = (l >> 4) * 8;

  const int row1 = t >> 2;
  const int row2 = row1 + 64;
  const int seg  = t & 3;

  f32x4 acc[4][4];
#pragma unroll
  for (int i = 0; i < 4; i++)
#pragma unroll
    for (int j = 0; j < 4; j++) acc[i][j] = (f32x4){0.f, 0.f, 0.f, 0.f};

  char* ldsA0 = (char*)As + (size_t)(w * 64) * 16;
  char* ldsA1 = (char*)As + (size_t)(w * 64 + 256) * 16;
  char* ldsB0 = (char*)Bs + (size_t)(w * 64) * 16;
  char* ldsB1 = (char*)Bs + (size_t)(w * 64 + 256) * 16;

  for (int k0 = 0; k0 < KD; k0 += 32) {
    gload_lds16(A + (size_t)(m0 + row1) * KD + k0 + seg * 8, ldsA0);
    gload_lds16(A + (size_t)(m0 + row2) * KD + k0 + seg * 8, ldsA1);
    gload_lds16(B + (size_t)(n0 + row1) * KD + k0 + seg * 8, ldsB0);
    gload_lds16(B + (size_t)(n0 + row2) * KD + k0 + seg * 8, ldsB1);
    __syncthreads();
    bf16x8 af[4], bfv[4];
#pragma unroll
    for (int fi = 0; fi < 4; fi++)
      af[fi] = *(const bf16x8*)(As + (wr + fi * 16 + lr) * 32 + lk);
#pragma unroll
    for (int fj = 0; fj < 4; fj++)
      bfv[fj] = *(const bf16x8*)(Bs + (wc + fj * 16 + lr) * 32 + lk);
#pragma unroll
    for (int fi = 0; fi < 4; fi++)
#pragma unroll
      for (int fj = 0; fj < 4; fj++)
        acc[fi][fj] = __builtin_amdgcn_mfma_f32_16x16x32_bf16(af[fi], bfv[fj], acc[fi][fj], 0, 0, 0);
    __syncthreads();
  }

#pragma unroll
  for (int fi = 0; fi < 4; fi++) {
    const int mbase = m0 + wr + fi * 16 + (l >> 4) * 4;
#pragma unroll
    for (int fj = 0; fj < 4; fj++) {
      const int n = n0 + wc + fj * 16 + lr;
      if (EPI == 1) {
        const float bb = bo[n];
#pragma unroll
        for (int r = 0; r < 4; r++)
          outf[(size_t)(mbase + r) * DM + n] = acc[fi][fj][r] + bb;
      } else if (n < DM) {                       // Q (scaled by 1/8) -> f16
        const int hh = n >> 6, dk = n & 63;
        const float bb = bq[n];
#pragma unroll
        for (int r = 0; r < 4; r++)
          qb[((size_t)hh * SEQ + mbase + r) * HD + dk] = f2h((acc[fi][fj][r] + bb) * 0.125f);
      } else if (n < 2 * DM) {                   // K row-major [h][s][dk] -> f16
        const int n2 = n - DM, hh = n2 >> 6, dk = n2 & 63;
        const float bb = bk[n2];
#pragma unroll
        for (int r = 0; r < 4; r++)
          kb[((size_t)hh * SEQ + mbase + r) * HD + dk] = f2h(acc[fi][fj][r] + bb);
      } else {                                   // V -> transposed [h][dk][s] f16
        const int n3 = n - 2 * DM, hh = n3 >> 6, dk = n3 & 63;
        const float bb = bv[n3];
        ushort4 ov = make_ushort4(f2h(acc[fi][fj][0] + bb), f2h(acc[fi][fj][1] + bb),
                                  f2h(acc[fi][fj][2] + bb), f2h(acc[fi][fj][3] + bb));
        *(ushort4*)(vt + ((size_t)hh * HD + dk) * SEQ + mbase) = ov;
      }
    }
  }
}

// ------ MFMA band attention: 64q/block, 4 waves, dbuf swizzled tiles ---------
// f16 MFMA 16x16x32; s_nop guard after acc writes (hazard theory, R9/R10).
// Tiles staged with the R13-verified XOR swizzle: row r slot s holds global
// block s^(r&7); fragment read at slot (cb^(r&7)).
// mask: valid = (j==0) || |qi-j|<=256 (row 0 overwritten by attn_global12).
#define PSTR 72
__global__ __launch_bounds__(256, 2)
void attn_mfma64(const unsigned short* __restrict__ qb,
                 const unsigned short* __restrict__ kb,
                 const unsigned short* __restrict__ vt,
                 unsigned short* __restrict__ ctx)
{
  __shared__ __align__(16) unsigned short Qs[64 * 64];
  __shared__ __align__(16) unsigned short Ks[2][64 * 64];
  __shared__ __align__(16) unsigned short Vts[2][64 * 64];
  __shared__ __align__(16) unsigned short plds[4][16 * PSTR];
  const int h  = blockIdx.y;
  const int i0 = blockIdx.x * 64;
  const int t  = threadIdx.x;
  const int w  = t >> 6, l = t & 63;
  const int lr = l & 15, lk = (l >> 4) * 8;
  const int cb = (l >> 4);                  // 16B block index 0..3
  const int qi0 = i0 + w * 16 + (l >> 4) * 4;
  const unsigned short* Qh  = qb + (size_t)h * SEQ * HD;
  const unsigned short* Kh  = kb + (size_t)h * SEQ * HD;
  const unsigned short* Vth = vt + (size_t)h * HD * SEQ;

  const int srow = t >> 3;                  // 0..31
  const int scol = (t & 7) ^ (srow & 7);    // pre-swizzled source 16B-slot

  // stage Q tile [64][64] once (swizzled)
  gload_lds16(Qh + (size_t)(i0 + srow) * HD + scol * 8, (char*)Qs + t * 16);
  gload_lds16(Qh + (size_t)(i0 + 32 + srow) * HD + scol * 8, (char*)Qs + 4096 + t * 16);

  // chunk list: band union for 64 queries, chunk 0 prepended if absent
  int lo = i0 - 256; if (lo < 0) lo = 0;
  int hi = i0 + 63 + 257; if (hi > SEQ) hi = SEQ;
  const int cbeg = lo >> 6, cend = (hi - 1) >> 6;
  const int pre  = (cbeg > 0) ? 1 : 0;
  const int nch  = cend - cbeg + 1 + pre;

  auto chunkof = [&](int it) -> int {
    return (pre && it == 0) ? 0 : (cbeg + it - pre);
  };
  auto stage = [&](int bsel, int cch) {
    const int jj0 = cch * 64;
    char* kd = (char*)(&Ks[bsel][0]);
    char* vd = (char*)(&Vts[bsel][0]);
    gload_lds16(Kh + (size_t)(jj0 + srow) * HD + scol * 8, kd + t * 16);
    gload_lds16(Kh + (size_t)(jj0 + 32 + srow) * HD + scol * 8, kd + 4096 + t * 16);
    gload_lds16(Vth + (size_t)srow * SEQ + jj0 + scol * 8, vd + t * 16);
    gload_lds16(Vth + (size_t)(32 + srow) * SEQ + jj0 + scol * 8, vd + 4096 + t * 16);
  };
  auto frag = [&](const unsigned short* base, int rr, int cc) -> f16x8 {
    return __builtin_bit_cast(f16x8,
        *(const bf16x8*)(base + rr * 64 + ((cc ^ (rr & 7)) * 8)));
  };

  stage(0, chunkof(0));
  __syncthreads();

  f32x4 o[4];
#pragma unroll
  for (int i = 0; i < 4; i++) o[i] = (f32x4){0.f, 0.f, 0.f, 0.f};
  float mrow[4] = {-1e30f, -1e30f, -1e30f, -1e30f};
  float lsum[4] = {0.f, 0.f, 0.f, 0.f};
  unsigned short* P = &plds[w][0];

  for (int it = 0; it < nch; ++it) {
    if (it + 1 < nch) stage((it + 1) & 1, chunkof(it + 1));  // async prefetch

    const int c  = chunkof(it);
    const int j0 = c * 64;
    const unsigned short* Kc = &Ks[it & 1][0];
    const unsigned short* Vc = &Vts[it & 1][0];

    // ---- MFMA QK^T: 16x64 strip per wave
    const f16x8 qa0 = frag(Qs, w * 16 + lr, cb);
    const f16x8 qa1 = frag(Qs, w * 16 + lr, cb + 4);
    f32x4 sc[4];
#pragma unroll
    for (int i = 0; i < 4; i++) sc[i] = (f32x4){0.f, 0.f, 0.f, 0.f};
#pragma unroll
    for (int fj = 0; fj < 4; fj++) {
      const f16x8 kf0 = frag(Kc, fj * 16 + lr, cb);
      const f16x8 kf1 = frag(Kc, fj * 16 + lr, cb + 4);
      sc[fj] = __builtin_amdgcn_mfma_f32_16x16x32_f16(qa0, kf0, sc[fj], 0, 0, 0);
      sc[fj] = __builtin_amdgcn_mfma_f32_16x16x32_f16(qa1, kf1, sc[fj], 0, 0, 0);
    }
    mfma_guard();   // real delay before first VALU consumer of acc

    // ---- mask + online softmax (C-layout: row=(l>>4)*4+r, col=lane&15)
#pragma unroll
    for (int r = 0; r < 4; r++) {
      const int qi = qi0 + r;
      float mx = -1e30f;
#pragma unroll
      for (int fj = 0; fj < 4; fj++) {
        const int j = j0 + fj * 16 + lr;
        const bool valid = (j == 0) || ((j - qi) <= 256 && (qi - j) <= 256);
        const float v = valid ? sc[fj][r] : -1e30f;
        sc[fj][r] = v;
        mx = fmaxf(mx, v);
      }
      for (int d = 1; d < 16; d <<= 1) mx = fmaxf(mx, __shfl_xor(mx, d));
      const float mnew = fmaxf(mrow[r], mx);
      const float scale = __expf(mrow[r] - mnew);
      mrow[r] = mnew;
      float sum = 0.f;
#pragma unroll
      for (int fj = 0; fj < 4; fj++) {
        const float p = __expf(sc[fj][r] - mnew);
        sc[fj][r] = p;
        sum += p;
      }
      for (int d = 1; d < 16; d <<= 1) sum += __shfl_xor(sum, d);
      lsum[r] = lsum[r] * scale + sum;
#pragma unroll
      for (int fn = 0; fn < 4; fn++) o[fn][r] *= scale;
    }

    // ---- P (C-layout, f16) -> LDS (padded stride)
#pragma unroll
    for (int fj = 0; fj < 4; fj++)
#pragma unroll
      for (int r = 0; r < 4; r++)
        P[(size_t)((l >> 4) * 4 + r) * PSTR + fj * 16 + lr] = f2h(sc[fj][r]);
    __syncthreads();

    // ---- MFMA PV: A = P rows (q), B = V^T rows (dims)
    const f16x8 pf0 = __builtin_bit_cast(f16x8, *(const bf16x8*)(P + lr * PSTR + lk));
    const f16x8 pf1 = __builtin_bit_cast(f16x8, *(const bf16x8*)(P + lr * PSTR + 32 + lk));
#pragma unroll
    for (int fn = 0; fn < 4; fn++) {
      const f16x8 vf0 = frag(Vc, fn * 16 + lr, cb);
      const f16x8 vf1 = frag(Vc, fn * 16 + lr, cb + 4);
      o[fn] = __builtin_amdgcn_mfma_f32_16x16x32_f16(pf0, vf0, o[fn], 0, 0, 0);
      o[fn] = __builtin_amdgcn_mfma_f32_16x16x32_f16(pf1, vf1, o[fn], 0, 0, 0);
    }
    __syncthreads();   // prefetch landed + all waves done with buf[it&1]
  }

  mfma_guard();   // real delay before epilogue reads of o

#pragma unroll
  for (int fn = 0; fn < 4; fn++)
#pragma unroll
    for (int r = 0; r < 4; r++) {
      const int s = qi0 + r;
      const float val = o[fn][r] / lsum[r];
      ctx[(size_t)s * DM + h * HD + fn * 16 + lr] = f2b(val);
    }
}

// ---------------- global row: query 0 attends to ALL keys (V^T input) --------
__global__ __launch_bounds__(256)
void attn_global12(const unsigned short* __restrict__ qb,
                   const unsigned short* __restrict__ kb,
                   const unsigned short* __restrict__ vt,
                   unsigned short* __restrict__ ctx)
{
  __shared__ float sc[SEQ];
  __shared__ float q0[HD];
  __shared__ float red[4];
  __shared__ float accl[4][HD];
  const int t = threadIdx.x;
  const int h = blockIdx.x;
  const unsigned short* Qh  = qb + (size_t)h * SEQ * HD;
  const unsigned short* Kh  = kb + (size_t)h * SEQ * HD;
  const unsigned short* Vth = vt + (size_t)h * HD * SEQ;

  if (t < HD) q0[t] = h2f(Qh[t]);   // pre-scaled by 1/8
  __syncthreads();

  for (int j = t; j < SEQ; j += 256) {
    const unsigned short* Kp = Kh + (size_t)j * HD;
    float a0 = 0.f, a1 = 0.f;
    for (int d0 = 0; d0 < 8; d0++) {
      const bf16x8 kv = *(const bf16x8*)(Kp + d0 * 8);
#pragma unroll
      for (int e = 0; e < 8; e += 2) {
        a0 += q0[d0 * 8 + e]     * h2f((unsigned short)kv[e]);
        a1 += q0[d0 * 8 + e + 1] * h2f((unsigned short)kv[e + 1]);
      }
    }
    sc[j] = a0 + a1;
  }
  __syncthreads();

  float mx = -1e30f;
  for (int j = t; j < SEQ; j += 256) mx = fmaxf(mx, sc[j]);
  for (int d = 1; d < 64; d <<= 1) mx = fmaxf(mx, __shfl_xor(mx, d));
  if ((t & 63) == 0) red[t >> 6] = mx;
  __syncthreads();
  mx = fmaxf(fmaxf(red[0], red[1]), fmaxf(red[2], red[3]));
  __syncthreads();

  float sum = 0.f;
  for (int j = t; j < SEQ; j += 256) {
    const float p = __expf(sc[j] - mx);
    sc[j] = p;
    sum += p;
  }
  for (int d = 1; d < 64; d <<= 1) sum += __shfl_xor(sum, d);
  __syncthreads();
  if ((t & 63) == 0) red[t >> 6] = sum;
  __syncthreads();
  const float inv = 1.f / (red[0] + red[1] + red[2] + red[3]);

  const int dd = t & 63, part = t >> 6;
  const unsigned short* Vp = Vth + (size_t)dd * SEQ;   // row dd, contiguous in j
  float a0 = 0.f, a1 = 0.f, a2 = 0.f, a3 = 0.f;
  const int jb = part * 1024;
  for (int j = 0; j < 1024; j += 4) {
    a0 += sc[jb + j + 0] * h2f(Vp[jb + j + 0]);
    a1 += sc[jb + j + 1] * h2f(Vp[jb + j + 1]);
    a2 += sc[jb + j + 2] * h2f(Vp[jb + j + 2]);
    a3 += sc[jb + j + 3] * h2f(Vp[jb + j + 3]);
  }
  accl[part][dd] = (a0 + a1) + (a2 + a3);
  __syncthreads();
  if (part == 0) {
    const float v = (accl[0][dd] + accl[1][dd] + accl[2][dd] + accl[3][dd]) * inv;
    ctx[(size_t)h * HD + dd] = f2b(v);   // row 0
  }
}

// ---------------- launch ----------------
extern "C" void kernel_launch(void* const* d_in, const int* in_sizes, int n_in,
                              void* d_out, int out_size, void* d_ws, size_t ws_size,
                              hipStream_t stream)
{
  (void)in_sizes; (void)n_in; (void)out_size; (void)ws_size;
  const float* x  = (const float*)d_in[0];
  const float* Wq = (const float*)d_in[1];
  const float* bq = (const float*)d_in[2];
  const float* Wk = (const float*)d_in[3];
  const float* bk = (const float*)d_in[4];
  const float* Wv = (const float*)d_in[5];
  const float* bv = (const float*)d_in[6];
  const float* Wo = (const float*)d_in[7];
  const float* bo = (const float*)d_in[8];
  float* out = (float*)d_out;

  char* ws = (char*)d_ws;
  unsigned short* xb   = (unsigned short*)(ws + 0);         // dead after gemm<0>
  unsigned short* wqkv = (unsigned short*)(ws + 6291456);
  unsigned short* wob  = (unsigned short*)(ws + 9830400);
  unsigned short* qbuf = (unsigned short*)(ws + 11010048);  // [12][4096][64] f16
  unsigned short* kbuf = (unsigned short*)(ws + 17301504);  // [12][4096][64] f16
  unsigned short* vtb  = (unsigned short*)(ws + 23592960);  // [12][64][4096] f16
  unsigned short* ctx  = (unsigned short*)(ws + 0);         // bf16, aliases xb

  convert_all<<<dim3(1024), dim3(256), 0, stream>>>(x, Wq, Wk, Wv, Wo, xb, wqkv, wob);
  gemm_bt<0><<<dim3(18, 32), dim3(256), 0, stream>>>(xb, wqkv, qbuf, kbuf, vtb,
                                                     bq, bk, bv, nullptr, nullptr);
  attn_mfma64<<<dim3(SEQ / 64, NH), dim3(256), 0, stream>>>(qbuf, kbuf, vtb, ctx);
  attn_global12<<<dim3(NH), dim3(256), 0, stream>>>(qbuf, kbuf, vtb, ctx);
  gemm_bt<1><<<dim3(6, 32), dim3(256), 0, stream>>>(ctx, wob, nullptr, nullptr, nullptr,
                                                    nullptr, nullptr, nullptr, bo, out);
}

// Round 21
// 118.946 us; speedup vs baseline: 80.7884x; 1.0699x over previous
//
#include <hip/hip_runtime.h>
#include <cstdint>

#define SEQ   4096
#define DM    768
#define NH    12
#define HD    64
#define KD    768

typedef float  f32x4  __attribute__((ext_vector_type(4)));
typedef short  bf16x8 __attribute__((ext_vector_type(8)));
typedef _Float16 f16x8 __attribute__((ext_vector_type(8)));
typedef unsigned int u32;

typedef __attribute__((address_space(1))) const unsigned int gu32;
typedef __attribute__((address_space(3))) unsigned int lu32;

__device__ __forceinline__ unsigned short f2b(float f) {
  unsigned int u = __builtin_bit_cast(unsigned int, f);
  u += 0x7fffu + ((u >> 16) & 1u);
  return (unsigned short)(u >> 16);
}
__device__ __forceinline__ float b2f(unsigned short s) {
  return __builtin_bit_cast(float, ((unsigned int)s) << 16);
}
__device__ __forceinline__ unsigned short f2h(float f) {
  _Float16 h = (_Float16)f;
  return __builtin_bit_cast(unsigned short, h);
}
__device__ __forceinline__ float h2f(unsigned short s) {
  return (float)__builtin_bit_cast(_Float16, s);
}

__device__ __forceinline__ void gload_lds16(const void* g, void* l) {
  gu32* gp = reinterpret_cast<gu32*>(reinterpret_cast<uintptr_t>(g));
  lu32* lp = reinterpret_cast<lu32*>(reinterpret_cast<uintptr_t>(l));
  __builtin_amdgcn_global_load_lds(gp, lp, 16, 0, 0);
}

// Real-time guard between MFMA acc writes and first VALU/DPP consumer
// (R20-verified: gfx950 needs genuine delay, not register-copy fences).
__device__ __forceinline__ void mfma_guard() {
  __builtin_amdgcn_sched_barrier(0);
  asm volatile("s_nop 7\n\ts_nop 7\n\ts_nop 7\n\ts_nop 7");
  __builtin_amdgcn_sched_barrier(0);
}

// ---------------- pack/convert: f32 -> bf16 (R3-verified) ----------------
__global__ void convert_all(const float* __restrict__ x,
                            const float* __restrict__ wq,
                            const float* __restrict__ wk,
                            const float* __restrict__ wv,
                            const float* __restrict__ wo,
                            unsigned short* __restrict__ xb,
                            unsigned short* __restrict__ wqkv,
                            unsigned short* __restrict__ wob)
{
  const int XN = SEQ * DM;
  const int WN = DM * DM;
  const int total4 = (XN + 4 * WN) >> 2;
  for (int i = blockIdx.x * blockDim.x + threadIdx.x; i < total4;
       i += gridDim.x * blockDim.x) {
    const int base = i << 2;
    const float* src;
    unsigned short* dst;
    if (base < XN)                 { src = x  + base;               dst = xb   + base; }
    else if (base < XN + WN)       { src = wq + (base - XN);        dst = wqkv + (base - XN); }
    else if (base < XN + 2 * WN)   { src = wk + (base - XN - WN);   dst = wqkv + (base - XN); }
    else if (base < XN + 3 * WN)   { src = wv + (base - XN - 2*WN); dst = wqkv + (base - XN); }
    else                           { src = wo + (base - XN - 3*WN); dst = wob  + (base - XN - 3*WN); }
    const float4 v = *(const float4*)src;
    *(ushort4*)dst = make_ushort4(f2b(v.x), f2b(v.y), f2b(v.z), f2b(v.w));
  }
}

// ---------------- GEMM C = A[M,K] * B[N,K]^T (R3-verified, bf16 MFMA) --------
// EPI 0: Q/K row-major f16; V written TRANSPOSED [h][dk][s] f16 (R2≡R4 verified)
template<int EPI>
__global__ __launch_bounds__(256, 2)
void gemm_bt(const unsigned short* __restrict__ A,
             const unsigned short* __restrict__ B,
             unsigned short* __restrict__ qb,
             unsigned short* __restrict__ kb,
             unsigned short* __restrict__ vt,
             const float* __restrict__ bq,
             const float* __restrict__ bk,
             const float* __restrict__ bv,
             const float* __restrict__ bo,
             float* __restrict__ outf)
{
  __shared__ __align__(16) unsigned short As[128 * 32];
  __shared__ __align__(16) unsigned short Bs[128 * 32];
  const int t  = threadIdx.x;
  const int w  = t >> 6;
  const int l  = t & 63;
  const int m0 = blockIdx.y * 128;
  const int n0 = blockIdx.x * 128;
  const int wr = (w >> 1) * 64;
  const int wc = (w & 1) * 64;
  const int lr = l & 15;
  const int lk = (l >> 4) * 8;

  const int row1 = t >> 2;
  const int row2 = row1 + 64;
  const int seg  = t & 3;

  f32x4 acc[4][4];
#pragma unroll
  for (int i = 0; i < 4; i++)
#pragma unroll
    for (int j = 0; j < 4; j++) acc[i][j] = (f32x4){0.f, 0.f, 0.f, 0.f};

  char* ldsA0 = (char*)As + (size_t)(w * 64) * 16;
  char* ldsA1 = (char*)As + (size_t)(w * 64 + 256) * 16;
  char* ldsB0 = (char*)Bs + (size_t)(w * 64) * 16;
  char* ldsB1 = (char*)Bs + (size_t)(w * 64 + 256) * 16;

  for (int k0 = 0; k0 < KD; k0 += 32) {
    gload_lds16(A + (size_t)(m0 + row1) * KD + k0 + seg * 8, ldsA0);
    gload_lds16(A + (size_t)(m0 + row2) * KD + k0 + seg * 8, ldsA1);
    gload_lds16(B + (size_t)(n0 + row1) * KD + k0 + seg * 8, ldsB0);
    gload_lds16(B + (size_t)(n0 + row2) * KD + k0 + seg * 8, ldsB1);
    __syncthreads();
    bf16x8 af[4], bfv[4];
#pragma unroll
    for (int fi = 0; fi < 4; fi++)
      af[fi] = *(const bf16x8*)(As + (wr + fi * 16 + lr) * 32 + lk);
#pragma unroll
    for (int fj = 0; fj < 4; fj++)
      bfv[fj] = *(const bf16x8*)(Bs + (wc + fj * 16 + lr) * 32 + lk);
#pragma unroll
    for (int fi = 0; fi < 4; fi++)
#pragma unroll
      for (int fj = 0; fj < 4; fj++)
        acc[fi][fj] = __builtin_amdgcn_mfma_f32_16x16x32_bf16(af[fi], bfv[fj], acc[fi][fj], 0, 0, 0);
    __syncthreads();
  }

#pragma unroll
  for (int fi = 0; fi < 4; fi++) {
    const int mbase = m0 + wr + fi * 16 + (l >> 4) * 4;
#pragma unroll
    for (int fj = 0; fj < 4; fj++) {
      const int n = n0 + wc + fj * 16 + lr;
      if (EPI == 1) {
        const float bb = bo[n];
#pragma unroll
        for (int r = 0; r < 4; r++)
          outf[(size_t)(mbase + r) * DM + n] = acc[fi][fj][r] + bb;
      } else if (n < DM) {                       // Q (scaled by 1/8) -> f16
        const int hh = n >> 6, dk = n & 63;
        const float bb = bq[n];
#pragma unroll
        for (int r = 0; r < 4; r++)
          qb[((size_t)hh * SEQ + mbase + r) * HD + dk] = f2h((acc[fi][fj][r] + bb) * 0.125f);
      } else if (n < 2 * DM) {                   // K row-major [h][s][dk] -> f16
        const int n2 = n - DM, hh = n2 >> 6, dk = n2 & 63;
        const float bb = bk[n2];
#pragma unroll
        for (int r = 0; r < 4; r++)
          kb[((size_t)hh * SEQ + mbase + r) * HD + dk] = f2h(acc[fi][fj][r] + bb);
      } else {                                   // V -> transposed [h][dk][s] f16
        const int n3 = n - 2 * DM, hh = n3 >> 6, dk = n3 & 63;
        const float bb = bv[n3];
        ushort4 ov = make_ushort4(f2h(acc[fi][fj][0] + bb), f2h(acc[fi][fj][1] + bb),
                                  f2h(acc[fi][fj][2] + bb), f2h(acc[fi][fj][3] + bb));
        *(ushort4*)(vt + ((size_t)hh * HD + dk) * SEQ + mbase) = ov;
      }
    }
  }
}

// ------ MFMA band attention: 64q/block, dbuf swizzled tiles, DEFER-MAX -------
// R20-verified structure + R16-verified defer-max transplanted to the 16-lane
// row-group layout: rescale only when __any(masked s > m[r]+8); ls[r] is a
// per-lane partial (summed over fj), reduced ONCE at the end. P bounded e^8.
// mask: valid = (j==0) || |qi-j|<=256 (row 0 overwritten by attn_global12).
#define PSTR 72
__global__ __launch_bounds__(256, 2)
void attn_mfma64(const unsigned short* __restrict__ qb,
                 const unsigned short* __restrict__ kb,
                 const unsigned short* __restrict__ vt,
                 unsigned short* __restrict__ ctx)
{
  __shared__ __align__(16) unsigned short Qs[64 * 64];
  __shared__ __align__(16) unsigned short Ks[2][64 * 64];
  __shared__ __align__(16) unsigned short Vts[2][64 * 64];
  __shared__ __align__(16) unsigned short plds[4][16 * PSTR];
  const int h  = blockIdx.y;
  const int i0 = blockIdx.x * 64;
  const int t  = threadIdx.x;
  const int w  = t >> 6, l = t & 63;
  const int lr = l & 15, lk = (l >> 4) * 8;
  const int cb = (l >> 4);                  // 16B block index 0..3
  const int qi0 = i0 + w * 16 + (l >> 4) * 4;
  const unsigned short* Qh  = qb + (size_t)h * SEQ * HD;
  const unsigned short* Kh  = kb + (size_t)h * SEQ * HD;
  const unsigned short* Vth = vt + (size_t)h * HD * SEQ;

  const int srow = t >> 3;                  // 0..31
  const int scol = (t & 7) ^ (srow & 7);    // pre-swizzled source 16B-slot

  // stage Q tile [64][64] once (swizzled)
  gload_lds16(Qh + (size_t)(i0 + srow) * HD + scol * 8, (char*)Qs + t * 16);
  gload_lds16(Qh + (size_t)(i0 + 32 + srow) * HD + scol * 8, (char*)Qs + 4096 + t * 16);

  // chunk list: band union for 64 queries, chunk 0 prepended if absent
  int lo = i0 - 256; if (lo < 0) lo = 0;
  int hi = i0 + 63 + 257; if (hi > SEQ) hi = SEQ;
  const int cbeg = lo >> 6, cend = (hi - 1) >> 6;
  const int pre  = (cbeg > 0) ? 1 : 0;
  const int nch  = cend - cbeg + 1 + pre;

  auto chunkof = [&](int it) -> int {
    return (pre && it == 0) ? 0 : (cbeg + it - pre);
  };
  auto stage = [&](int bsel, int cch) {
    const int jj0 = cch * 64;
    char* kd = (char*)(&Ks[bsel][0]);
    char* vd = (char*)(&Vts[bsel][0]);
    gload_lds16(Kh + (size_t)(jj0 + srow) * HD + scol * 8, kd + t * 16);
    gload_lds16(Kh + (size_t)(jj0 + 32 + srow) * HD + scol * 8, kd + 4096 + t * 16);
    gload_lds16(Vth + (size_t)srow * SEQ + jj0 + scol * 8, vd + t * 16);
    gload_lds16(Vth + (size_t)(32 + srow) * SEQ + jj0 + scol * 8, vd + 4096 + t * 16);
  };
  auto frag = [&](const unsigned short* base, int rr, int cc) -> f16x8 {
    return __builtin_bit_cast(f16x8,
        *(const bf16x8*)(base + rr * 64 + ((cc ^ (rr & 7)) * 8)));
  };

  stage(0, chunkof(0));
  __syncthreads();

  f32x4 o[4];
#pragma unroll
  for (int i = 0; i < 4; i++) o[i] = (f32x4){0.f, 0.f, 0.f, 0.f};
  float mrow[4] = {-1e30f, -1e30f, -1e30f, -1e30f};
  float ls[4]   = {0.f, 0.f, 0.f, 0.f};      // per-lane partials
  unsigned short* P = &plds[w][0];

  for (int it = 0; it < nch; ++it) {
    if (it + 1 < nch) stage((it + 1) & 1, chunkof(it + 1));  // async prefetch

    const int c  = chunkof(it);
    const int j0 = c * 64;
    const unsigned short* Kc = &Ks[it & 1][0];
    const unsigned short* Vc = &Vts[it & 1][0];

    // ---- MFMA QK^T: 16x64 strip per wave
    const f16x8 qa0 = frag(Qs, w * 16 + lr, cb);
    const f16x8 qa1 = frag(Qs, w * 16 + lr, cb + 4);
    f32x4 sc[4];
#pragma unroll
    for (int i = 0; i < 4; i++) sc[i] = (f32x4){0.f, 0.f, 0.f, 0.f};
#pragma unroll
    for (int fj = 0; fj < 4; fj++) {
      const f16x8 kf0 = frag(Kc, fj * 16 + lr, cb);
      const f16x8 kf1 = frag(Kc, fj * 16 + lr, cb + 4);
      sc[fj] = __builtin_amdgcn_mfma_f32_16x16x32_f16(qa0, kf0, sc[fj], 0, 0, 0);
      sc[fj] = __builtin_amdgcn_mfma_f32_16x16x32_f16(qa1, kf1, sc[fj], 0, 0, 0);
    }
    mfma_guard();   // real delay before first VALU consumer of acc

    // ---- mask + defer-max trigger check (C-layout: row=(l>>4)*4+r, col=lr)
    bool exceed = false;
#pragma unroll
    for (int r = 0; r < 4; r++) {
      const int qi = qi0 + r;
#pragma unroll
      for (int fj = 0; fj < 4; fj++) {
        const int j = j0 + fj * 16 + lr;
        const bool valid = (j == 0) || ((j - qi) <= 256 && (qi - j) <= 256);
        const float v = valid ? sc[fj][r] : -1e30f;
        sc[fj][r] = v;
        exceed |= (v > mrow[r] + 8.f);
      }
    }
    if (__any(exceed)) {
      // rare: full rescale for this wave's 16 rows
#pragma unroll
      for (int r = 0; r < 4; r++) {
        float mx = fmaxf(fmaxf(sc[0][r], sc[1][r]), fmaxf(sc[2][r], sc[3][r]));
        for (int d = 1; d < 16; d <<= 1) mx = fmaxf(mx, __shfl_xor(mx, d));
        const float mnew  = fmaxf(mrow[r], mx);
        const float scale = __expf(mrow[r] - mnew);
        mrow[r] = mnew;
        ls[r] *= scale;
#pragma unroll
        for (int fn = 0; fn < 4; fn++) o[fn][r] *= scale;
      }
    }
    // ---- P = exp(s - m) (bounded e^8); per-lane lsum partial, no butterfly
#pragma unroll
    for (int r = 0; r < 4; r++) {
      float psum = 0.f;
#pragma unroll
      for (int fj = 0; fj < 4; fj++) {
        const float p = __expf(sc[fj][r] - mrow[r]);
        sc[fj][r] = p;
        psum += p;
      }
      ls[r] += psum;
    }

    // ---- P (C-layout, f16) -> LDS (padded stride)
#pragma unroll
    for (int fj = 0; fj < 4; fj++)
#pragma unroll
      for (int r = 0; r < 4; r++)
        P[(size_t)((l >> 4) * 4 + r) * PSTR + fj * 16 + lr] = f2h(sc[fj][r]);
    __syncthreads();

    // ---- MFMA PV: A = P rows (q), B = V^T rows (dims)
    const f16x8 pf0 = __builtin_bit_cast(f16x8, *(const bf16x8*)(P + lr * PSTR + lk));
    const f16x8 pf1 = __builtin_bit_cast(f16x8, *(const bf16x8*)(P + lr * PSTR + 32 + lk));
#pragma unroll
    for (int fn = 0; fn < 4; fn++) {
      const f16x8 vf0 = frag(Vc, fn * 16 + lr, cb);
      const f16x8 vf1 = frag(Vc, fn * 16 + lr, cb + 4);
      o[fn] = __builtin_amdgcn_mfma_f32_16x16x32_f16(pf0, vf0, o[fn], 0, 0, 0);
      o[fn] = __builtin_amdgcn_mfma_f32_16x16x32_f16(pf1, vf1, o[fn], 0, 0, 0);
    }
    __syncthreads();   // prefetch landed + all waves done with buf[it&1]
  }

  mfma_guard();   // real delay before epilogue reads of o

  // final: one butterfly per row for the deferred lsum partials
#pragma unroll
  for (int r = 0; r < 4; r++)
    for (int d = 1; d < 16; d <<= 1) ls[r] += __shfl_xor(ls[r], d);

#pragma unroll
  for (int fn = 0; fn < 4; fn++)
#pragma unroll
    for (int r = 0; r < 4; r++) {
      const int s = qi0 + r;
      const float val = o[fn][r] / ls[r];
      ctx[(size_t)s * DM + h * HD + fn * 16 + lr] = f2b(val);
    }
}

// ---------------- global row: query 0 attends to ALL keys (V^T input) --------
__global__ __launch_bounds__(256)
void attn_global12(const unsigned short* __restrict__ qb,
                   const unsigned short* __restrict__ kb,
                   const unsigned short* __restrict__ vt,
                   unsigned short* __restrict__ ctx)
{
  __shared__ float sc[SEQ];
  __shared__ float q0[HD];
  __shared__ float red[4];
  __shared__ float accl[4][HD];
  const int t = threadIdx.x;
  const int h = blockIdx.x;
  const unsigned short* Qh  = qb + (size_t)h * SEQ * HD;
  const unsigned short* Kh  = kb + (size_t)h * SEQ * HD;
  const unsigned short* Vth = vt + (size_t)h * HD * SEQ;

  if (t < HD) q0[t] = h2f(Qh[t]);   // pre-scaled by 1/8
  __syncthreads();

  for (int j = t; j < SEQ; j += 256) {
    const unsigned short* Kp = Kh + (size_t)j * HD;
    float a0 = 0.f, a1 = 0.f;
    for (int d0 = 0; d0 < 8; d0++) {
      const bf16x8 kv = *(const bf16x8*)(Kp + d0 * 8);
#pragma unroll
      for (int e = 0; e < 8; e += 2) {
        a0 += q0[d0 * 8 + e]     * h2f((unsigned short)kv[e]);
        a1 += q0[d0 * 8 + e + 1] * h2f((unsigned short)kv[e + 1]);
      }
    }
    sc[j] = a0 + a1;
  }
  __syncthreads();

  float mx = -1e30f;
  for (int j = t; j < SEQ; j += 256) mx = fmaxf(mx, sc[j]);
  for (int d = 1; d < 64; d <<= 1) mx = fmaxf(mx, __shfl_xor(mx, d));
  if ((t & 63) == 0) red[t >> 6] = mx;
  __syncthreads();
  mx = fmaxf(fmaxf(red[0], red[1]), fmaxf(red[2], red[3]));
  __syncthreads();

  float sum = 0.f;
  for (int j = t; j < SEQ; j += 256) {
    const float p = __expf(sc[j] - mx);
    sc[j] = p;
    sum += p;
  }
  for (int d = 1; d < 64; d <<= 1) sum += __shfl_xor(sum, d);
  __syncthreads();
  if ((t & 63) == 0) red[t >> 6] = sum;
  __syncthreads();
  const float inv = 1.f / (red[0] + red[1] + red[2] + red[3]);

  const int dd = t & 63, part = t >> 6;
  const unsigned short* Vp = Vth + (size_t)dd * SEQ;   // row dd, contiguous in j
  float a0 = 0.f, a1 = 0.f, a2 = 0.f, a3 = 0.f;
  const int jb = part * 1024;
  for (int j = 0; j < 1024; j += 4) {
    a0 += sc[jb + j + 0] * h2f(Vp[jb + j + 0]);
    a1 += sc[jb + j + 1] * h2f(Vp[jb + j + 1]);
    a2 += sc[jb + j + 2] * h2f(Vp[jb + j + 2]);
    a3 += sc[jb + j + 3] * h2f(Vp[jb + j + 3]);
  }
  accl[part][dd] = (a0 + a1) + (a2 + a3);
  __syncthreads();
  if (part == 0) {
    const float v = (accl[0][dd] + accl[1][dd] + accl[2][dd] + accl[3][dd]) * inv;
    ctx[(size_t)h * HD + dd] = f2b(v);   // row 0
  }
}

// ---------------- launch ----------------
extern "C" void kernel_launch(void* const* d_in, const int* in_sizes, int n_in,
                              void* d_out, int out_size, void* d_ws, size_t ws_size,
                              hipStream_t stream)
{
  (void)in_sizes; (void)n_in; (void)out_size; (void)ws_size;
  const float* x  = (const float*)d_in[0];
  const float* Wq = (const float*)d_in[1];
  const float* bq = (const float*)d_in[2];
  const float* Wk = (const float*)d_in[3];
  const float* bk = (const float*)d_in[4];
  const float* Wv = (const float*)d_in[5];
  const float* bv = (const float*)d_in[6];
  const float* Wo = (const float*)d_in[7];
  const float* bo = (const float*)d_in[8];
  float* out = (float*)d_out;

  char* ws = (char*)d_ws;
  unsigned short* xb   = (unsigned short*)(ws + 0);         // dead after gemm<0>
  unsigned short* wqkv = (unsigned short*)(ws + 6291456);
  unsigned short* wob  = (unsigned short*)(ws + 9830400);
  unsigned short* qbuf = (unsigned short*)(ws + 11010048);  // [12][4096][64] f16
  unsigned short* kbuf = (unsigned short*)(ws + 17301504);  // [12][4096][64] f16
  unsigned short* vtb  = (unsigned short*)(ws + 23592960);  // [12][64][4096] f16
  unsigned short* ctx  = (unsigned short*)(ws + 0);         // bf16, aliases xb

  convert_all<<<dim3(1024), dim3(256), 0, stream>>>(x, Wq, Wk, Wv, Wo, xb, wqkv, wob);
  gemm_bt<0><<<dim3(18, 32), dim3(256), 0, stream>>>(xb, wqkv, qbuf, kbuf, vtb,
                                                     bq, bk, bv, nullptr, nullptr);
  attn_mfma64<<<dim3(SEQ / 64, NH), dim3(256), 0, stream>>>(qbuf, kbuf, vtb, ctx);
  attn_global12<<<dim3(NH), dim3(256), 0, stream>>>(qbuf, kbuf, vtb, ctx);
  gemm_bt<1><<<dim3(6, 32), dim3(256), 0, stream>>>(ctx, wob, nullptr, nullptr, nullptr,
                                                    nullptr, nullptr, nullptr, bo, out);
}

// Round 22
// 104.866 us; speedup vs baseline: 91.6357x; 1.1343x over previous
//
#include <hip/hip_runtime.h>
#include <cstdint>

#define SEQ   4096
#define DM    768
#define NH    12
#define HD    64
#define KD    768

typedef float  f32x4  __attribute__((ext_vector_type(4)));
typedef short  bf16x8 __attribute__((ext_vector_type(8)));
typedef _Float16 f16x8 __attribute__((ext_vector_type(8)));
typedef unsigned int u32;

typedef __attribute__((address_space(1))) const unsigned int gu32;
typedef __attribute__((address_space(3))) unsigned int lu32;

__device__ __forceinline__ unsigned short f2b(float f) {
  unsigned int u = __builtin_bit_cast(unsigned int, f);
  u += 0x7fffu + ((u >> 16) & 1u);
  return (unsigned short)(u >> 16);
}
__device__ __forceinline__ float b2f(unsigned short s) {
  return __builtin_bit_cast(float, ((unsigned int)s) << 16);
}
__device__ __forceinline__ unsigned short f2h(float f) {
  _Float16 h = (_Float16)f;
  return __builtin_bit_cast(unsigned short, h);
}
__device__ __forceinline__ float h2f(unsigned short s) {
  return (float)__builtin_bit_cast(_Float16, s);
}

__device__ __forceinline__ void gload_lds16(const void* g, void* l) {
  gu32* gp = reinterpret_cast<gu32*>(reinterpret_cast<uintptr_t>(g));
  lu32* lp = reinterpret_cast<lu32*>(reinterpret_cast<uintptr_t>(l));
  __builtin_amdgcn_global_load_lds(gp, lp, 16, 0, 0);
}

// Real-time guard between MFMA acc writes and first VALU/DPP consumer
// (R20-verified: gfx950 needs genuine delay, not register-copy fences).
__device__ __forceinline__ void mfma_guard() {
  __builtin_amdgcn_sched_barrier(0);
  asm volatile("s_nop 7\n\ts_nop 7\n\ts_nop 7\n\ts_nop 7");
  __builtin_amdgcn_sched_barrier(0);
}

// ---------------- pack/convert: f32 -> bf16 (R3-verified) ----------------
__global__ void convert_all(const float* __restrict__ x,
                            const float* __restrict__ wq,
                            const float* __restrict__ wk,
                            const float* __restrict__ wv,
                            const float* __restrict__ wo,
                            unsigned short* __restrict__ xb,
                            unsigned short* __restrict__ wqkv,
                            unsigned short* __restrict__ wob)
{
  const int XN = SEQ * DM;
  const int WN = DM * DM;
  const int total4 = (XN + 4 * WN) >> 2;
  for (int i = blockIdx.x * blockDim.x + threadIdx.x; i < total4;
       i += gridDim.x * blockDim.x) {
    const int base = i << 2;
    const float* src;
    unsigned short* dst;
    if (base < XN)                 { src = x  + base;               dst = xb   + base; }
    else if (base < XN + WN)       { src = wq + (base - XN);        dst = wqkv + (base - XN); }
    else if (base < XN + 2 * WN)   { src = wk + (base - XN - WN);   dst = wqkv + (base - XN); }
    else if (base < XN + 3 * WN)   { src = wv + (base - XN - 2*WN); dst = wqkv + (base - XN); }
    else                           { src = wo + (base - XN - 3*WN); dst = wob  + (base - XN - 3*WN); }
    const float4 v = *(const float4*)src;
    *(ushort4*)dst = make_ushort4(f2b(v.x), f2b(v.y), f2b(v.z), f2b(v.w));
  }
}

// ---------------- GEMM C = A[M,K] * B[N,K]^T (R3-verified, bf16 MFMA) --------
// EPI 0: Q/K row-major f16; V written TRANSPOSED [h][dk][s] f16 (R2≡R4 verified)
// XCD-aware block swizzle (T1, bijective: nwg % 8 == 0 for both grids).
template<int EPI>
__global__ __launch_bounds__(256, 2)
void gemm_bt(const unsigned short* __restrict__ A,
             const unsigned short* __restrict__ B,
             unsigned short* __restrict__ qb,
             unsigned short* __restrict__ kb,
             unsigned short* __restrict__ vt,
             const float* __restrict__ bq,
             const float* __restrict__ bk,
             const float* __restrict__ bv,
             const float* __restrict__ bo,
             float* __restrict__ outf)
{
  __shared__ __align__(16) unsigned short As[128 * 32];
  __shared__ __align__(16) unsigned short Bs[128 * 32];
  const int t  = threadIdx.x;
  const int w  = t >> 6;
  const int l  = t & 63;

  // XCD swizzle: contiguous work chunks per XCD (round-robin dispatch)
  const int nwg  = gridDim.x * gridDim.y;
  const int flat = blockIdx.y * gridDim.x + blockIdx.x;
  const int cpx  = nwg >> 3;
  const int wid  = (flat & 7) * cpx + (flat >> 3);
  const int m0 = (wid / gridDim.x) * 128;
  const int n0 = (wid % gridDim.x) * 128;

  const int wr = (w >> 1) * 64;
  const int wc = (w & 1) * 64;
  const int lr = l & 15;
  const int lk = (l >> 4) * 8;

  const int row1 = t >> 2;
  const int row2 = row1 + 64;
  const int seg  = t & 3;

  f32x4 acc[4][4];
#pragma unroll
  for (int i = 0; i < 4; i++)
#pragma unroll
    for (int j = 0; j < 4; j++) acc[i][j] = (f32x4){0.f, 0.f, 0.f, 0.f};

  char* ldsA0 = (char*)As + (size_t)(w * 64) * 16;
  char* ldsA1 = (char*)As + (size_t)(w * 64 + 256) * 16;
  char* ldsB0 = (char*)Bs + (size_t)(w * 64) * 16;
  char* ldsB1 = (char*)Bs + (size_t)(w * 64 + 256) * 16;

  for (int k0 = 0; k0 < KD; k0 += 32) {
    gload_lds16(A + (size_t)(m0 + row1) * KD + k0 + seg * 8, ldsA0);
    gload_lds16(A + (size_t)(m0 + row2) * KD + k0 + seg * 8, ldsA1);
    gload_lds16(B + (size_t)(n0 + row1) * KD + k0 + seg * 8, ldsB0);
    gload_lds16(B + (size_t)(n0 + row2) * KD + k0 + seg * 8, ldsB1);
    __syncthreads();
    bf16x8 af[4], bfv[4];
#pragma unroll
    for (int fi = 0; fi < 4; fi++)
      af[fi] = *(const bf16x8*)(As + (wr + fi * 16 + lr) * 32 + lk);
#pragma unroll
    for (int fj = 0; fj < 4; fj++)
      bfv[fj] = *(const bf16x8*)(Bs + (wc + fj * 16 + lr) * 32 + lk);
#pragma unroll
    for (int fi = 0; fi < 4; fi++)
#pragma unroll
      for (int fj = 0; fj < 4; fj++)
        acc[fi][fj] = __builtin_amdgcn_mfma_f32_16x16x32_bf16(af[fi], bfv[fj], acc[fi][fj], 0, 0, 0);
    __syncthreads();
  }

  mfma_guard();

#pragma unroll
  for (int fi = 0; fi < 4; fi++) {
    const int mbase = m0 + wr + fi * 16 + (l >> 4) * 4;
#pragma unroll
    for (int fj = 0; fj < 4; fj++) {
      const int n = n0 + wc + fj * 16 + lr;
      if (EPI == 1) {
        const float bb = bo[n];
#pragma unroll
        for (int r = 0; r < 4; r++)
          outf[(size_t)(mbase + r) * DM + n] = acc[fi][fj][r] + bb;
      } else if (n < DM) {                       // Q (scaled by 1/8) -> f16
        const int hh = n >> 6, dk = n & 63;
        const float bb = bq[n];
#pragma unroll
        for (int r = 0; r < 4; r++)
          qb[((size_t)hh * SEQ + mbase + r) * HD + dk] = f2h((acc[fi][fj][r] + bb) * 0.125f);
      } else if (n < 2 * DM) {                   // K row-major [h][s][dk] -> f16
        const int n2 = n - DM, hh = n2 >> 6, dk = n2 & 63;
        const float bb = bk[n2];
#pragma unroll
        for (int r = 0; r < 4; r++)
          kb[((size_t)hh * SEQ + mbase + r) * HD + dk] = f2h(acc[fi][fj][r] + bb);
      } else {                                   // V -> transposed [h][dk][s] f16
        const int n3 = n - 2 * DM, hh = n3 >> 6, dk = n3 & 63;
        const float bb = bv[n3];
        ushort4 ov = make_ushort4(f2h(acc[fi][fj][0] + bb), f2h(acc[fi][fj][1] + bb),
                                  f2h(acc[fi][fj][2] + bb), f2h(acc[fi][fj][3] + bb));
        *(ushort4*)(vt + ((size_t)hh * HD + dk) * SEQ + mbase) = ov;
      }
    }
  }
}

// ------ MFMA band attention + merged global row -------------------------------
// grid (SEQ/64 + 1, NH). blockIdx.x < 64: band blocks (R21-verified defer-max
// MFMA path). blockIdx.x == 64: global row for query 0 (runs CONCURRENTLY with
// band blocks; overwrites ctx row 0 computed band-only by block 0).
#define PSTR 72
__global__ __launch_bounds__(256, 2)
void attn_fused(const unsigned short* __restrict__ qb,
                const unsigned short* __restrict__ kb,
                const unsigned short* __restrict__ vt,
                unsigned short* __restrict__ ctx)
{
  __shared__ __align__(16) unsigned short Qs[64 * 64];
  __shared__ __align__(16) unsigned short Ks[2][64 * 64];
  __shared__ __align__(16) unsigned short Vts[2][64 * 64];
  __shared__ __align__(16) unsigned short plds[4][16 * PSTR];
  const int h = blockIdx.y;
  const int t = threadIdx.x;
  const unsigned short* Qh  = qb + (size_t)h * SEQ * HD;
  const unsigned short* Kh  = kb + (size_t)h * SEQ * HD;
  const unsigned short* Vth = vt + (size_t)h * HD * SEQ;

  if (blockIdx.x == (SEQ / 64)) {
    // ============== global row path (query 0, all keys) =====================
    float* sc   = (float*)&Ks[0][0];          // 16 KB = 4096 f32
    float* q0   = (float*)&Qs[0];             // 64 f32
    float* red  = q0 + 64;                    // 4 f32
    float* accl = red + 8;                    // 4*64 f32
    if (t < HD) q0[t] = h2f(Qh[t]);           // pre-scaled by 1/8
    __syncthreads();

    for (int j = t; j < SEQ; j += 256) {
      const unsigned short* Kp = Kh + (size_t)j * HD;
      float a0 = 0.f, a1 = 0.f;
      for (int d0 = 0; d0 < 8; d0++) {
        const bf16x8 kv = *(const bf16x8*)(Kp + d0 * 8);
#pragma unroll
        for (int e = 0; e < 8; e += 2) {
          a0 += q0[d0 * 8 + e]     * h2f((unsigned short)kv[e]);
          a1 += q0[d0 * 8 + e + 1] * h2f((unsigned short)kv[e + 1]);
        }
      }
      sc[j] = a0 + a1;
    }
    __syncthreads();

    float mx = -1e30f;
    for (int j = t; j < SEQ; j += 256) mx = fmaxf(mx, sc[j]);
    for (int d = 1; d < 64; d <<= 1) mx = fmaxf(mx, __shfl_xor(mx, d));
    if ((t & 63) == 0) red[t >> 6] = mx;
    __syncthreads();
    mx = fmaxf(fmaxf(red[0], red[1]), fmaxf(red[2], red[3]));
    __syncthreads();

    float sum = 0.f;
    for (int j = t; j < SEQ; j += 256) {
      const float p = __expf(sc[j] - mx);
      sc[j] = p;
      sum += p;
    }
    for (int d = 1; d < 64; d <<= 1) sum += __shfl_xor(sum, d);
    __syncthreads();
    if ((t & 63) == 0) red[t >> 6] = sum;
    __syncthreads();
    const float inv = 1.f / (red[0] + red[1] + red[2] + red[3]);

    const int dd = t & 63, part = t >> 6;
    const unsigned short* Vp = Vth + (size_t)dd * SEQ;
    float a0 = 0.f, a1 = 0.f, a2 = 0.f, a3 = 0.f;
    const int jb = part * 1024;
    for (int j = 0; j < 1024; j += 4) {
      a0 += sc[jb + j + 0] * h2f(Vp[jb + j + 0]);
      a1 += sc[jb + j + 1] * h2f(Vp[jb + j + 1]);
      a2 += sc[jb + j + 2] * h2f(Vp[jb + j + 2]);
      a3 += sc[jb + j + 3] * h2f(Vp[jb + j + 3]);
    }
    accl[part * 64 + dd] = (a0 + a1) + (a2 + a3);
    __syncthreads();
    if (part == 0) {
      const float v = (accl[0 * 64 + dd] + accl[1 * 64 + dd] +
                       accl[2 * 64 + dd] + accl[3 * 64 + dd]) * inv;
      ctx[(size_t)h * HD + dd] = f2b(v);   // row 0
    }
    return;
  }

  // ================= band path (R21-verified) ===============================
  const int i0 = blockIdx.x * 64;
  const int w  = t >> 6, l = t & 63;
  const int lr = l & 15, lk = (l >> 4) * 8;
  const int cb = (l >> 4);
  const int qi0 = i0 + w * 16 + (l >> 4) * 4;

  const int srow = t >> 3;
  const int scol = (t & 7) ^ (srow & 7);

  gload_lds16(Qh + (size_t)(i0 + srow) * HD + scol * 8, (char*)Qs + t * 16);
  gload_lds16(Qh + (size_t)(i0 + 32 + srow) * HD + scol * 8, (char*)Qs + 4096 + t * 16);

  int lo = i0 - 256; if (lo < 0) lo = 0;
  int hi = i0 + 63 + 257; if (hi > SEQ) hi = SEQ;
  const int cbeg = lo >> 6, cend = (hi - 1) >> 6;
  const int pre  = (cbeg > 0) ? 1 : 0;
  const int nch  = cend - cbeg + 1 + pre;

  auto chunkof = [&](int it) -> int {
    return (pre && it == 0) ? 0 : (cbeg + it - pre);
  };
  auto stage = [&](int bsel, int cch) {
    const int jj0 = cch * 64;
    char* kd = (char*)(&Ks[bsel][0]);
    char* vd = (char*)(&Vts[bsel][0]);
    gload_lds16(Kh + (size_t)(jj0 + srow) * HD + scol * 8, kd + t * 16);
    gload_lds16(Kh + (size_t)(jj0 + 32 + srow) * HD + scol * 8, kd + 4096 + t * 16);
    gload_lds16(Vth + (size_t)srow * SEQ + jj0 + scol * 8, vd + t * 16);
    gload_lds16(Vth + (size_t)(32 + srow) * SEQ + jj0 + scol * 8, vd + 4096 + t * 16);
  };
  auto frag = [&](const unsigned short* base, int rr, int cc) -> f16x8 {
    return __builtin_bit_cast(f16x8,
        *(const bf16x8*)(base + rr * 64 + ((cc ^ (rr & 7)) * 8)));
  };

  stage(0, chunkof(0));
  __syncthreads();

  // loop-invariant Q fragments (hoisted: Qs never rewritten after barrier)
  const f16x8 qa0 = frag(Qs, w * 16 + lr, cb);
  const f16x8 qa1 = frag(Qs, w * 16 + lr, cb + 4);

  f32x4 o[4];
#pragma unroll
  for (int i = 0; i < 4; i++) o[i] = (f32x4){0.f, 0.f, 0.f, 0.f};
  float mrow[4] = {-1e30f, -1e30f, -1e30f, -1e30f};
  float ls[4]   = {0.f, 0.f, 0.f, 0.f};
  unsigned short* P = &plds[w][0];

  for (int it = 0; it < nch; ++it) {
    if (it + 1 < nch) stage((it + 1) & 1, chunkof(it + 1));

    const int c  = chunkof(it);
    const int j0 = c * 64;
    const unsigned short* Kc = &Ks[it & 1][0];
    const unsigned short* Vc = &Vts[it & 1][0];

    f32x4 sc[4];
#pragma unroll
    for (int i = 0; i < 4; i++) sc[i] = (f32x4){0.f, 0.f, 0.f, 0.f};
#pragma unroll
    for (int fj = 0; fj < 4; fj++) {
      const f16x8 kf0 = frag(Kc, fj * 16 + lr, cb);
      const f16x8 kf1 = frag(Kc, fj * 16 + lr, cb + 4);
      sc[fj] = __builtin_amdgcn_mfma_f32_16x16x32_f16(qa0, kf0, sc[fj], 0, 0, 0);
      sc[fj] = __builtin_amdgcn_mfma_f32_16x16x32_f16(qa1, kf1, sc[fj], 0, 0, 0);
    }
    mfma_guard();

    bool exceed = false;
#pragma unroll
    for (int r = 0; r < 4; r++) {
      const int qi = qi0 + r;
#pragma unroll
      for (int fj = 0; fj < 4; fj++) {
        const int j = j0 + fj * 16 + lr;
        const bool valid = (j == 0) || ((j - qi) <= 256 && (qi - j) <= 256);
        const float v = valid ? sc[fj][r] : -1e30f;
        sc[fj][r] = v;
        exceed |= (v > mrow[r] + 8.f);
      }
    }
    if (__any(exceed)) {
#pragma unroll
      for (int r = 0; r < 4; r++) {
        float mx = fmaxf(fmaxf(sc[0][r], sc[1][r]), fmaxf(sc[2][r], sc[3][r]));
        for (int d = 1; d < 16; d <<= 1) mx = fmaxf(mx, __shfl_xor(mx, d));
        const float mnew  = fmaxf(mrow[r], mx);
        const float scale = __expf(mrow[r] - mnew);
        mrow[r] = mnew;
        ls[r] *= scale;
#pragma unroll
        for (int fn = 0; fn < 4; fn++) o[fn][r] *= scale;
      }
    }
#pragma unroll
    for (int r = 0; r < 4; r++) {
      float psum = 0.f;
#pragma unroll
      for (int fj = 0; fj < 4; fj++) {
        const float p = __expf(sc[fj][r] - mrow[r]);
        sc[fj][r] = p;
        psum += p;
      }
      ls[r] += psum;
    }

#pragma unroll
    for (int fj = 0; fj < 4; fj++)
#pragma unroll
      for (int r = 0; r < 4; r++)
        P[(size_t)((l >> 4) * 4 + r) * PSTR + fj * 16 + lr] = f2h(sc[fj][r]);
    __syncthreads();

    const f16x8 pf0 = __builtin_bit_cast(f16x8, *(const bf16x8*)(P + lr * PSTR + lk));
    const f16x8 pf1 = __builtin_bit_cast(f16x8, *(const bf16x8*)(P + lr * PSTR + 32 + lk));
#pragma unroll
    for (int fn = 0; fn < 4; fn++) {
      const f16x8 vf0 = frag(Vc, fn * 16 + lr, cb);
      const f16x8 vf1 = frag(Vc, fn * 16 + lr, cb + 4);
      o[fn] = __builtin_amdgcn_mfma_f32_16x16x32_f16(pf0, vf0, o[fn], 0, 0, 0);
      o[fn] = __builtin_amdgcn_mfma_f32_16x16x32_f16(pf1, vf1, o[fn], 0, 0, 0);
    }
    __syncthreads();
  }

  mfma_guard();

#pragma unroll
  for (int r = 0; r < 4; r++)
    for (int d = 1; d < 16; d <<= 1) ls[r] += __shfl_xor(ls[r], d);

#pragma unroll
  for (int fn = 0; fn < 4; fn++)
#pragma unroll
    for (int r = 0; r < 4; r++) {
      const int s = qi0 + r;
      const float val = o[fn][r] / ls[r];
      ctx[(size_t)s * DM + h * HD + fn * 16 + lr] = f2b(val);
    }
}

// ---------------- launch ----------------
extern "C" void kernel_launch(void* const* d_in, const int* in_sizes, int n_in,
                              void* d_out, int out_size, void* d_ws, size_t ws_size,
                              hipStream_t stream)
{
  (void)in_sizes; (void)n_in; (void)out_size; (void)ws_size;
  const float* x  = (const float*)d_in[0];
  const float* Wq = (const float*)d_in[1];
  const float* bq = (const float*)d_in[2];
  const float* Wk = (const float*)d_in[3];
  const float* bk = (const float*)d_in[4];
  const float* Wv = (const float*)d_in[5];
  const float* bv = (const float*)d_in[6];
  const float* Wo = (const float*)d_in[7];
  const float* bo = (const float*)d_in[8];
  float* out = (float*)d_out;

  char* ws = (char*)d_ws;
  unsigned short* xb   = (unsigned short*)(ws + 0);         // dead after gemm<0>
  unsigned short* wqkv = (unsigned short*)(ws + 6291456);
  unsigned short* wob  = (unsigned short*)(ws + 9830400);
  unsigned short* qbuf = (unsigned short*)(ws + 11010048);  // [12][4096][64] f16
  unsigned short* kbuf = (unsigned short*)(ws + 17301504);  // [12][4096][64] f16
  unsigned short* vtb  = (unsigned short*)(ws + 23592960);  // [12][64][4096] f16
  unsigned short* ctx  = (unsigned short*)(ws + 0);         // bf16, aliases xb

  convert_all<<<dim3(1024), dim3(256), 0, stream>>>(x, Wq, Wk, Wv, Wo, xb, wqkv, wob);
  gemm_bt<0><<<dim3(18, 32), dim3(256), 0, stream>>>(xb, wqkv, qbuf, kbuf, vtb,
                                                     bq, bk, bv, nullptr, nullptr);
  attn_fused<<<dim3(SEQ / 64 + 1, NH), dim3(256), 0, stream>>>(qbuf, kbuf, vtb, ctx);
  gemm_bt<1><<<dim3(6, 32), dim3(256), 0, stream>>>(ctx, wob, nullptr, nullptr, nullptr,
                                                    nullptr, nullptr, nullptr, bo, out);
}

// Round 23
// 104.465 us; speedup vs baseline: 91.9874x; 1.0038x over previous
//
#include <hip/hip_runtime.h>
#include <cstdint>

#define SEQ   4096
#define DM    768
#define NH    12
#define HD    64
#define KD    768

typedef float  f32x4  __attribute__((ext_vector_type(4)));
typedef short  bf16x8 __attribute__((ext_vector_type(8)));
typedef _Float16 f16x8 __attribute__((ext_vector_type(8)));
typedef unsigned int u32;

typedef __attribute__((address_space(1))) const unsigned int gu32;
typedef __attribute__((address_space(3))) unsigned int lu32;

__device__ __forceinline__ unsigned short f2b(float f) {
  unsigned int u = __builtin_bit_cast(unsigned int, f);
  u += 0x7fffu + ((u >> 16) & 1u);
  return (unsigned short)(u >> 16);
}
__device__ __forceinline__ float b2f(unsigned short s) {
  return __builtin_bit_cast(float, ((unsigned int)s) << 16);
}
__device__ __forceinline__ unsigned short f2h(float f) {
  _Float16 h = (_Float16)f;
  return __builtin_bit_cast(unsigned short, h);
}
__device__ __forceinline__ float h2f(unsigned short s) {
  return (float)__builtin_bit_cast(_Float16, s);
}

__device__ __forceinline__ void gload_lds16(const void* g, void* l) {
  gu32* gp = reinterpret_cast<gu32*>(reinterpret_cast<uintptr_t>(g));
  lu32* lp = reinterpret_cast<lu32*>(reinterpret_cast<uintptr_t>(l));
  __builtin_amdgcn_global_load_lds(gp, lp, 16, 0, 0);
}

// Real-time guard between MFMA acc writes and first VALU/DPP consumer
// (R20-verified: gfx950 needs genuine delay, not register-copy fences).
__device__ __forceinline__ void mfma_guard() {
  __builtin_amdgcn_sched_barrier(0);
  asm volatile("s_nop 7\n\ts_nop 7\n\ts_nop 7\n\ts_nop 7");
  __builtin_amdgcn_sched_barrier(0);
}

// ---------------- pack/convert: f32 -> bf16 (R3-verified) ----------------
__global__ void convert_all(const float* __restrict__ x,
                            const float* __restrict__ wq,
                            const float* __restrict__ wk,
                            const float* __restrict__ wv,
                            const float* __restrict__ wo,
                            unsigned short* __restrict__ xb,
                            unsigned short* __restrict__ wqkv,
                            unsigned short* __restrict__ wob)
{
  const int XN = SEQ * DM;
  const int WN = DM * DM;
  const int total4 = (XN + 4 * WN) >> 2;
  for (int i = blockIdx.x * blockDim.x + threadIdx.x; i < total4;
       i += gridDim.x * blockDim.x) {
    const int base = i << 2;
    const float* src;
    unsigned short* dst;
    if (base < XN)                 { src = x  + base;               dst = xb   + base; }
    else if (base < XN + WN)       { src = wq + (base - XN);        dst = wqkv + (base - XN); }
    else if (base < XN + 2 * WN)   { src = wk + (base - XN - WN);   dst = wqkv + (base - XN); }
    else if (base < XN + 3 * WN)   { src = wv + (base - XN - 2*WN); dst = wqkv + (base - XN); }
    else                           { src = wo + (base - XN - 3*WN); dst = wob  + (base - XN - 3*WN); }
    const float4 v = *(const float4*)src;
    *(ushort4*)dst = make_ushort4(f2b(v.x), f2b(v.y), f2b(v.z), f2b(v.w));
  }
}

// ---------------- GEMM C = A[M,K] * B[N,K]^T (R3-verified, bf16 MFMA) --------
// EPI 0: Q/K row-major f16; V written TRANSPOSED [h][dk][s] f16 (R2≡R4 verified)
// XCD-aware block swizzle (T1, bijective: nwg % 8 == 0 for both grids).
template<int EPI>
__global__ __launch_bounds__(256, 2)
void gemm_bt(const unsigned short* __restrict__ A,
             const unsigned short* __restrict__ B,
             unsigned short* __restrict__ qb,
             unsigned short* __restrict__ kb,
             unsigned short* __restrict__ vt,
             const float* __restrict__ bq,
             const float* __restrict__ bk,
             const float* __restrict__ bv,
             const float* __restrict__ bo,
             float* __restrict__ outf)
{
  __shared__ __align__(16) unsigned short As[128 * 32];
  __shared__ __align__(16) unsigned short Bs[128 * 32];
  const int t  = threadIdx.x;
  const int w  = t >> 6;
  const int l  = t & 63;

  // XCD swizzle: contiguous work chunks per XCD (round-robin dispatch)
  const int nwg  = gridDim.x * gridDim.y;
  const int flat = blockIdx.y * gridDim.x + blockIdx.x;
  const int cpx  = nwg >> 3;
  const int wid  = (flat & 7) * cpx + (flat >> 3);
  const int m0 = (wid / gridDim.x) * 128;
  const int n0 = (wid % gridDim.x) * 128;

  const int wr = (w >> 1) * 64;
  const int wc = (w & 1) * 64;
  const int lr = l & 15;
  const int lk = (l >> 4) * 8;

  const int row1 = t >> 2;
  const int row2 = row1 + 64;
  const int seg  = t & 3;

  f32x4 acc[4][4];
#pragma unroll
  for (int i = 0; i < 4; i++)
#pragma unroll
    for (int j = 0; j < 4; j++) acc[i][j] = (f32x4){0.f, 0.f, 0.f, 0.f};

  char* ldsA0 = (char*)As + (size_t)(w * 64) * 16;
  char* ldsA1 = (char*)As + (size_t)(w * 64 + 256) * 16;
  char* ldsB0 = (char*)Bs + (size_t)(w * 64) * 16;
  char* ldsB1 = (char*)Bs + (size_t)(w * 64 + 256) * 16;

  for (int k0 = 0; k0 < KD; k0 += 32) {
    gload_lds16(A + (size_t)(m0 + row1) * KD + k0 + seg * 8, ldsA0);
    gload_lds16(A + (size_t)(m0 + row2) * KD + k0 + seg * 8, ldsA1);
    gload_lds16(B + (size_t)(n0 + row1) * KD + k0 + seg * 8, ldsB0);
    gload_lds16(B + (size_t)(n0 + row2) * KD + k0 + seg * 8, ldsB1);
    __syncthreads();
    bf16x8 af[4], bfv[4];
#pragma unroll
    for (int fi = 0; fi < 4; fi++)
      af[fi] = *(const bf16x8*)(As + (wr + fi * 16 + lr) * 32 + lk);
#pragma unroll
    for (int fj = 0; fj < 4; fj++)
      bfv[fj] = *(const bf16x8*)(Bs + (wc + fj * 16 + lr) * 32 + lk);
#pragma unroll
    for (int fi = 0; fi < 4; fi++)
#pragma unroll
      for (int fj = 0; fj < 4; fj++)
        acc[fi][fj] = __builtin_amdgcn_mfma_f32_16x16x32_bf16(af[fi], bfv[fj], acc[fi][fj], 0, 0, 0);
    __syncthreads();
  }

  mfma_guard();

#pragma unroll
  for (int fi = 0; fi < 4; fi++) {
    const int mbase = m0 + wr + fi * 16 + (l >> 4) * 4;
#pragma unroll
    for (int fj = 0; fj < 4; fj++) {
      const int n = n0 + wc + fj * 16 + lr;
      if (EPI == 1) {
        const float bb = bo[n];
#pragma unroll
        for (int r = 0; r < 4; r++)
          outf[(size_t)(mbase + r) * DM + n] = acc[fi][fj][r] + bb;
      } else if (n < DM) {                       // Q (scaled by 1/8) -> f16
        const int hh = n >> 6, dk = n & 63;
        const float bb = bq[n];
#pragma unroll
        for (int r = 0; r < 4; r++)
          qb[((size_t)hh * SEQ + mbase + r) * HD + dk] = f2h((acc[fi][fj][r] + bb) * 0.125f);
      } else if (n < 2 * DM) {                   // K row-major [h][s][dk] -> f16
        const int n2 = n - DM, hh = n2 >> 6, dk = n2 & 63;
        const float bb = bk[n2];
#pragma unroll
        for (int r = 0; r < 4; r++)
          kb[((size_t)hh * SEQ + mbase + r) * HD + dk] = f2h(acc[fi][fj][r] + bb);
      } else {                                   // V -> transposed [h][dk][s] f16
        const int n3 = n - 2 * DM, hh = n3 >> 6, dk = n3 & 63;
        const float bb = bv[n3];
        ushort4 ov = make_ushort4(f2h(acc[fi][fj][0] + bb), f2h(acc[fi][fj][1] + bb),
                                  f2h(acc[fi][fj][2] + bb), f2h(acc[fi][fj][3] + bb));
        *(ushort4*)(vt + ((size_t)hh * HD + dk) * SEQ + mbase) = ov;
      }
    }
  }
}

// ------ MFMA band attention + merged global row -------------------------------
// grid (SEQ/64 + 1, NH). blockIdx.x < 64: band blocks. blockIdx.x == 64: global
// row for query 0 (concurrent; overwrites ctx row 0).
// R23: no Qs tile (Q fragments direct from global), plds unpadded + XOR-swizzled
// (same involution as K/V tiles), mid-loop barrier removed (plds is wave-private).
// LDS = 16K + 16K + 8K = 40960 B -> 4 blocks/CU.
__global__ __launch_bounds__(256, 2)
void attn_fused(const unsigned short* __restrict__ qb,
                const unsigned short* __restrict__ kb,
                const unsigned short* __restrict__ vt,
                unsigned short* __restrict__ ctx)
{
  __shared__ __align__(16) unsigned short Ks[2][64 * 64];
  __shared__ __align__(16) unsigned short Vts[2][64 * 64];
  __shared__ __align__(16) unsigned short plds[4][16 * 64];
  const int h = blockIdx.y;
  const int t = threadIdx.x;
  const unsigned short* Qh  = qb + (size_t)h * SEQ * HD;
  const unsigned short* Kh  = kb + (size_t)h * SEQ * HD;
  const unsigned short* Vth = vt + (size_t)h * HD * SEQ;

  if (blockIdx.x == (SEQ / 64)) {
    // ============== global row path (query 0, all keys) =====================
    float* sc   = (float*)&Ks[0][0];          // 16 KB = 4096 f32 (spans Ks[0..1])
    float* q0   = (float*)&plds[0][0];        // 64 f32
    float* red  = q0 + 64;                    // 4 f32
    float* accl = red + 8;                    // 4*64 f32
    if (t < HD) q0[t] = h2f(Qh[t]);           // pre-scaled by 1/8
    __syncthreads();

    for (int j = t; j < SEQ; j += 256) {
      const unsigned short* Kp = Kh + (size_t)j * HD;
      float a0 = 0.f, a1 = 0.f;
      for (int d0 = 0; d0 < 8; d0++) {
        const bf16x8 kv = *(const bf16x8*)(Kp + d0 * 8);
#pragma unroll
        for (int e = 0; e < 8; e += 2) {
          a0 += q0[d0 * 8 + e]     * h2f((unsigned short)kv[e]);
          a1 += q0[d0 * 8 + e + 1] * h2f((unsigned short)kv[e + 1]);
        }
      }
      sc[j] = a0 + a1;
    }
    __syncthreads();

    float mx = -1e30f;
    for (int j = t; j < SEQ; j += 256) mx = fmaxf(mx, sc[j]);
    for (int d = 1; d < 64; d <<= 1) mx = fmaxf(mx, __shfl_xor(mx, d));
    if ((t & 63) == 0) red[t >> 6] = mx;
    __syncthreads();
    mx = fmaxf(fmaxf(red[0], red[1]), fmaxf(red[2], red[3]));
    __syncthreads();

    float sum = 0.f;
    for (int j = t; j < SEQ; j += 256) {
      const float p = __expf(sc[j] - mx);
      sc[j] = p;
      sum += p;
    }
    for (int d = 1; d < 64; d <<= 1) sum += __shfl_xor(sum, d);
    __syncthreads();
    if ((t & 63) == 0) red[t >> 6] = sum;
    __syncthreads();
    const float inv = 1.f / (red[0] + red[1] + red[2] + red[3]);

    const int dd = t & 63, part = t >> 6;
    const unsigned short* Vp = Vth + (size_t)dd * SEQ;
    float a0 = 0.f, a1 = 0.f, a2 = 0.f, a3 = 0.f;
    const int jb = part * 1024;
    for (int j = 0; j < 1024; j += 4) {
      a0 += sc[jb + j + 0] * h2f(Vp[jb + j + 0]);
      a1 += sc[jb + j + 1] * h2f(Vp[jb + j + 1]);
      a2 += sc[jb + j + 2] * h2f(Vp[jb + j + 2]);
      a3 += sc[jb + j + 3] * h2f(Vp[jb + j + 3]);
    }
    accl[part * 64 + dd] = (a0 + a1) + (a2 + a3);
    __syncthreads();
    if (part == 0) {
      const float v = (accl[0 * 64 + dd] + accl[1 * 64 + dd] +
                       accl[2 * 64 + dd] + accl[3 * 64 + dd]) * inv;
      ctx[(size_t)h * HD + dd] = f2b(v);   // row 0
    }
    return;
  }

  // ================= band path ==============================================
  const int i0 = blockIdx.x * 64;
  const int w  = t >> 6, l = t & 63;
  const int lr = l & 15;
  const int cb = (l >> 4);
  const int qi0 = i0 + w * 16 + (l >> 4) * 4;

  const int srow = t >> 3;
  const int scol = (t & 7) ^ (srow & 7);

  // Q fragments: loop-invariant, loaded DIRECTLY from global (one row, 2x16B)
  const int qrow = i0 + w * 16 + lr;
  const f16x8 qa0 = __builtin_bit_cast(f16x8,
      *(const bf16x8*)(Qh + (size_t)qrow * HD + cb * 8));
  const f16x8 qa1 = __builtin_bit_cast(f16x8,
      *(const bf16x8*)(Qh + (size_t)qrow * HD + (cb + 4) * 8));

  int lo = i0 - 256; if (lo < 0) lo = 0;
  int hi = i0 + 63 + 257; if (hi > SEQ) hi = SEQ;
  const int cbeg = lo >> 6, cend = (hi - 1) >> 6;
  const int pre  = (cbeg > 0) ? 1 : 0;
  const int nch  = cend - cbeg + 1 + pre;

  auto chunkof = [&](int it) -> int {
    return (pre && it == 0) ? 0 : (cbeg + it - pre);
  };
  auto stage = [&](int bsel, int cch) {
    const int jj0 = cch * 64;
    char* kd = (char*)(&Ks[bsel][0]);
    char* vd = (char*)(&Vts[bsel][0]);
    gload_lds16(Kh + (size_t)(jj0 + srow) * HD + scol * 8, kd + t * 16);
    gload_lds16(Kh + (size_t)(jj0 + 32 + srow) * HD + scol * 8, kd + 4096 + t * 16);
    gload_lds16(Vth + (size_t)srow * SEQ + jj0 + scol * 8, vd + t * 16);
    gload_lds16(Vth + (size_t)(32 + srow) * SEQ + jj0 + scol * 8, vd + 4096 + t * 16);
  };
  auto frag = [&](const unsigned short* base, int rr, int cc) -> f16x8 {
    return __builtin_bit_cast(f16x8,
        *(const bf16x8*)(base + rr * 64 + ((cc ^ (rr & 7)) * 8)));
  };

  stage(0, chunkof(0));
  __syncthreads();

  f32x4 o[4];
#pragma unroll
  for (int i = 0; i < 4; i++) o[i] = (f32x4){0.f, 0.f, 0.f, 0.f};
  float mrow[4] = {-1e30f, -1e30f, -1e30f, -1e30f};
  float ls[4]   = {0.f, 0.f, 0.f, 0.f};
  unsigned short* P = &plds[w][0];

  for (int it = 0; it < nch; ++it) {
    if (it + 1 < nch) stage((it + 1) & 1, chunkof(it + 1));

    const int c  = chunkof(it);
    const int j0 = c * 64;
    const unsigned short* Kc = &Ks[it & 1][0];
    const unsigned short* Vc = &Vts[it & 1][0];

    f32x4 sc[4];
#pragma unroll
    for (int i = 0; i < 4; i++) sc[i] = (f32x4){0.f, 0.f, 0.f, 0.f};
#pragma unroll
    for (int fj = 0; fj < 4; fj++) {
      const f16x8 kf0 = frag(Kc, fj * 16 + lr, cb);
      const f16x8 kf1 = frag(Kc, fj * 16 + lr, cb + 4);
      sc[fj] = __builtin_amdgcn_mfma_f32_16x16x32_f16(qa0, kf0, sc[fj], 0, 0, 0);
      sc[fj] = __builtin_amdgcn_mfma_f32_16x16x32_f16(qa1, kf1, sc[fj], 0, 0, 0);
    }
    mfma_guard();

    bool exceed = false;
#pragma unroll
    for (int r = 0; r < 4; r++) {
      const int qi = qi0 + r;
#pragma unroll
      for (int fj = 0; fj < 4; fj++) {
        const int j = j0 + fj * 16 + lr;
        const bool valid = (j == 0) || ((j - qi) <= 256 && (qi - j) <= 256);
        const float v = valid ? sc[fj][r] : -1e30f;
        sc[fj][r] = v;
        exceed |= (v > mrow[r] + 8.f);
      }
    }
    if (__any(exceed)) {
#pragma unroll
      for (int r = 0; r < 4; r++) {
        float mx = fmaxf(fmaxf(sc[0][r], sc[1][r]), fmaxf(sc[2][r], sc[3][r]));
        for (int d = 1; d < 16; d <<= 1) mx = fmaxf(mx, __shfl_xor(mx, d));
        const float mnew  = fmaxf(mrow[r], mx);
        const float scale = __expf(mrow[r] - mnew);
        mrow[r] = mnew;
        ls[r] *= scale;
#pragma unroll
        for (int fn = 0; fn < 4; fn++) o[fn][r] *= scale;
      }
    }
#pragma unroll
    for (int r = 0; r < 4; r++) {
      float psum = 0.f;
#pragma unroll
      for (int fj = 0; fj < 4; fj++) {
        const float p = __expf(sc[fj][r] - mrow[r]);
        sc[fj][r] = p;
        psum += p;
      }
      ls[r] += psum;
    }

    // ---- P (C-layout, f16) -> wave-private LDS, XOR-block swizzled:
    //      element (row, e): block (e>>3) stored at slot (e>>3)^(row&7).
    //      frag(P, lr, cb) reads it back exactly (same involution). No block
    //      barrier needed: P is produced and consumed by THIS wave only.
#pragma unroll
    for (int fj = 0; fj < 4; fj++)
#pragma unroll
      for (int r = 0; r < 4; r++) {
        const int prow = (l >> 4) * 4 + r;
        const int e    = fj * 16 + lr;
        P[prow * 64 + (((e >> 3) ^ (prow & 7)) * 8) + (e & 7)] = f2h(sc[fj][r]);
      }

    const f16x8 pf0 = frag(P, lr, cb);
    const f16x8 pf1 = frag(P, lr, cb + 4);
#pragma unroll
    for (int fn = 0; fn < 4; fn++) {
      const f16x8 vf0 = frag(Vc, fn * 16 + lr, cb);
      const f16x8 vf1 = frag(Vc, fn * 16 + lr, cb + 4);
      o[fn] = __builtin_amdgcn_mfma_f32_16x16x32_f16(pf0, vf0, o[fn], 0, 0, 0);
      o[fn] = __builtin_amdgcn_mfma_f32_16x16x32_f16(pf1, vf1, o[fn], 0, 0, 0);
    }
    __syncthreads();   // prefetch landed + all waves done with buf[it&1]
  }

  mfma_guard();

#pragma unroll
  for (int r = 0; r < 4; r++)
    for (int d = 1; d < 16; d <<= 1) ls[r] += __shfl_xor(ls[r], d);

#pragma unroll
  for (int fn = 0; fn < 4; fn++)
#pragma unroll
    for (int r = 0; r < 4; r++) {
      const int s = qi0 + r;
      const float val = o[fn][r] / ls[r];
      ctx[(size_t)s * DM + h * HD + fn * 16 + lr] = f2b(val);
    }
}

// ---------------- launch ----------------
extern "C" void kernel_launch(void* const* d_in, const int* in_sizes, int n_in,
                              void* d_out, int out_size, void* d_ws, size_t ws_size,
                              hipStream_t stream)
{
  (void)in_sizes; (void)n_in; (void)out_size; (void)ws_size;
  const float* x  = (const float*)d_in[0];
  const float* Wq = (const float*)d_in[1];
  const float* bq = (const float*)d_in[2];
  const float* Wk = (const float*)d_in[3];
  const float* bk = (const float*)d_in[4];
  const float* Wv = (const float*)d_in[5];
  const float* bv = (const float*)d_in[6];
  const float* Wo = (const float*)d_in[7];
  const float* bo = (const float*)d_in[8];
  float* out = (float*)d_out;

  char* ws = (char*)d_ws;
  unsigned short* xb   = (unsigned short*)(ws + 0);         // dead after gemm<0>
  unsigned short* wqkv = (unsigned short*)(ws + 6291456);
  unsigned short* wob  = (unsigned short*)(ws + 9830400);
  unsigned short* qbuf = (unsigned short*)(ws + 11010048);  // [12][4096][64] f16
  unsigned short* kbuf = (unsigned short*)(ws + 17301504);  // [12][4096][64] f16
  unsigned short* vtb  = (unsigned short*)(ws + 23592960);  // [12][64][4096] f16
  unsigned short* ctx  = (unsigned short*)(ws + 0);         // bf16, aliases xb

  convert_all<<<dim3(1024), dim3(256), 0, stream>>>(x, Wq, Wk, Wv, Wo, xb, wqkv, wob);
  gemm_bt<0><<<dim3(18, 32), dim3(256), 0, stream>>>(xb, wqkv, qbuf, kbuf, vtb,
                                                     bq, bk, bv, nullptr, nullptr);
  attn_fused<<<dim3(SEQ / 64 + 1, NH), dim3(256), 0, stream>>>(qbuf, kbuf, vtb, ctx);
  gemm_bt<1><<<dim3(6, 32), dim3(256), 0, stream>>>(ctx, wob, nullptr, nullptr, nullptr,
                                                    nullptr, nullptr, nullptr, bo, out);
}

// Round 24
// 96.795 us; speedup vs baseline: 99.2768x; 1.0792x over previous
//
#include <hip/hip_runtime.h>
#include <cstdint>

#define SEQ   4096
#define DM    768
#define NH    12
#define HD    64
#define KD    768

typedef float  f32x4  __attribute__((ext_vector_type(4)));
typedef short  bf16x8 __attribute__((ext_vector_type(8)));
typedef _Float16 f16x8 __attribute__((ext_vector_type(8)));
typedef unsigned int u32;

typedef __attribute__((address_space(1))) const unsigned int gu32;
typedef __attribute__((address_space(3))) unsigned int lu32;

__device__ __forceinline__ unsigned short f2b(float f) {
  unsigned int u = __builtin_bit_cast(unsigned int, f);
  u += 0x7fffu + ((u >> 16) & 1u);
  return (unsigned short)(u >> 16);
}
__device__ __forceinline__ float b2f(unsigned short s) {
  return __builtin_bit_cast(float, ((unsigned int)s) << 16);
}
__device__ __forceinline__ unsigned short f2h(float f) {
  _Float16 h = (_Float16)f;
  return __builtin_bit_cast(unsigned short, h);
}
__device__ __forceinline__ float h2f(unsigned short s) {
  return (float)__builtin_bit_cast(_Float16, s);
}

__device__ __forceinline__ void gload_lds16(const void* g, void* l) {
  gu32* gp = reinterpret_cast<gu32*>(reinterpret_cast<uintptr_t>(g));
  lu32* lp = reinterpret_cast<lu32*>(reinterpret_cast<uintptr_t>(l));
  __builtin_amdgcn_global_load_lds(gp, lp, 16, 0, 0);
}

// Real-time guard between MFMA acc writes and first VALU/DPP consumer
// (R20-verified: gfx950 needs genuine delay, not register-copy fences).
__device__ __forceinline__ void mfma_guard() {
  __builtin_amdgcn_sched_barrier(0);
  asm volatile("s_nop 7\n\ts_nop 7\n\ts_nop 7\n\ts_nop 7");
  __builtin_amdgcn_sched_barrier(0);
}

// ---------------- pack/convert: f32 -> bf16 (R3-verified) ----------------
__global__ void convert_all(const float* __restrict__ x,
                            const float* __restrict__ wq,
                            const float* __restrict__ wk,
                            const float* __restrict__ wv,
                            const float* __restrict__ wo,
                            unsigned short* __restrict__ xb,
                            unsigned short* __restrict__ wqkv,
                            unsigned short* __restrict__ wob)
{
  const int XN = SEQ * DM;
  const int WN = DM * DM;
  const int total4 = (XN + 4 * WN) >> 2;
  for (int i = blockIdx.x * blockDim.x + threadIdx.x; i < total4;
       i += gridDim.x * blockDim.x) {
    const int base = i << 2;
    const float* src;
    unsigned short* dst;
    if (base < XN)                 { src = x  + base;               dst = xb   + base; }
    else if (base < XN + WN)       { src = wq + (base - XN);        dst = wqkv + (base - XN); }
    else if (base < XN + 2 * WN)   { src = wk + (base - XN - WN);   dst = wqkv + (base - XN); }
    else if (base < XN + 3 * WN)   { src = wv + (base - XN - 2*WN); dst = wqkv + (base - XN); }
    else                           { src = wo + (base - XN - 3*WN); dst = wob  + (base - XN - 3*WN); }
    const float4 v = *(const float4*)src;
    *(ushort4*)dst = make_ushort4(f2b(v.x), f2b(v.y), f2b(v.z), f2b(v.w));
  }
}

// ---------------- GEMM C = A[M,K] * B[N,K]^T (R3-verified, bf16 MFMA) --------
// EPI 0: Q/K row-major f16; V written TRANSPOSED [h][dk][s] f16 (R2≡R4 verified)
// XCD-aware block swizzle (T1, bijective: nwg % 8 == 0 for both grids).
template<int EPI>
__global__ __launch_bounds__(256, 2)
void gemm_bt(const unsigned short* __restrict__ A,
             const unsigned short* __restrict__ B,
             unsigned short* __restrict__ qb,
             unsigned short* __restrict__ kb,
             unsigned short* __restrict__ vt,
             const float* __restrict__ bq,
             const float* __restrict__ bk,
             const float* __restrict__ bv,
             const float* __restrict__ bo,
             float* __restrict__ outf)
{
  __shared__ __align__(16) unsigned short As[128 * 32];
  __shared__ __align__(16) unsigned short Bs[128 * 32];
  const int t  = threadIdx.x;
  const int w  = t >> 6;
  const int l  = t & 63;

  // XCD swizzle: contiguous work chunks per XCD (round-robin dispatch)
  const int nwg  = gridDim.x * gridDim.y;
  const int flat = blockIdx.y * gridDim.x + blockIdx.x;
  const int cpx  = nwg >> 3;
  const int wid  = (flat & 7) * cpx + (flat >> 3);
  const int m0 = (wid / gridDim.x) * 128;
  const int n0 = (wid % gridDim.x) * 128;

  const int wr = (w >> 1) * 64;
  const int wc = (w & 1) * 64;
  const int lr = l & 15;
  const int lk = (l >> 4) * 8;

  const int row1 = t >> 2;
  const int row2 = row1 + 64;
  const int seg  = t & 3;

  f32x4 acc[4][4];
#pragma unroll
  for (int i = 0; i < 4; i++)
#pragma unroll
    for (int j = 0; j < 4; j++) acc[i][j] = (f32x4){0.f, 0.f, 0.f, 0.f};

  char* ldsA0 = (char*)As + (size_t)(w * 64) * 16;
  char* ldsA1 = (char*)As + (size_t)(w * 64 + 256) * 16;
  char* ldsB0 = (char*)Bs + (size_t)(w * 64) * 16;
  char* ldsB1 = (char*)Bs + (size_t)(w * 64 + 256) * 16;

  for (int k0 = 0; k0 < KD; k0 += 32) {
    gload_lds16(A + (size_t)(m0 + row1) * KD + k0 + seg * 8, ldsA0);
    gload_lds16(A + (size_t)(m0 + row2) * KD + k0 + seg * 8, ldsA1);
    gload_lds16(B + (size_t)(n0 + row1) * KD + k0 + seg * 8, ldsB0);
    gload_lds16(B + (size_t)(n0 + row2) * KD + k0 + seg * 8, ldsB1);
    __syncthreads();
    bf16x8 af[4], bfv[4];
#pragma unroll
    for (int fi = 0; fi < 4; fi++)
      af[fi] = *(const bf16x8*)(As + (wr + fi * 16 + lr) * 32 + lk);
#pragma unroll
    for (int fj = 0; fj < 4; fj++)
      bfv[fj] = *(const bf16x8*)(Bs + (wc + fj * 16 + lr) * 32 + lk);
#pragma unroll
    for (int fi = 0; fi < 4; fi++)
#pragma unroll
      for (int fj = 0; fj < 4; fj++)
        acc[fi][fj] = __builtin_amdgcn_mfma_f32_16x16x32_bf16(af[fi], bfv[fj], acc[fi][fj], 0, 0, 0);
    __syncthreads();
  }

  mfma_guard();

#pragma unroll
  for (int fi = 0; fi < 4; fi++) {
    const int mbase = m0 + wr + fi * 16 + (l >> 4) * 4;
#pragma unroll
    for (int fj = 0; fj < 4; fj++) {
      const int n = n0 + wc + fj * 16 + lr;
      if (EPI == 1) {
        const float bb = bo[n];
#pragma unroll
        for (int r = 0; r < 4; r++)
          outf[(size_t)(mbase + r) * DM + n] = acc[fi][fj][r] + bb;
      } else if (n < DM) {                       // Q (scaled by 1/8) -> f16
        const int hh = n >> 6, dk = n & 63;
        const float bb = bq[n];
#pragma unroll
        for (int r = 0; r < 4; r++)
          qb[((size_t)hh * SEQ + mbase + r) * HD + dk] = f2h((acc[fi][fj][r] + bb) * 0.125f);
      } else if (n < 2 * DM) {                   // K row-major [h][s][dk] -> f16
        const int n2 = n - DM, hh = n2 >> 6, dk = n2 & 63;
        const float bb = bk[n2];
#pragma unroll
        for (int r = 0; r < 4; r++)
          kb[((size_t)hh * SEQ + mbase + r) * HD + dk] = f2h(acc[fi][fj][r] + bb);
      } else {                                   // V -> transposed [h][dk][s] f16
        const int n3 = n - 2 * DM, hh = n3 >> 6, dk = n3 & 63;
        const float bb = bv[n3];
        ushort4 ov = make_ushort4(f2h(acc[fi][fj][0] + bb), f2h(acc[fi][fj][1] + bb),
                                  f2h(acc[fi][fj][2] + bb), f2h(acc[fi][fj][3] + bb));
        *(ushort4*)(vt + ((size_t)hh * HD + dk) * SEQ + mbase) = ov;
      }
    }
  }
}

// ------ MFMA band attention, 128 queries/block (8 waves) + merged global row --
// grid (SEQ/128 + 1, NH), 512 threads. blockIdx.x < 32: band blocks.
// blockIdx.x == 32: global row for query 0 (concurrent; overwrites ctx row 0).
// Halves chunk-iterations vs R23 (the per-chunk stage+drain stall dominates).
// LDS = 16K (Ks) + 16K (Vts) + 16K (plds) = 49152 B -> 3 blocks/CU, 24 waves.
__global__ __launch_bounds__(512, 1)
void attn_fused(const unsigned short* __restrict__ qb,
                const unsigned short* __restrict__ kb,
                const unsigned short* __restrict__ vt,
                unsigned short* __restrict__ ctx)
{
  __shared__ __align__(16) unsigned short Ks[2][64 * 64];
  __shared__ __align__(16) unsigned short Vts[2][64 * 64];
  __shared__ __align__(16) unsigned short plds[8][16 * 64];
  const int h = blockIdx.y;
  const int t = threadIdx.x;
  const unsigned short* Qh  = qb + (size_t)h * SEQ * HD;
  const unsigned short* Kh  = kb + (size_t)h * SEQ * HD;
  const unsigned short* Vth = vt + (size_t)h * HD * SEQ;

  if (blockIdx.x == (SEQ / 128)) {
    // ============== global row path (query 0, all keys; 512 threads) =========
    float* sc   = (float*)&Ks[0][0];          // 16 KB = 4096 f32 (spans Ks[0..1])
    float* q0   = (float*)&plds[0][0];        // 64 f32
    float* red  = q0 + 64;                    // 8 f32
    float* accl = red + 8;                    // 8*64 f32
    if (t < HD) q0[t] = h2f(Qh[t]);           // pre-scaled by 1/8
    __syncthreads();

    for (int j = t; j < SEQ; j += 512) {
      const unsigned short* Kp = Kh + (size_t)j * HD;
      float a0 = 0.f, a1 = 0.f;
      for (int d0 = 0; d0 < 8; d0++) {
        const bf16x8 kv = *(const bf16x8*)(Kp + d0 * 8);
#pragma unroll
        for (int e = 0; e < 8; e += 2) {
          a0 += q0[d0 * 8 + e]     * h2f((unsigned short)kv[e]);
          a1 += q0[d0 * 8 + e + 1] * h2f((unsigned short)kv[e + 1]);
        }
      }
      sc[j] = a0 + a1;
    }
    __syncthreads();

    float mx = -1e30f;
    for (int j = t; j < SEQ; j += 512) mx = fmaxf(mx, sc[j]);
    for (int d = 1; d < 64; d <<= 1) mx = fmaxf(mx, __shfl_xor(mx, d));
    if ((t & 63) == 0) red[t >> 6] = mx;
    __syncthreads();
    mx = red[0];
#pragma unroll
    for (int i = 1; i < 8; i++) mx = fmaxf(mx, red[i]);
    __syncthreads();

    float sum = 0.f;
    for (int j = t; j < SEQ; j += 512) {
      const float p = __expf(sc[j] - mx);
      sc[j] = p;
      sum += p;
    }
    for (int d = 1; d < 64; d <<= 1) sum += __shfl_xor(sum, d);
    __syncthreads();
    if ((t & 63) == 0) red[t >> 6] = sum;
    __syncthreads();
    float tot = red[0];
#pragma unroll
    for (int i = 1; i < 8; i++) tot += red[i];
    const float inv = 1.f / tot;

    const int dd = t & 63, part = t >> 6;     // part 0..7, each covers 512 j
    const unsigned short* Vp = Vth + (size_t)dd * SEQ;
    float a0 = 0.f, a1 = 0.f, a2 = 0.f, a3 = 0.f;
    const int jb = part * 512;
    for (int j = 0; j < 512; j += 4) {
      a0 += sc[jb + j + 0] * h2f(Vp[jb + j + 0]);
      a1 += sc[jb + j + 1] * h2f(Vp[jb + j + 1]);
      a2 += sc[jb + j + 2] * h2f(Vp[jb + j + 2]);
      a3 += sc[jb + j + 3] * h2f(Vp[jb + j + 3]);
    }
    accl[part * 64 + dd] = (a0 + a1) + (a2 + a3);
    __syncthreads();
    if (part == 0) {
      float v = 0.f;
#pragma unroll
      for (int i = 0; i < 8; i++) v += accl[i * 64 + dd];
      ctx[(size_t)h * HD + dd] = f2b(v * inv);   // row 0
    }
    return;
  }

  // ================= band path (128 queries, 8 waves) =======================
  const int i0 = blockIdx.x * 128;
  const int w  = t >> 6, l = t & 63;
  const int lr = l & 15;
  const int cb = (l >> 4);
  const int qi0 = i0 + w * 16 + (l >> 4) * 4;

  const int srow = t >> 3;                  // 0..63 (512 threads cover all rows)
  const int scol = (t & 7) ^ (srow & 7);    // pre-swizzled source 16B-slot

  // Q fragments: loop-invariant, loaded DIRECTLY from global (one row, 2x16B)
  const int qrow = i0 + w * 16 + lr;
  const f16x8 qa0 = __builtin_bit_cast(f16x8,
      *(const bf16x8*)(Qh + (size_t)qrow * HD + cb * 8));
  const f16x8 qa1 = __builtin_bit_cast(f16x8,
      *(const bf16x8*)(Qh + (size_t)qrow * HD + (cb + 4) * 8));

  int lo = i0 - 256; if (lo < 0) lo = 0;
  int hi = i0 + 127 + 257; if (hi > SEQ) hi = SEQ;
  const int cbeg = lo >> 6, cend = (hi - 1) >> 6;
  const int pre  = (cbeg > 0) ? 1 : 0;
  const int nch  = cend - cbeg + 1 + pre;

  auto chunkof = [&](int it) -> int {
    return (pre && it == 0) ? 0 : (cbeg + it - pre);
  };
  auto stage = [&](int bsel, int cch) {
    const int jj0 = cch * 64;
    gload_lds16(Kh + (size_t)(jj0 + srow) * HD + scol * 8,
                (char*)(&Ks[bsel][0]) + t * 16);
    gload_lds16(Vth + (size_t)srow * SEQ + jj0 + scol * 8,
                (char*)(&Vts[bsel][0]) + t * 16);
  };
  auto frag = [&](const unsigned short* base, int rr, int cc) -> f16x8 {
    return __builtin_bit_cast(f16x8,
        *(const bf16x8*)(base + rr * 64 + ((cc ^ (rr & 7)) * 8)));
  };

  stage(0, chunkof(0));
  __syncthreads();

  f32x4 o[4];
#pragma unroll
  for (int i = 0; i < 4; i++) o[i] = (f32x4){0.f, 0.f, 0.f, 0.f};
  float mrow[4] = {-1e30f, -1e30f, -1e30f, -1e30f};
  float ls[4]   = {0.f, 0.f, 0.f, 0.f};
  unsigned short* P = &plds[w][0];

  for (int it = 0; it < nch; ++it) {
    if (it + 1 < nch) stage((it + 1) & 1, chunkof(it + 1));

    const int c  = chunkof(it);
    const int j0 = c * 64;
    const unsigned short* Kc = &Ks[it & 1][0];
    const unsigned short* Vc = &Vts[it & 1][0];

    f32x4 sc[4];
#pragma unroll
    for (int i = 0; i < 4; i++) sc[i] = (f32x4){0.f, 0.f, 0.f, 0.f};
#pragma unroll
    for (int fj = 0; fj < 4; fj++) {
      const f16x8 kf0 = frag(Kc, fj * 16 + lr, cb);
      const f16x8 kf1 = frag(Kc, fj * 16 + lr, cb + 4);
      sc[fj] = __builtin_amdgcn_mfma_f32_16x16x32_f16(qa0, kf0, sc[fj], 0, 0, 0);
      sc[fj] = __builtin_amdgcn_mfma_f32_16x16x32_f16(qa1, kf1, sc[fj], 0, 0, 0);
    }
    mfma_guard();

    bool exceed = false;
#pragma unroll
    for (int r = 0; r < 4; r++) {
      const int qi = qi0 + r;
#pragma unroll
      for (int fj = 0; fj < 4; fj++) {
        const int j = j0 + fj * 16 + lr;
        const bool valid = (j == 0) || ((j - qi) <= 256 && (qi - j) <= 256);
        const float v = valid ? sc[fj][r] : -1e30f;
        sc[fj][r] = v;
        exceed |= (v > mrow[r] + 8.f);
      }
    }
    if (__any(exceed)) {
#pragma unroll
      for (int r = 0; r < 4; r++) {
        float mx = fmaxf(fmaxf(sc[0][r], sc[1][r]), fmaxf(sc[2][r], sc[3][r]));
        for (int d = 1; d < 16; d <<= 1) mx = fmaxf(mx, __shfl_xor(mx, d));
        const float mnew  = fmaxf(mrow[r], mx);
        const float scale = __expf(mrow[r] - mnew);
        mrow[r] = mnew;
        ls[r] *= scale;
#pragma unroll
        for (int fn = 0; fn < 4; fn++) o[fn][r] *= scale;
      }
    }
#pragma unroll
    for (int r = 0; r < 4; r++) {
      float psum = 0.f;
#pragma unroll
      for (int fj = 0; fj < 4; fj++) {
        const float p = __expf(sc[fj][r] - mrow[r]);
        sc[fj][r] = p;
        psum += p;
      }
      ls[r] += psum;
    }

    // ---- P (C-layout, f16) -> wave-private LDS, XOR-block swizzled (R23)
#pragma unroll
    for (int fj = 0; fj < 4; fj++)
#pragma unroll
      for (int r = 0; r < 4; r++) {
        const int prow = (l >> 4) * 4 + r;
        const int e    = fj * 16 + lr;
        P[prow * 64 + (((e >> 3) ^ (prow & 7)) * 8) + (e & 7)] = f2h(sc[fj][r]);
      }

    const f16x8 pf0 = frag(P, lr, cb);
    const f16x8 pf1 = frag(P, lr, cb + 4);
#pragma unroll
    for (int fn = 0; fn < 4; fn++) {
      const f16x8 vf0 = frag(Vc, fn * 16 + lr, cb);
      const f16x8 vf1 = frag(Vc, fn * 16 + lr, cb + 4);
      o[fn] = __builtin_amdgcn_mfma_f32_16x16x32_f16(pf0, vf0, o[fn], 0, 0, 0);
      o[fn] = __builtin_amdgcn_mfma_f32_16x16x32_f16(pf1, vf1, o[fn], 0, 0, 0);
    }
    __syncthreads();   // prefetch landed + all waves done with buf[it&1]
  }

  mfma_guard();

#pragma unroll
  for (int r = 0; r < 4; r++)
    for (int d = 1; d < 16; d <<= 1) ls[r] += __shfl_xor(ls[r], d);

#pragma unroll
  for (int fn = 0; fn < 4; fn++)
#pragma unroll
    for (int r = 0; r < 4; r++) {
      const int s = qi0 + r;
      const float val = o[fn][r] / ls[r];
      ctx[(size_t)s * DM + h * HD + fn * 16 + lr] = f2b(val);
    }
}

// ---------------- launch ----------------
extern "C" void kernel_launch(void* const* d_in, const int* in_sizes, int n_in,
                              void* d_out, int out_size, void* d_ws, size_t ws_size,
                              hipStream_t stream)
{
  (void)in_sizes; (void)n_in; (void)out_size; (void)ws_size;
  const float* x  = (const float*)d_in[0];
  const float* Wq = (const float*)d_in[1];
  const float* bq = (const float*)d_in[2];
  const float* Wk = (const float*)d_in[3];
  const float* bk = (const float*)d_in[4];
  const float* Wv = (const float*)d_in[5];
  const float* bv = (const float*)d_in[6];
  const float* Wo = (const float*)d_in[7];
  const float* bo = (const float*)d_in[8];
  float* out = (float*)d_out;

  char* ws = (char*)d_ws;
  unsigned short* xb   = (unsigned short*)(ws + 0);         // dead after gemm<0>
  unsigned short* wqkv = (unsigned short*)(ws + 6291456);
  unsigned short* wob  = (unsigned short*)(ws + 9830400);
  unsigned short* qbuf = (unsigned short*)(ws + 11010048);  // [12][4096][64] f16
  unsigned short* kbuf = (unsigned short*)(ws + 17301504);  // [12][4096][64] f16
  unsigned short* vtb  = (unsigned short*)(ws + 23592960);  // [12][64][4096] f16
  unsigned short* ctx  = (unsigned short*)(ws + 0);         // bf16, aliases xb

  convert_all<<<dim3(1024), dim3(256), 0, stream>>>(x, Wq, Wk, Wv, Wo, xb, wqkv, wob);
  gemm_bt<0><<<dim3(18, 32), dim3(256), 0, stream>>>(xb, wqkv, qbuf, kbuf, vtb,
                                                     bq, bk, bv, nullptr, nullptr);
  attn_fused<<<dim3(SEQ / 128 + 1, NH), dim3(512), 0, stream>>>(qbuf, kbuf, vtb, ctx);
  gemm_bt<1><<<dim3(6, 32), dim3(256), 0, stream>>>(ctx, wob, nullptr, nullptr, nullptr,
                                                    nullptr, nullptr, nullptr, bo, out);
}

// Round 25
// 93.545 us; speedup vs baseline: 102.7253x; 1.0347x over previous
//
#include <hip/hip_runtime.h>
#include <cstdint>

#define SEQ   4096
#define DM    768
#define NH    12
#define HD    64
#define KD    768

typedef float  f32x4  __attribute__((ext_vector_type(4)));
typedef short  bf16x8 __attribute__((ext_vector_type(8)));
typedef _Float16 f16x8 __attribute__((ext_vector_type(8)));
typedef unsigned int u32;

typedef __attribute__((address_space(1))) const unsigned int gu32;
typedef __attribute__((address_space(3))) unsigned int lu32;

__device__ __forceinline__ unsigned short f2b(float f) {
  unsigned int u = __builtin_bit_cast(unsigned int, f);
  u += 0x7fffu + ((u >> 16) & 1u);
  return (unsigned short)(u >> 16);
}
__device__ __forceinline__ float b2f(unsigned short s) {
  return __builtin_bit_cast(float, ((unsigned int)s) << 16);
}
__device__ __forceinline__ unsigned short f2h(float f) {
  _Float16 h = (_Float16)f;
  return __builtin_bit_cast(unsigned short, h);
}
__device__ __forceinline__ float h2f(unsigned short s) {
  return (float)__builtin_bit_cast(_Float16, s);
}

__device__ __forceinline__ void gload_lds16(const void* g, void* l) {
  gu32* gp = reinterpret_cast<gu32*>(reinterpret_cast<uintptr_t>(g));
  lu32* lp = reinterpret_cast<lu32*>(reinterpret_cast<uintptr_t>(l));
  __builtin_amdgcn_global_load_lds(gp, lp, 16, 0, 0);
}

// Real-time guard between MFMA acc writes and first VALU/DPP consumer
// (R20-verified: gfx950 needs genuine delay, not register-copy fences).
__device__ __forceinline__ void mfma_guard() {
  __builtin_amdgcn_sched_barrier(0);
  asm volatile("s_nop 7\n\ts_nop 7\n\ts_nop 7\n\ts_nop 7");
  __builtin_amdgcn_sched_barrier(0);
}

// ---------------- pack/convert: f32 -> bf16 (R3-verified) ----------------
__global__ void convert_all(const float* __restrict__ x,
                            const float* __restrict__ wq,
                            const float* __restrict__ wk,
                            const float* __restrict__ wv,
                            const float* __restrict__ wo,
                            unsigned short* __restrict__ xb,
                            unsigned short* __restrict__ wqkv,
                            unsigned short* __restrict__ wob)
{
  const int XN = SEQ * DM;
  const int WN = DM * DM;
  const int total4 = (XN + 4 * WN) >> 2;
  for (int i = blockIdx.x * blockDim.x + threadIdx.x; i < total4;
       i += gridDim.x * blockDim.x) {
    const int base = i << 2;
    const float* src;
    unsigned short* dst;
    if (base < XN)                 { src = x  + base;               dst = xb   + base; }
    else if (base < XN + WN)       { src = wq + (base - XN);        dst = wqkv + (base - XN); }
    else if (base < XN + 2 * WN)   { src = wk + (base - XN - WN);   dst = wqkv + (base - XN); }
    else if (base < XN + 3 * WN)   { src = wv + (base - XN - 2*WN); dst = wqkv + (base - XN); }
    else                           { src = wo + (base - XN - 3*WN); dst = wob  + (base - XN - 3*WN); }
    const float4 v = *(const float4*)src;
    *(ushort4*)dst = make_ushort4(f2b(v.x), f2b(v.y), f2b(v.z), f2b(v.w));
  }
}

// ---------------- GEMM C = A[M,K] * B[N,K]^T (R3-verified, bf16 MFMA) --------
// EPI 0: Q/K row-major f16; V written TRANSPOSED [h][dk][s] f16 (R2≡R4 verified)
// XCD-aware block swizzle (T1, bijective: nwg % 8 == 0 for both grids).
template<int EPI>
__global__ __launch_bounds__(256, 2)
void gemm_bt(const unsigned short* __restrict__ A,
             const unsigned short* __restrict__ B,
             unsigned short* __restrict__ qb,
             unsigned short* __restrict__ kb,
             unsigned short* __restrict__ vt,
             const float* __restrict__ bq,
             const float* __restrict__ bk,
             const float* __restrict__ bv,
             const float* __restrict__ bo,
             float* __restrict__ outf)
{
  __shared__ __align__(16) unsigned short As[128 * 32];
  __shared__ __align__(16) unsigned short Bs[128 * 32];
  const int t  = threadIdx.x;
  const int w  = t >> 6;
  const int l  = t & 63;

  // XCD swizzle: contiguous work chunks per XCD (round-robin dispatch)
  const int nwg  = gridDim.x * gridDim.y;
  const int flat = blockIdx.y * gridDim.x + blockIdx.x;
  const int cpx  = nwg >> 3;
  const int wid  = (flat & 7) * cpx + (flat >> 3);
  const int m0 = (wid / gridDim.x) * 128;
  const int n0 = (wid % gridDim.x) * 128;

  const int wr = (w >> 1) * 64;
  const int wc = (w & 1) * 64;
  const int lr = l & 15;
  const int lk = (l >> 4) * 8;

  const int row1 = t >> 2;
  const int row2 = row1 + 64;
  const int seg  = t & 3;

  f32x4 acc[4][4];
#pragma unroll
  for (int i = 0; i < 4; i++)
#pragma unroll
    for (int j = 0; j < 4; j++) acc[i][j] = (f32x4){0.f, 0.f, 0.f, 0.f};

  char* ldsA0 = (char*)As + (size_t)(w * 64) * 16;
  char* ldsA1 = (char*)As + (size_t)(w * 64 + 256) * 16;
  char* ldsB0 = (char*)Bs + (size_t)(w * 64) * 16;
  char* ldsB1 = (char*)Bs + (size_t)(w * 64 + 256) * 16;

  for (int k0 = 0; k0 < KD; k0 += 32) {
    gload_lds16(A + (size_t)(m0 + row1) * KD + k0 + seg * 8, ldsA0);
    gload_lds16(A + (size_t)(m0 + row2) * KD + k0 + seg * 8, ldsA1);
    gload_lds16(B + (size_t)(n0 + row1) * KD + k0 + seg * 8, ldsB0);
    gload_lds16(B + (size_t)(n0 + row2) * KD + k0 + seg * 8, ldsB1);
    __syncthreads();
    bf16x8 af[4], bfv[4];
#pragma unroll
    for (int fi = 0; fi < 4; fi++)
      af[fi] = *(const bf16x8*)(As + (wr + fi * 16 + lr) * 32 + lk);
#pragma unroll
    for (int fj = 0; fj < 4; fj++)
      bfv[fj] = *(const bf16x8*)(Bs + (wc + fj * 16 + lr) * 32 + lk);
#pragma unroll
    for (int fi = 0; fi < 4; fi++)
#pragma unroll
      for (int fj = 0; fj < 4; fj++)
        acc[fi][fj] = __builtin_amdgcn_mfma_f32_16x16x32_bf16(af[fi], bfv[fj], acc[fi][fj], 0, 0, 0);
    __syncthreads();
  }

  mfma_guard();

#pragma unroll
  for (int fi = 0; fi < 4; fi++) {
    const int mbase = m0 + wr + fi * 16 + (l >> 4) * 4;
#pragma unroll
    for (int fj = 0; fj < 4; fj++) {
      const int n = n0 + wc + fj * 16 + lr;
      if (EPI == 1) {
        const float bb = bo[n];
#pragma unroll
        for (int r = 0; r < 4; r++)
          outf[(size_t)(mbase + r) * DM + n] = acc[fi][fj][r] + bb;
      } else if (n < DM) {                       // Q (scaled by 1/8) -> f16
        const int hh = n >> 6, dk = n & 63;
        const float bb = bq[n];
#pragma unroll
        for (int r = 0; r < 4; r++)
          qb[((size_t)hh * SEQ + mbase + r) * HD + dk] = f2h((acc[fi][fj][r] + bb) * 0.125f);
      } else if (n < 2 * DM) {                   // K row-major [h][s][dk] -> f16
        const int n2 = n - DM, hh = n2 >> 6, dk = n2 & 63;
        const float bb = bk[n2];
#pragma unroll
        for (int r = 0; r < 4; r++)
          kb[((size_t)hh * SEQ + mbase + r) * HD + dk] = f2h(acc[fi][fj][r] + bb);
      } else {                                   // V -> transposed [h][dk][s] f16
        const int n3 = n - 2 * DM, hh = n3 >> 6, dk = n3 & 63;
        const float bb = bv[n3];
        ushort4 ov = make_ushort4(f2h(acc[fi][fj][0] + bb), f2h(acc[fi][fj][1] + bb),
                                  f2h(acc[fi][fj][2] + bb), f2h(acc[fi][fj][3] + bb));
        *(ushort4*)(vt + ((size_t)hh * HD + dk) * SEQ + mbase) = ov;
      }
    }
  }
}

// ------ MFMA band attention, 256 queries/block (16 waves) + merged global row -
// grid (SEQ/256 + 1, NH), 1024 threads. blockIdx.x < 16: band blocks.
// blockIdx.x == 16: global row for query 0 (concurrent; overwrites ctx row 0).
// Staging: threads 0-511 stage K (1 gload each), 512-1023 stage V.
// LDS = 16K (Ks) + 16K (Vts) + 32K (plds) = 65536 B -> 2 blocks/CU, 32 waves.
__global__ __launch_bounds__(1024, 1)
void attn_fused(const unsigned short* __restrict__ qb,
                const unsigned short* __restrict__ kb,
                const unsigned short* __restrict__ vt,
                unsigned short* __restrict__ ctx)
{
  __shared__ __align__(16) unsigned short Ks[2][64 * 64];
  __shared__ __align__(16) unsigned short Vts[2][64 * 64];
  __shared__ __align__(16) unsigned short plds[16][16 * 64];
  const int h = blockIdx.y;
  const int t = threadIdx.x;
  const unsigned short* Qh  = qb + (size_t)h * SEQ * HD;
  const unsigned short* Kh  = kb + (size_t)h * SEQ * HD;
  const unsigned short* Vth = vt + (size_t)h * HD * SEQ;

  if (blockIdx.x == (SEQ / 256)) {
    // ============== global row path (query 0, all keys; 1024 threads) ========
    float* sc   = (float*)&Ks[0][0];          // 16 KB = 4096 f32 (spans Ks[0..1])
    float* q0   = (float*)&plds[0][0];        // 64 f32
    float* red  = q0 + 64;                    // 16 f32
    float* accl = red + 16;                   // 16*64 f32
    if (t < HD) q0[t] = h2f(Qh[t]);           // pre-scaled by 1/8
    __syncthreads();

    for (int j = t; j < SEQ; j += 1024) {
      const unsigned short* Kp = Kh + (size_t)j * HD;
      float a0 = 0.f, a1 = 0.f;
      for (int d0 = 0; d0 < 8; d0++) {
        const bf16x8 kv = *(const bf16x8*)(Kp + d0 * 8);
#pragma unroll
        for (int e = 0; e < 8; e += 2) {
          a0 += q0[d0 * 8 + e]     * h2f((unsigned short)kv[e]);
          a1 += q0[d0 * 8 + e + 1] * h2f((unsigned short)kv[e + 1]);
        }
      }
      sc[j] = a0 + a1;
    }
    __syncthreads();

    float mx = -1e30f;
    for (int j = t; j < SEQ; j += 1024) mx = fmaxf(mx, sc[j]);
    for (int d = 1; d < 64; d <<= 1) mx = fmaxf(mx, __shfl_xor(mx, d));
    if ((t & 63) == 0) red[t >> 6] = mx;
    __syncthreads();
    mx = red[0];
#pragma unroll
    for (int i = 1; i < 16; i++) mx = fmaxf(mx, red[i]);
    __syncthreads();

    float sum = 0.f;
    for (int j = t; j < SEQ; j += 1024) {
      const float p = __expf(sc[j] - mx);
      sc[j] = p;
      sum += p;
    }
    for (int d = 1; d < 64; d <<= 1) sum += __shfl_xor(sum, d);
    __syncthreads();
    if ((t & 63) == 0) red[t >> 6] = sum;
    __syncthreads();
    float tot = red[0];
#pragma unroll
    for (int i = 1; i < 16; i++) tot += red[i];
    const float inv = 1.f / tot;

    const int dd = t & 63, part = t >> 6;     // part 0..15, each covers 256 j
    const unsigned short* Vp = Vth + (size_t)dd * SEQ;
    float a0 = 0.f, a1 = 0.f, a2 = 0.f, a3 = 0.f;
    const int jb = part * 256;
    for (int j = 0; j < 256; j += 4) {
      a0 += sc[jb + j + 0] * h2f(Vp[jb + j + 0]);
      a1 += sc[jb + j + 1] * h2f(Vp[jb + j + 1]);
      a2 += sc[jb + j + 2] * h2f(Vp[jb + j + 2]);
      a3 += sc[jb + j + 3] * h2f(Vp[jb + j + 3]);
    }
    accl[part * 64 + dd] = (a0 + a1) + (a2 + a3);
    __syncthreads();
    if (part == 0) {
      float v = 0.f;
#pragma unroll
      for (int i = 0; i < 16; i++) v += accl[i * 64 + dd];
      ctx[(size_t)h * HD + dd] = f2b(v * inv);   // row 0
    }
    return;
  }

  // ================= band path (256 queries, 16 waves) ======================
  const int i0 = blockIdx.x * 256;
  const int w  = t >> 6, l = t & 63;
  const int lr = l & 15;
  const int cb = (l >> 4);
  const int qi0 = i0 + w * 16 + (l >> 4) * 4;

  // staging: threads 0-511 cover K rows 0..63 (slot t&7), 512-1023 cover V
  const int sti  = t & 511;
  const int srow = sti >> 3;                 // 0..63
  const int scol = (sti & 7) ^ (srow & 7);   // pre-swizzled source 16B-slot
  const bool doK = (t < 512);

  // Q fragments: loop-invariant, loaded DIRECTLY from global (one row, 2x16B)
  const int qrow = i0 + w * 16 + lr;
  const f16x8 qa0 = __builtin_bit_cast(f16x8,
      *(const bf16x8*)(Qh + (size_t)qrow * HD + cb * 8));
  const f16x8 qa1 = __builtin_bit_cast(f16x8,
      *(const bf16x8*)(Qh + (size_t)qrow * HD + (cb + 4) * 8));

  int lo = i0 - 256; if (lo < 0) lo = 0;
  int hi = i0 + 255 + 257; if (hi > SEQ) hi = SEQ;
  const int cbeg = lo >> 6, cend = (hi - 1) >> 6;
  const int pre  = (cbeg > 0) ? 1 : 0;
  const int nch  = cend - cbeg + 1 + pre;

  auto chunkof = [&](int it) -> int {
    return (pre && it == 0) ? 0 : (cbeg + it - pre);
  };
  auto stage = [&](int bsel, int cch) {
    const int jj0 = cch * 64;
    if (doK) {
      gload_lds16(Kh + (size_t)(jj0 + srow) * HD + scol * 8,
                  (char*)(&Ks[bsel][0]) + sti * 16);
    } else {
      gload_lds16(Vth + (size_t)srow * SEQ + jj0 + scol * 8,
                  (char*)(&Vts[bsel][0]) + sti * 16);
    }
  };
  auto frag = [&](const unsigned short* base, int rr, int cc) -> f16x8 {
    return __builtin_bit_cast(f16x8,
        *(const bf16x8*)(base + rr * 64 + ((cc ^ (rr & 7)) * 8)));
  };

  stage(0, chunkof(0));
  __syncthreads();

  f32x4 o[4];
#pragma unroll
  for (int i = 0; i < 4; i++) o[i] = (f32x4){0.f, 0.f, 0.f, 0.f};
  float mrow[4] = {-1e30f, -1e30f, -1e30f, -1e30f};
  float ls[4]   = {0.f, 0.f, 0.f, 0.f};
  unsigned short* P = &plds[w][0];

  for (int it = 0; it < nch; ++it) {
    if (it + 1 < nch) stage((it + 1) & 1, chunkof(it + 1));

    const int c  = chunkof(it);
    const int j0 = c * 64;
    const unsigned short* Kc = &Ks[it & 1][0];
    const unsigned short* Vc = &Vts[it & 1][0];

    f32x4 sc[4];
#pragma unroll
    for (int i = 0; i < 4; i++) sc[i] = (f32x4){0.f, 0.f, 0.f, 0.f};
#pragma unroll
    for (int fj = 0; fj < 4; fj++) {
      const f16x8 kf0 = frag(Kc, fj * 16 + lr, cb);
      const f16x8 kf1 = frag(Kc, fj * 16 + lr, cb + 4);
      sc[fj] = __builtin_amdgcn_mfma_f32_16x16x32_f16(qa0, kf0, sc[fj], 0, 0, 0);
      sc[fj] = __builtin_amdgcn_mfma_f32_16x16x32_f16(qa1, kf1, sc[fj], 0, 0, 0);
    }
    mfma_guard();

    bool exceed = false;
#pragma unroll
    for (int r = 0; r < 4; r++) {
      const int qi = qi0 + r;
#pragma unroll
      for (int fj = 0; fj < 4; fj++) {
        const int j = j0 + fj * 16 + lr;
        const bool valid = (j == 0) || ((j - qi) <= 256 && (qi - j) <= 256);
        const float v = valid ? sc[fj][r] : -1e30f;
        sc[fj][r] = v;
        exceed |= (v > mrow[r] + 8.f);
      }
    }
    if (__any(exceed)) {
#pragma unroll
      for (int r = 0; r < 4; r++) {
        float mx = fmaxf(fmaxf(sc[0][r], sc[1][r]), fmaxf(sc[2][r], sc[3][r]));
        for (int d = 1; d < 16; d <<= 1) mx = fmaxf(mx, __shfl_xor(mx, d));
        const float mnew  = fmaxf(mrow[r], mx);
        const float scale = __expf(mrow[r] - mnew);
        mrow[r] = mnew;
        ls[r] *= scale;
#pragma unroll
        for (int fn = 0; fn < 4; fn++) o[fn][r] *= scale;
      }
    }
#pragma unroll
    for (int r = 0; r < 4; r++) {
      float psum = 0.f;
#pragma unroll
      for (int fj = 0; fj < 4; fj++) {
        const float p = __expf(sc[fj][r] - mrow[r]);
        sc[fj][r] = p;
        psum += p;
      }
      ls[r] += psum;
    }

    // ---- P (C-layout, f16) -> wave-private LDS, XOR-block swizzled (R23)
#pragma unroll
    for (int fj = 0; fj < 4; fj++)
#pragma unroll
      for (int r = 0; r < 4; r++) {
        const int prow = (l >> 4) * 4 + r;
        const int e    = fj * 16 + lr;
        P[prow * 64 + (((e >> 3) ^ (prow & 7)) * 8) + (e & 7)] = f2h(sc[fj][r]);
      }

    const f16x8 pf0 = frag(P, lr, cb);
    const f16x8 pf1 = frag(P, lr, cb + 4);
#pragma unroll
    for (int fn = 0; fn < 4; fn++) {
      const f16x8 vf0 = frag(Vc, fn * 16 + lr, cb);
      const f16x8 vf1 = frag(Vc, fn * 16 + lr, cb + 4);
      o[fn] = __builtin_amdgcn_mfma_f32_16x16x32_f16(pf0, vf0, o[fn], 0, 0, 0);
      o[fn] = __builtin_amdgcn_mfma_f32_16x16x32_f16(pf1, vf1, o[fn], 0, 0, 0);
    }
    __syncthreads();   // prefetch landed + all waves done with buf[it&1]
  }

  mfma_guard();

#pragma unroll
  for (int r = 0; r < 4; r++)
    for (int d = 1; d < 16; d <<= 1) ls[r] += __shfl_xor(ls[r], d);

#pragma unroll
  for (int fn = 0; fn < 4; fn++)
#pragma unroll
    for (int r = 0; r < 4; r++) {
      const int s = qi0 + r;
      const float val = o[fn][r] / ls[r];
      ctx[(size_t)s * DM + h * HD + fn * 16 + lr] = f2b(val);
    }
}

// ---------------- launch ----------------
extern "C" void kernel_launch(void* const* d_in, const int* in_sizes, int n_in,
                              void* d_out, int out_size, void* d_ws, size_t ws_size,
                              hipStream_t stream)
{
  (void)in_sizes; (void)n_in; (void)out_size; (void)ws_size;
  const float* x  = (const float*)d_in[0];
  const float* Wq = (const float*)d_in[1];
  const float* bq = (const float*)d_in[2];
  const float* Wk = (const float*)d_in[3];
  const float* bk = (const float*)d_in[4];
  const float* Wv = (const float*)d_in[5];
  const float* bv = (const float*)d_in[6];
  const float* Wo = (const float*)d_in[7];
  const float* bo = (const float*)d_in[8];
  float* out = (float*)d_out;

  char* ws = (char*)d_ws;
  unsigned short* xb   = (unsigned short*)(ws + 0);         // dead after gemm<0>
  unsigned short* wqkv = (unsigned short*)(ws + 6291456);
  unsigned short* wob  = (unsigned short*)(ws + 9830400);
  unsigned short* qbuf = (unsigned short*)(ws + 11010048);  // [12][4096][64] f16
  unsigned short* kbuf = (unsigned short*)(ws + 17301504);  // [12][4096][64] f16
  unsigned short* vtb  = (unsigned short*)(ws + 23592960);  // [12][64][4096] f16
  unsigned short* ctx  = (unsigned short*)(ws + 0);         // bf16, aliases xb

  convert_all<<<dim3(1024), dim3(256), 0, stream>>>(x, Wq, Wk, Wv, Wo, xb, wqkv, wob);
  gemm_bt<0><<<dim3(18, 32), dim3(256), 0, stream>>>(xb, wqkv, qbuf, kbuf, vtb,
                                                     bq, bk, bv, nullptr, nullptr);
  attn_fused<<<dim3(SEQ / 256 + 1, NH), dim3(1024), 0, stream>>>(qbuf, kbuf, vtb, ctx);
  gemm_bt<1><<<dim3(6, 32), dim3(256), 0, stream>>>(ctx, wob, nullptr, nullptr, nullptr,
                                                    nullptr, nullptr, nullptr, bo, out);
}

// Round 28
// 91.618 us; speedup vs baseline: 104.8869x; 1.0210x over previous
//
#include <hip/hip_runtime.h>
#include <cstdint>

#define SEQ   4096
#define DM    768
#define NH    12
#define HD    64
#define KD    768

typedef float  f32x4  __attribute__((ext_vector_type(4)));
typedef short  bf16x8 __attribute__((ext_vector_type(8)));
typedef _Float16 f16x8 __attribute__((ext_vector_type(8)));
typedef unsigned int u32;

typedef __attribute__((address_space(1))) const unsigned int gu32;
typedef __attribute__((address_space(3))) unsigned int lu32;

__device__ __forceinline__ unsigned short f2b(float f) {
  unsigned int u = __builtin_bit_cast(unsigned int, f);
  u += 0x7fffu + ((u >> 16) & 1u);
  return (unsigned short)(u >> 16);
}
__device__ __forceinline__ float b2f(unsigned short s) {
  return __builtin_bit_cast(float, ((unsigned int)s) << 16);
}
__device__ __forceinline__ unsigned short f2h(float f) {
  _Float16 h = (_Float16)f;
  return __builtin_bit_cast(unsigned short, h);
}
__device__ __forceinline__ float h2f(unsigned short s) {
  return (float)__builtin_bit_cast(_Float16, s);
}

__device__ __forceinline__ void gload_lds16(const void* g, void* l) {
  gu32* gp = reinterpret_cast<gu32*>(reinterpret_cast<uintptr_t>(g));
  lu32* lp = reinterpret_cast<lu32*>(reinterpret_cast<uintptr_t>(l));
  __builtin_amdgcn_global_load_lds(gp, lp, 16, 0, 0);
}

// Real-time guard between MFMA acc writes and first VALU/DPP consumer
// (R20-verified: gfx950 needs genuine delay, not register-copy fences).
__device__ __forceinline__ void mfma_guard() {
  __builtin_amdgcn_sched_barrier(0);
  asm volatile("s_nop 7\n\ts_nop 7\n\ts_nop 7\n\ts_nop 7");
  __builtin_amdgcn_sched_barrier(0);
}

// ---------------- pack/convert: f32 -> bf16 (R3-verified) ----------------
__global__ void convert_all(const float* __restrict__ x,
                            const float* __restrict__ wq,
                            const float* __restrict__ wk,
                            const float* __restrict__ wv,
                            const float* __restrict__ wo,
                            unsigned short* __restrict__ xb,
                            unsigned short* __restrict__ wqkv,
                            unsigned short* __restrict__ wob)
{
  const int XN = SEQ * DM;
  const int WN = DM * DM;
  const int total4 = (XN + 4 * WN) >> 2;
  for (int i = blockIdx.x * blockDim.x + threadIdx.x; i < total4;
       i += gridDim.x * blockDim.x) {
    const int base = i << 2;
    const float* src;
    unsigned short* dst;
    if (base < XN)                 { src = x  + base;               dst = xb   + base; }
    else if (base < XN + WN)       { src = wq + (base - XN);        dst = wqkv + (base - XN); }
    else if (base < XN + 2 * WN)   { src = wk + (base - XN - WN);   dst = wqkv + (base - XN); }
    else if (base < XN + 3 * WN)   { src = wv + (base - XN - 2*WN); dst = wqkv + (base - XN); }
    else                           { src = wo + (base - XN - 3*WN); dst = wob  + (base - XN - 3*WN); }
    const float4 v = *(const float4*)src;
    *(ushort4*)dst = make_ushort4(f2b(v.x), f2b(v.y), f2b(v.z), f2b(v.w));
  }
}

// ---------------- GEMM C = A[M,K] * B[N,K]^T (R3-verified, bf16 MFMA) --------
// EPI 0: Q/K row-major f16; V written TRANSPOSED [h][dk][s] f16 (R2≡R4 verified)
// XCD-aware block swizzle (T1, bijective: nwg % 8 == 0 for both grids).
template<int EPI>
__global__ __launch_bounds__(256, 2)
void gemm_bt(const unsigned short* __restrict__ A,
             const unsigned short* __restrict__ B,
             unsigned short* __restrict__ qb,
             unsigned short* __restrict__ kb,
             unsigned short* __restrict__ vt,
             const float* __restrict__ bq,
             const float* __restrict__ bk,
             const float* __restrict__ bv,
             const float* __restrict__ bo,
             float* __restrict__ outf)
{
  __shared__ __align__(16) unsigned short As[128 * 32];
  __shared__ __align__(16) unsigned short Bs[128 * 32];
  const int t  = threadIdx.x;
  const int w  = t >> 6;
  const int l  = t & 63;

  // XCD swizzle: contiguous work chunks per XCD (round-robin dispatch)
  const int nwg  = gridDim.x * gridDim.y;
  const int flat = blockIdx.y * gridDim.x + blockIdx.x;
  const int cpx  = nwg >> 3;
  const int wid  = (flat & 7) * cpx + (flat >> 3);
  const int m0 = (wid / gridDim.x) * 128;
  const int n0 = (wid % gridDim.x) * 128;

  const int wr = (w >> 1) * 64;
  const int wc = (w & 1) * 64;
  const int lr = l & 15;
  const int lk = (l >> 4) * 8;

  const int row1 = t >> 2;
  const int row2 = row1 + 64;
  const int seg  = t & 3;

  f32x4 acc[4][4];
#pragma unroll
  for (int i = 0; i < 4; i++)
#pragma unroll
    for (int j = 0; j < 4; j++) acc[i][j] = (f32x4){0.f, 0.f, 0.f, 0.f};

  char* ldsA0 = (char*)As + (size_t)(w * 64) * 16;
  char* ldsA1 = (char*)As + (size_t)(w * 64 + 256) * 16;
  char* ldsB0 = (char*)Bs + (size_t)(w * 64) * 16;
  char* ldsB1 = (char*)Bs + (size_t)(w * 64 + 256) * 16;

  for (int k0 = 0; k0 < KD; k0 += 32) {
    gload_lds16(A + (size_t)(m0 + row1) * KD + k0 + seg * 8, ldsA0);
    gload_lds16(A + (size_t)(m0 + row2) * KD + k0 + seg * 8, ldsA1);
    gload_lds16(B + (size_t)(n0 + row1) * KD + k0 + seg * 8, ldsB0);
    gload_lds16(B + (size_t)(n0 + row2) * KD + k0 + seg * 8, ldsB1);
    __syncthreads();
    bf16x8 af[4], bfv[4];
#pragma unroll
    for (int fi = 0; fi < 4; fi++)
      af[fi] = *(const bf16x8*)(As + (wr + fi * 16 + lr) * 32 + lk);
#pragma unroll
    for (int fj = 0; fj < 4; fj++)
      bfv[fj] = *(const bf16x8*)(Bs + (wc + fj * 16 + lr) * 32 + lk);
#pragma unroll
    for (int fi = 0; fi < 4; fi++)
#pragma unroll
      for (int fj = 0; fj < 4; fj++)
        acc[fi][fj] = __builtin_amdgcn_mfma_f32_16x16x32_bf16(af[fi], bfv[fj], acc[fi][fj], 0, 0, 0);
    __syncthreads();
  }

  mfma_guard();

#pragma unroll
  for (int fi = 0; fi < 4; fi++) {
    const int mbase = m0 + wr + fi * 16 + (l >> 4) * 4;
#pragma unroll
    for (int fj = 0; fj < 4; fj++) {
      const int n = n0 + wc + fj * 16 + lr;
      if (EPI == 1) {
        const float bb = bo[n];
#pragma unroll
        for (int r = 0; r < 4; r++)
          outf[(size_t)(mbase + r) * DM + n] = acc[fi][fj][r] + bb;
      } else if (n < DM) {                       // Q (scaled by 1/8) -> f16
        const int hh = n >> 6, dk = n & 63;
        const float bb = bq[n];
#pragma unroll
        for (int r = 0; r < 4; r++)
          qb[((size_t)hh * SEQ + mbase + r) * HD + dk] = f2h((acc[fi][fj][r] + bb) * 0.125f);
      } else if (n < 2 * DM) {                   // K row-major [h][s][dk] -> f16
        const int n2 = n - DM, hh = n2 >> 6, dk = n2 & 63;
        const float bb = bk[n2];
#pragma unroll
        for (int r = 0; r < 4; r++)
          kb[((size_t)hh * SEQ + mbase + r) * HD + dk] = f2h(acc[fi][fj][r] + bb);
      } else {                                   // V -> transposed [h][dk][s] f16
        const int n3 = n - 2 * DM, hh = n3 >> 6, dk = n3 & 63;
        const float bb = bv[n3];
        ushort4 ov = make_ushort4(f2h(acc[fi][fj][0] + bb), f2h(acc[fi][fj][1] + bb),
                                  f2h(acc[fi][fj][2] + bb), f2h(acc[fi][fj][3] + bb));
        *(ushort4*)(vt + ((size_t)hh * HD + dk) * SEQ + mbase) = ov;
      }
    }
  }
}

// ------ MFMA band attention, 256 queries/block (16 waves) + merged global row -
// R25-verified structure + R27 XCD head-locality swizzle. RACE FIX (R28): band
// path never writes ctx row 0 (s==0 guard) — the global-row block is the sole
// writer, so the result no longer depends on block dispatch order (G16).
__global__ __launch_bounds__(1024, 1)
void attn_fused(const unsigned short* __restrict__ qb,
                const unsigned short* __restrict__ kb,
                const unsigned short* __restrict__ vt,
                unsigned short* __restrict__ ctx)
{
  __shared__ __align__(16) unsigned short Ks[2][64 * 64];
  __shared__ __align__(16) unsigned short Vts[2][64 * 64];
  __shared__ __align__(16) unsigned short plds[16][16 * 64];
  const int t = threadIdx.x;

  // bijective XCD swizzle of the (x, head) work space
  const int nwg  = gridDim.x * gridDim.y;                 // 204
  const int flat = blockIdx.y * gridDim.x + blockIdx.x;
  const int qch  = nwg >> 3, rch = nwg & 7;
  const int xcd  = flat & 7, idx = flat >> 3;
  const int nf   = (xcd < rch) ? xcd * (qch + 1) + idx
                               : rch * (qch + 1) + (xcd - rch) * qch + idx;
  const int bx = nf % gridDim.x;
  const int h  = nf / gridDim.x;

  const unsigned short* Qh  = qb + (size_t)h * SEQ * HD;
  const unsigned short* Kh  = kb + (size_t)h * SEQ * HD;
  const unsigned short* Vth = vt + (size_t)h * HD * SEQ;

  if (bx == (SEQ / 256)) {
    // ============== global row path (query 0, all keys; 1024 threads) ========
    float* sc   = (float*)&Ks[0][0];          // 16 KB = 4096 f32 (spans Ks[0..1])
    float* q0   = (float*)&plds[0][0];        // 64 f32
    float* red  = q0 + 64;                    // 16 f32
    float* accl = red + 16;                   // 16*64 f32
    if (t < HD) q0[t] = h2f(Qh[t]);           // pre-scaled by 1/8
    __syncthreads();

    for (int j = t; j < SEQ; j += 1024) {
      const unsigned short* Kp = Kh + (size_t)j * HD;
      float a0 = 0.f, a1 = 0.f;
      for (int d0 = 0; d0 < 8; d0++) {
        const bf16x8 kv = *(const bf16x8*)(Kp + d0 * 8);
#pragma unroll
        for (int e = 0; e < 8; e += 2) {
          a0 += q0[d0 * 8 + e]     * h2f((unsigned short)kv[e]);
          a1 += q0[d0 * 8 + e + 1] * h2f((unsigned short)kv[e + 1]);
        }
      }
      sc[j] = a0 + a1;
    }
    __syncthreads();

    float mx = -1e30f;
    for (int j = t; j < SEQ; j += 1024) mx = fmaxf(mx, sc[j]);
    for (int d = 1; d < 64; d <<= 1) mx = fmaxf(mx, __shfl_xor(mx, d));
    if ((t & 63) == 0) red[t >> 6] = mx;
    __syncthreads();
    mx = red[0];
#pragma unroll
    for (int i = 1; i < 16; i++) mx = fmaxf(mx, red[i]);
    __syncthreads();

    float sum = 0.f;
    for (int j = t; j < SEQ; j += 1024) {
      const float p = __expf(sc[j] - mx);
      sc[j] = p;
      sum += p;
    }
    for (int d = 1; d < 64; d <<= 1) sum += __shfl_xor(sum, d);
    __syncthreads();
    if ((t & 63) == 0) red[t >> 6] = sum;
    __syncthreads();
    float tot = red[0];
#pragma unroll
    for (int i = 1; i < 16; i++) tot += red[i];
    const float inv = 1.f / tot;

    const int dd = t & 63, part = t >> 6;     // part 0..15, each covers 256 j
    const unsigned short* Vp = Vth + (size_t)dd * SEQ;
    float a0 = 0.f, a1 = 0.f, a2 = 0.f, a3 = 0.f;
    const int jb = part * 256;
    for (int j = 0; j < 256; j += 4) {
      a0 += sc[jb + j + 0] * h2f(Vp[jb + j + 0]);
      a1 += sc[jb + j + 1] * h2f(Vp[jb + j + 1]);
      a2 += sc[jb + j + 2] * h2f(Vp[jb + j + 2]);
      a3 += sc[jb + j + 3] * h2f(Vp[jb + j + 3]);
    }
    accl[part * 64 + dd] = (a0 + a1) + (a2 + a3);
    __syncthreads();
    if (part == 0) {
      float v = 0.f;
#pragma unroll
      for (int i = 0; i < 16; i++) v += accl[i * 64 + dd];
      ctx[(size_t)h * HD + dd] = f2b(v * inv);   // row 0 (sole writer)
    }
    return;
  }

  // ================= band path (256 queries, 16 waves) ======================
  const int i0 = bx * 256;
  const int w  = t >> 6, l = t & 63;
  const int lr = l & 15;
  const int cb = (l >> 4);
  const int qi0 = i0 + w * 16 + (l >> 4) * 4;

  // staging: threads 0-511 cover K rows 0..63 (slot t&7), 512-1023 cover V
  const int sti  = t & 511;
  const int srow = sti >> 3;                 // 0..63
  const int scol = (sti & 7) ^ (srow & 7);   // pre-swizzled source 16B-slot
  const bool doK = (t < 512);

  // Q fragments: loop-invariant, loaded DIRECTLY from global (one row, 2x16B)
  const int qrow = i0 + w * 16 + lr;
  const f16x8 qa0 = __builtin_bit_cast(f16x8,
      *(const bf16x8*)(Qh + (size_t)qrow * HD + cb * 8));
  const f16x8 qa1 = __builtin_bit_cast(f16x8,
      *(const bf16x8*)(Qh + (size_t)qrow * HD + (cb + 4) * 8));

  int lo = i0 - 256; if (lo < 0) lo = 0;
  int hi = i0 + 255 + 257; if (hi > SEQ) hi = SEQ;
  const int cbeg = lo >> 6, cend = (hi - 1) >> 6;
  const int pre  = (cbeg > 0) ? 1 : 0;
  const int nch  = cend - cbeg + 1 + pre;

  auto chunkof = [&](int it) -> int {
    return (pre && it == 0) ? 0 : (cbeg + it - pre);
  };
  auto stage = [&](int bsel, int cch) {
    const int jj0 = cch * 64;
    if (doK) {
      gload_lds16(Kh + (size_t)(jj0 + srow) * HD + scol * 8,
                  (char*)(&Ks[bsel][0]) + sti * 16);
    } else {
      gload_lds16(Vth + (size_t)srow * SEQ + jj0 + scol * 8,
                  (char*)(&Vts[bsel][0]) + sti * 16);
    }
  };
  auto frag = [&](const unsigned short* base, int rr, int cc) -> f16x8 {
    return __builtin_bit_cast(f16x8,
        *(const bf16x8*)(base + rr * 64 + ((cc ^ (rr & 7)) * 8)));
  };

  stage(0, chunkof(0));
  __syncthreads();

  f32x4 o[4];
#pragma unroll
  for (int i = 0; i < 4; i++) o[i] = (f32x4){0.f, 0.f, 0.f, 0.f};
  float mrow[4] = {-1e30f, -1e30f, -1e30f, -1e30f};
  float ls[4]   = {0.f, 0.f, 0.f, 0.f};
  unsigned short* P = &plds[w][0];

  for (int it = 0; it < nch; ++it) {
    if (it + 1 < nch) stage((it + 1) & 1, chunkof(it + 1));

    const int c  = chunkof(it);
    const int j0 = c * 64;
    const unsigned short* Kc = &Ks[it & 1][0];
    const unsigned short* Vc = &Vts[it & 1][0];

    f32x4 sc[4];
#pragma unroll
    for (int i = 0; i < 4; i++) sc[i] = (f32x4){0.f, 0.f, 0.f, 0.f};
#pragma unroll
    for (int fj = 0; fj < 4; fj++) {
      const f16x8 kf0 = frag(Kc, fj * 16 + lr, cb);
      const f16x8 kf1 = frag(Kc, fj * 16 + lr, cb + 4);
      sc[fj] = __builtin_amdgcn_mfma_f32_16x16x32_f16(qa0, kf0, sc[fj], 0, 0, 0);
      sc[fj] = __builtin_amdgcn_mfma_f32_16x16x32_f16(qa1, kf1, sc[fj], 0, 0, 0);
    }
    mfma_guard();

    bool exceed = false;
#pragma unroll
    for (int r = 0; r < 4; r++) {
      const int qi = qi0 + r;
#pragma unroll
      for (int fj = 0; fj < 4; fj++) {
        const int j = j0 + fj * 16 + lr;
        const bool valid = (j == 0) || ((j - qi) <= 256 && (qi - j) <= 256);
        const float v = valid ? sc[fj][r] : -1e30f;
        sc[fj][r] = v;
        exceed |= (v > mrow[r] + 8.f);
      }
    }
    if (__any(exceed)) {
#pragma unroll
      for (int r = 0; r < 4; r++) {
        float mx = fmaxf(fmaxf(sc[0][r], sc[1][r]), fmaxf(sc[2][r], sc[3][r]));
        for (int d = 1; d < 16; d <<= 1) mx = fmaxf(mx, __shfl_xor(mx, d));
        const float mnew  = fmaxf(mrow[r], mx);
        const float scale = __expf(mrow[r] - mnew);
        mrow[r] = mnew;
        ls[r] *= scale;
#pragma unroll
        for (int fn = 0; fn < 4; fn++) o[fn][r] *= scale;
      }
    }
#pragma unroll
    for (int r = 0; r < 4; r++) {
      float psum = 0.f;
#pragma unroll
      for (int fj = 0; fj < 4; fj++) {
        const float p = __expf(sc[fj][r] - mrow[r]);
        sc[fj][r] = p;
        psum += p;
      }
      ls[r] += psum;
    }

    // ---- P (C-layout, f16) -> wave-private LDS, XOR-block swizzled (R23)
#pragma unroll
    for (int fj = 0; fj < 4; fj++)
#pragma unroll
      for (int r = 0; r < 4; r++) {
        const int prow = (l >> 4) * 4 + r;
        const int e    = fj * 16 + lr;
        P[prow * 64 + (((e >> 3) ^ (prow & 7)) * 8) + (e & 7)] = f2h(sc[fj][r]);
      }

    const f16x8 pf0 = frag(P, lr, cb);
    const f16x8 pf1 = frag(P, lr, cb + 4);
#pragma unroll
    for (int fn = 0; fn < 4; fn++) {
      const f16x8 vf0 = frag(Vc, fn * 16 + lr, cb);
      const f16x8 vf1 = frag(Vc, fn * 16 + lr, cb + 4);
      o[fn] = __builtin_amdgcn_mfma_f32_16x16x32_f16(pf0, vf0, o[fn], 0, 0, 0);
      o[fn] = __builtin_amdgcn_mfma_f32_16x16x32_f16(pf1, vf1, o[fn], 0, 0, 0);
    }
    __syncthreads();   // prefetch landed + all waves done with buf[it&1]
  }

  mfma_guard();

#pragma unroll
  for (int r = 0; r < 4; r++)
    for (int d = 1; d < 16; d <<= 1) ls[r] += __shfl_xor(ls[r], d);

#pragma unroll
  for (int fn = 0; fn < 4; fn++)
#pragma unroll
    for (int r = 0; r < 4; r++) {
      const int s = qi0 + r;
      if (s == 0) continue;                 // row 0 owned by global-row block
      const float val = o[fn][r] / ls[r];
      ctx[(size_t)s * DM + h * HD + fn * 16 + lr] = f2b(val);
    }
}

// ---------------- launch ----------------
extern "C" void kernel_launch(void* const* d_in, const int* in_sizes, int n_in,
                              void* d_out, int out_size, void* d_ws, size_t ws_size,
                              hipStream_t stream)
{
  (void)in_sizes; (void)n_in; (void)out_size; (void)ws_size;
  const float* x  = (const float*)d_in[0];
  const float* Wq = (const float*)d_in[1];
  const float* bq = (const float*)d_in[2];
  const float* Wk = (const float*)d_in[3];
  const float* bk = (const float*)d_in[4];
  const float* Wv = (const float*)d_in[5];
  const float* bv = (const float*)d_in[6];
  const float* Wo = (const float*)d_in[7];
  const float* bo = (const float*)d_in[8];
  float* out = (float*)d_out;

  char* ws = (char*)d_ws;
  unsigned short* xb   = (unsigned short*)(ws + 0);         // dead after gemm<0>
  unsigned short* wqkv = (unsigned short*)(ws + 6291456);
  unsigned short* wob  = (unsigned short*)(ws + 9830400);
  unsigned short* qbuf = (unsigned short*)(ws + 11010048);  // [12][4096][64] f16
  unsigned short* kbuf = (unsigned short*)(ws + 17301504);  // [12][4096][64] f16
  unsigned short* vtb  = (unsigned short*)(ws + 23592960);  // [12][64][4096] f16
  unsigned short* ctx  = (unsigned short*)(ws + 0);         // bf16, aliases xb

  convert_all<<<dim3(1024), dim3(256), 0, stream>>>(x, Wq, Wk, Wv, Wo, xb, wqkv, wob);
  gemm_bt<0><<<dim3(18, 32), dim3(256), 0, stream>>>(xb, wqkv, qbuf, kbuf, vtb,
                                                     bq, bk, bv, nullptr, nullptr);
  attn_fused<<<dim3(SEQ / 256 + 1, NH), dim3(1024), 0, stream>>>(qbuf, kbuf, vtb, ctx);
  gemm_bt<1><<<dim3(6, 32), dim3(256), 0, stream>>>(ctx, wob, nullptr, nullptr, nullptr,
                                                    nullptr, nullptr, nullptr, bo, out);
}